// Round 13
// baseline (578.910 us; speedup 1.0000x reference)
//
#include <hip/hip_runtime.h>

#define NN 100000
#define NE 1600000
#define TMAX 193760           // >= sum ceil(deg/16) worst case (193750)
#define NRANGES 24220         // TMAX / 8

typedef unsigned int uint32;
typedef unsigned long long ull;
typedef __attribute__((ext_vector_type(8))) short bf16x8;
typedef __attribute__((ext_vector_type(4))) float f32x4;

__device__ __forceinline__ unsigned short f2bf(float f) {
  unsigned int u = __float_as_uint(f);
  unsigned int r = (u + 0x7fffu + ((u >> 16) & 1u)) >> 16;  // RNE
  return (unsigned short)r;
}
__device__ __forceinline__ float bf2f(unsigned short u) {
  return __uint_as_float(((unsigned int)u) << 16);
}
__device__ __forceinline__ unsigned int pack2(float a, float b) {
  return (unsigned int)f2bf(a) | ((unsigned int)f2bf(b) << 16);
}
// round-half-up pack of two f32 -> bf16 pair (cheap, ~= RNE for random data)
__device__ __forceinline__ uint32 pack2ru(float a, float b) {
  const uint32 ua = __float_as_uint(a) + 0x8000u;
  const uint32 ub = __float_as_uint(b) + 0x8000u;
  return (ua >> 16) | (ub & 0xffff0000u);
}
// sum over the 16 lanes of each DPP row via row_ror adds (pure VALU, no LDS)
__device__ __forceinline__ float row16_sum(float x) {
  x += __int_as_float(__builtin_amdgcn_mov_dpp(__float_as_int(x), 0x128, 0xf, 0xf, false));
  x += __int_as_float(__builtin_amdgcn_mov_dpp(__float_as_int(x), 0x124, 0xf, 0xf, false));
  x += __int_as_float(__builtin_amdgcn_mov_dpp(__float_as_int(x), 0x122, 0xf, 0xf, false));
  x += __int_as_float(__builtin_amdgcn_mov_dpp(__float_as_int(x), 0x121, 0xf, 0xf, false));
  return x;
}

// ---------------------------------------------------------------------------
// Combined weight/activation conversion (one launch).
// ---------------------------------------------------------------------------
__device__ __forceinline__ void wconv_body(const float* __restrict__ src,
    unsigned short* __restrict__ dst, int K, int N, int b)
{
  const int i = b * 256 + threadIdx.x;
  if (i < K * N) {
    const int n = i / K, k = i - n * K;
    dst[i] = f2bf(src[k * N + n]);
  }
}

__global__ __launch_bounds__(256) void conv_all(
    const float* __restrict__ l0W1, const float* __restrict__ l0W2,
    const float* __restrict__ l1W1, const float* __restrict__ l1W2,
    const float* __restrict__ hW1,  const float* __restrict__ l0We,
    const float* __restrict__ l1We, const float* __restrict__ x,
    unsigned short* __restrict__ W1t0, unsigned short* __restrict__ W2t0,
    unsigned short* __restrict__ W1t1, unsigned short* __restrict__ W2t1,
    unsigned short* __restrict__ hW1t, unsigned short* __restrict__ Wet0,
    unsigned short* __restrict__ Wet1, unsigned short* __restrict__ xb)
{
  int b = blockIdx.x;
  if (b < 16)  { wconv_body(l0W1, W1t0, 32, 128, b); return; }  b -= 16;
  if (b < 64)  { wconv_body(l0W2, W2t0, 128, 128, b); return; } b -= 64;
  if (b < 64)  { wconv_body(l1W1, W1t1, 128, 128, b); return; } b -= 64;
  if (b < 64)  { wconv_body(l1W2, W2t1, 128, 128, b); return; } b -= 64;
  if (b < 64)  { wconv_body(hW1,  hW1t, 128, 128, b); return; } b -= 64;
  if (b < 2)   { wconv_body(l0We, Wet0, 16, 32, b); return; }   b -= 2;
  if (b < 8)   { wconv_body(l1We, Wet1, 16, 128, b); return; }  b -= 8;
  const int i = b * 256 + threadIdx.x;
  if (i * 8 < NN * 32) {
    const float4 a = ((const float4*)x)[i * 2];
    const float4 d = ((const float4*)x)[i * 2 + 1];
    uint4 o;
    o.x = pack2(a.x, a.y); o.y = pack2(a.z, a.w);
    o.z = pack2(d.x, d.y); o.w = pack2(d.z, d.w);
    ((uint4*)xb)[i] = o;
  }
}

// ---------------------------------------------------------------------------
// CSR build: histogram -> dual prefix scan (tiles, edges) -> snode -> fill
// ---------------------------------------------------------------------------
__global__ __launch_bounds__(256) void hist_kernel(
    const int* __restrict__ ei, uint32* __restrict__ deg)
{
  const int e = blockIdx.x * 256 + threadIdx.x;
  if (e < NE) atomicAdd(&deg[ei[NE + e]], 1u);
}

__global__ __launch_bounds__(256) void offsets2_kernel(
    const uint32* __restrict__ deg, uint32* __restrict__ toff,
    uint32* __restrict__ eoff, ull* __restrict__ counter)
{
  __shared__ ull s[256];
  __shared__ ull base;
  const int tid = threadIdx.x;
  const int n = blockIdx.x * 256 + tid;
  const uint32 d = (n < NN) ? deg[n] : 0u;
  const uint32 tc = (d + 15u) >> 4;
  const ull v = ((ull)tc << 32) | (ull)d;
  s[tid] = v;
  __syncthreads();
#pragma unroll
  for (int st = 1; st < 256; st <<= 1) {
    ull w = (tid >= st) ? s[tid - st] : 0ull;
    __syncthreads();
    s[tid] += w;
    __syncthreads();
  }
  if (tid == 255) base = atomicAdd(counter, s[255]);
  __syncthreads();
  if (n < NN) {
    const ull t = base + (s[tid] - v);
    toff[n] = (uint32)(t >> 32);
    eoff[n] = (uint32)t;
  }
}

__global__ __launch_bounds__(256) void snode_fill(
    const uint32* __restrict__ toff, const uint32* __restrict__ deg,
    int* __restrict__ snode)
{
  const int n = blockIdx.x * 256 + threadIdx.x;
  if (n < NN) {
    const uint32 t0 = toff[n];
    const uint32 tc = (deg[n] + 15u) >> 4;
    for (uint32 i = 0; i < tc; ++i) snode[t0 + i] = n;
  }
}

// single light scatter: 8B (edge id, src) per dense slot
__global__ __launch_bounds__(256) void fill_kernel(
    const int* __restrict__ ei, const uint32* __restrict__ eoff,
    uint32* __restrict__ cnt, uint2* __restrict__ esrc2)
{
  const int e = blockIdx.x * 256 + threadIdx.x;
  if (e < NE) {
    const int dst = ei[NE + e];
    const uint32 pos = eoff[dst] + atomicAdd(&cnt[dst], 1u);
    esrc2[pos] = make_uint2((uint32)e, (uint32)ei[e]);
  }
}

// ---------------------------------------------------------------------------
// flat_agg6: padded-tile aggregate.
//  GEA=true  (layer 0): gather ea f32, pack bf16, WRITE eabc coalesced (dense
//                       CSR slot) as producer for layer 1
//  GEA=false (layer 1): read pre-packed eabc (dense, coalesced/L3-warm)
//  MFMA with C=0; h added in VALU after (R9/R12 style)
//  poison-validity via A[k=17]=-1e38 & B[17]=1.0 on invalid edge columns
//  per-lane DIRECT esrc2 load (tile's 16 slots = one L1 line; no shfl chain)
//  permuted channel map, DPP row flush, 4-deep pipeline (3 tiles in flight)
// ---------------------------------------------------------------------------
template<int D, int NCT, bool GEA>
__global__ __launch_bounds__(256) void flat_agg6(
    const int* __restrict__ snode, const uint32* __restrict__ toff,
    const uint32* __restrict__ eoff, const uint32* __restrict__ deg,
    const uint2* __restrict__ esrc2, const float* __restrict__ ea,
    unsigned short* __restrict__ eabc,
    const unsigned short* __restrict__ hsrc,
    const unsigned short* __restrict__ Wet, const float* __restrict__ be,
    const ull* __restrict__ tot, float* __restrict__ agg)
{
  const int tid = threadIdx.x;
  const int wid = tid >> 6;
  const int lane = tid & 63;
  const int c = lane & 15;
  const int g = lane >> 4;
  constexpr bool HALF = (NCT * 16 != D);
  int range, ch0;
  if (HALF) { range = blockIdx.x * 2 + (wid >> 1); ch0 = (wid & 1) * (NCT * 16); }
  else      { range = blockIdx.x * 4 + wid;        ch0 = 0; }
  const int tile0 = range * 8;
  const uint32 ntile = (uint32)((*tot) >> 32);
  if ((uint32)tile0 >= ntile) return;   // dead range

  // W fragments; A row r <-> channel ch0 + (r>>2)*(4NCT) + ct*4 + (r&3)
  // k=16 carries be (B k16=1.0); k=17 carries -1e38 (B k17=1.0 iff invalid)
  bf16x8 wf[NCT];
#pragma unroll
  for (int ct = 0; ct < NCT; ++ct) {
    const int chA = ch0 + (c >> 2) * (NCT * 4) + ct * 4 + (c & 3);
    uint4 u = make_uint4(0u, 0u, 0u, 0u);
    if (g < 2) u = *(const uint4*)&Wet[chA * 16 + g * 8];
    else if (g == 2) u.x = (0xFE96u << 16) | (uint32)f2bf(be[chA]);
    union { uint4 u4; bf16x8 v; } cv; cv.u4 = u;
    wf[ct] = cv.v;
  }

  // per-tile metadata on lanes 0..7: pk = d0(7b) | rem(5b,<=16) | flags(2b)
  int sn8 = -1, pk8 = 0, p_ = 0;
  if (lane < 8) {
    sn8 = snode[tile0 + lane];
    if (sn8 >= 0) {
      const uint32 to = toff[sn8], dg = deg[sn8], eo = eoff[sn8];
      const int k = tile0 + lane - (int)to;
      p_ = (int)eo + k * 16;
      int rv = (int)dg - k * 16; if (rv > 16) rv = 16;
      const int fl = (k == 0 ? 1 : 0) |
                     ((k == (int)((dg + 15u) >> 4) - 1) ? 2 : 0);
      pk8 = (rv << 7) | (fl << 12);
    }
  }
  const int p0base = __shfl(p_, 0);   // lane 0 (tile0) is always real
  if (lane < 8 && sn8 >= 0) pk8 |= (p_ - p0base);

  float acc[NCT][4];
#pragma unroll
  for (int ct = 0; ct < NCT; ++ct) {
    acc[ct][0] = 0.f; acc[ct][1] = 0.f; acc[ct][2] = 0.f; acc[ct][3] = 0.f;
  }
  int openNode = -1; bool openFull = false, openClosed = false;

  auto flushOpen = [&](bool storeOK) {
#pragma unroll
    for (int ct = 0; ct < NCT; ++ct)
#pragma unroll
      for (int j = 0; j < 4; ++j)
        acc[ct][j] = row16_sum(acc[ct][j]);
    float4 sv = make_float4(0.f, 0.f, 0.f, 0.f);
#pragma unroll
    for (int ct = 0; ct < NCT; ++ct)
      if (c == ct)
        sv = make_float4(acc[ct][0], acc[ct][1], acc[ct][2], acc[ct][3]);
    if (c < NCT) {
      float* p = &agg[(size_t)openNode * D + ch0 + g * (NCT * 4) + c * 4];
      if (storeOK) {
        *(float4*)p = sv;
      } else {
        atomicAdd(p + 0, sv.x); atomicAdd(p + 1, sv.y);
        atomicAdd(p + 2, sv.z); atomicAdd(p + 3, sv.w);
      }
    }
  };

  // issue: per-lane DIRECT slot load (tile slots are contiguous; L1-resident)
  auto issue = [&](int t, float4& E0, float4& E1, uint4& afu,
                   uint4& h0, uint4& h1, int& n_, int& mt_) {
    n_ = __shfl(sn8, t);
    mt_ = __shfl(pk8, t);
    const int d0 = mt_ & 127;
    const int rem = (mt_ >> 7) & 31;
    const int idx = d0 + ((c < rem) ? c : 0);
    const uint2 es = esrc2[(size_t)p0base + idx];
    const int src = (int)es.y;
    if constexpr (GEA) {
      const int e = (int)es.x;
      if (g < 2) {
        E0 = *(const float4*)&ea[(size_t)e * 16 + g * 8];
        E1 = *(const float4*)&ea[(size_t)e * 16 + g * 8 + 4];
      }
    } else {
      if (g < 2) afu = *(const uint4*)&eabc[((size_t)p0base + idx) * 16 + g * 8];
    }
    h0 = *(const uint4*)&hsrc[(size_t)src * D + ch0 + g * (NCT * 4)];
    if constexpr (NCT == 4)
      h1 = *(const uint4*)&hsrc[(size_t)src * D + ch0 + g * (NCT * 4) + 8];
  };

  auto compute = [&](const float4 E0, const float4 E1, uint4 afu,
                     const uint4 h0, const uint4 h1, const int n, const int mt) {
    if (n < 0) return;
    const int rem = (mt >> 7) & 31;
    const int fl = mt >> 12;
    if (n != openNode) {
      if (openNode >= 0) {
        flushOpen(openFull);
#pragma unroll
        for (int ct = 0; ct < NCT; ++ct) {
          acc[ct][0] = 0.f; acc[ct][1] = 0.f;
          acc[ct][2] = 0.f; acc[ct][3] = 0.f;
        }
      }
      openNode = n; openFull = (fl & 1) != 0; openClosed = false;
    }
    if (fl & 2) openClosed = true;
    if constexpr (GEA) {
      afu.x = pack2ru(E0.x, E0.y); afu.y = pack2ru(E0.z, E0.w);
      afu.z = pack2ru(E1.x, E1.y); afu.w = pack2ru(E1.z, E1.w);
      if (g < 2) {
        const int d0 = mt & 127;
        const int idx = d0 + ((c < rem) ? c : 0);
        *(uint4*)&eabc[((size_t)p0base + idx) * 16 + g * 8] = afu;
      }
    }
    bf16x8 afv;
    {
      uint4 u = make_uint4(0u, 0u, 0u, 0u);
      if (g < 2) u = afu;
      else if (g == 2) u.x = (c < rem) ? 0x3f80u : 0x3f803f80u;
      union { uint4 u4; bf16x8 v; } cv; cv.u4 = u; afv = cv.v;
    }
#pragma unroll
    for (int ct = 0; ct < NCT; ++ct) {
      f32x4 pre = __builtin_amdgcn_mfma_f32_16x16x32_bf16(
          wf[ct], afv, (f32x4){0.f, 0.f, 0.f, 0.f}, 0, 0, 0);
      uint32 w0, w1;
      if constexpr (NCT == 4) {
        const uint4 hu = (ct < 2) ? h0 : h1;
        w0 = (ct & 1) ? hu.z : hu.x;
        w1 = (ct & 1) ? hu.w : hu.y;
      } else {
        w0 = (ct & 1) ? h0.z : h0.x;
        w1 = (ct & 1) ? h0.w : h0.y;
      }
      acc[ct][0] += fmaxf(pre[0] + bf2f((unsigned short)(w0 & 0xffffu)), 0.f);
      acc[ct][1] += fmaxf(pre[1] + bf2f((unsigned short)(w0 >> 16)), 0.f);
      acc[ct][2] += fmaxf(pre[2] + bf2f((unsigned short)(w1 & 0xffffu)), 0.f);
      acc[ct][3] += fmaxf(pre[3] + bf2f((unsigned short)(w1 >> 16)), 0.f);
    }
  };

  float4 eA0, eA1, eB0, eB1, eC0, eC1, eD0, eD1;
  uint4 aA = make_uint4(0,0,0,0), aB = make_uint4(0,0,0,0);
  uint4 aC = make_uint4(0,0,0,0), aD = make_uint4(0,0,0,0);
  uint4 h0A = make_uint4(0,0,0,0), h1A = make_uint4(0,0,0,0);
  uint4 h0B = make_uint4(0,0,0,0), h1B = make_uint4(0,0,0,0);
  uint4 h0C = make_uint4(0,0,0,0), h1C = make_uint4(0,0,0,0);
  uint4 h0D = make_uint4(0,0,0,0), h1D = make_uint4(0,0,0,0);
  int nA = -1, mA = 0, nB = -1, mB = 0, nC = -1, mC = 0, nD = -1, mD = 0;

  // 4-deep pipeline: 3 tiles of loads in flight ahead of each compute
  issue(0, eA0, eA1, aA, h0A, h1A, nA, mA);
  issue(1, eB0, eB1, aB, h0B, h1B, nB, mB);
  issue(2, eC0, eC1, aC, h0C, h1C, nC, mC);
  issue(3, eD0, eD1, aD, h0D, h1D, nD, mD);
  compute(eA0, eA1, aA, h0A, h1A, nA, mA); issue(4, eA0, eA1, aA, h0A, h1A, nA, mA);
  compute(eB0, eB1, aB, h0B, h1B, nB, mB); issue(5, eB0, eB1, aB, h0B, h1B, nB, mB);
  compute(eC0, eC1, aC, h0C, h1C, nC, mC); issue(6, eC0, eC1, aC, h0C, h1C, nC, mC);
  compute(eD0, eD1, aD, h0D, h1D, nD, mD); issue(7, eD0, eD1, aD, h0D, h1D, nD, mD);
  compute(eA0, eA1, aA, h0A, h1A, nA, mA);
  compute(eB0, eB1, aB, h0B, h1B, nB, mB);
  compute(eC0, eC1, aC, h0C, h1C, nC, mC);
  compute(eD0, eD1, aD, h0D, h1D, nD, mD);
  if (openNode >= 0) flushOpen(openFull && openClosed);
}

// ---------------------------------------------------------------------------
// MFMA node MLP: out = relu((a+agg)@W1+b1)@W2+b2, + BN stats.
// ---------------------------------------------------------------------------
template<int DIN, bool ABF16>
__global__ __launch_bounds__(256) void mlp_mfma(
    const float* __restrict__ a32, const unsigned short* __restrict__ abf,
    const float* __restrict__ agg,
    const unsigned short* __restrict__ W1t, const float* __restrict__ b1,
    const unsigned short* __restrict__ W2t, const float* __restrict__ b2,
    float* __restrict__ outp, float* __restrict__ stats, int nChunks)
{
  constexpr int P1 = (DIN == 128) ? 136 : 40;
  constexpr int KS1 = DIN / 32;
  __shared__ __align__(16) unsigned short hin[64 * P1];
  __shared__ __align__(16) unsigned short tls[64 * 136];
  const int tid = threadIdx.x;
  const int w = tid >> 6;
  const int lane = tid & 63;
  const int c = lane & 15, g = lane >> 4;
  const int cw = w * 32;

  bf16x8 B1[2][KS1], B2[2][4];
#pragma unroll
  for (int ct = 0; ct < 2; ++ct)
#pragma unroll
    for (int kk = 0; kk < KS1; ++kk)
      B1[ct][kk] = *(const bf16x8*)&W1t[(cw + ct * 16 + c) * DIN + kk * 32 + g * 8];
#pragma unroll
  for (int ct = 0; ct < 2; ++ct)
#pragma unroll
    for (int kk = 0; kk < 4; ++kk)
      B2[ct][kk] = *(const bf16x8*)&W2t[(cw + ct * 16 + c) * 128 + kk * 32 + g * 8];
  const float b1c0 = b1[cw + c], b1c1 = b1[cw + 16 + c];
  const float b2c0 = b2[cw + c], b2c1 = b2[cw + 16 + c];
  float lsum0 = 0.f, lsum1 = 0.f, lsq0 = 0.f, lsq1 = 0.f;

  for (int chunk = blockIdx.x; chunk < nChunks; chunk += gridDim.x) {
    const int base = chunk * 64;
    if constexpr (DIN == 128) {
#pragma unroll
      for (int p = 0; p < 4; ++p) {
        const int idx = tid + 256 * p;
        const int n = idx >> 4, k8 = idx & 15;
        const int node = base + n;
        uint4 ov = make_uint4(0u, 0u, 0u, 0u);
        if (node < NN) {
          const float4 g0 = *(const float4*)&agg[node * 128 + k8 * 8];
          const float4 g1 = *(const float4*)&agg[node * 128 + k8 * 8 + 4];
          const uint4 hv = *(const uint4*)&abf[node * 128 + k8 * 8];
          ov.x = pack2(bf2f((unsigned short)(hv.x & 0xffffu)) + g0.x,
                       bf2f((unsigned short)(hv.x >> 16)) + g0.y);
          ov.y = pack2(bf2f((unsigned short)(hv.y & 0xffffu)) + g0.z,
                       bf2f((unsigned short)(hv.y >> 16)) + g0.w);
          ov.z = pack2(bf2f((unsigned short)(hv.z & 0xffffu)) + g1.x,
                       bf2f((unsigned short)(hv.z >> 16)) + g1.y);
          ov.w = pack2(bf2f((unsigned short)(hv.w & 0xffffu)) + g1.z,
                       bf2f((unsigned short)(hv.w >> 16)) + g1.w);
        }
        *(uint4*)&hin[n * P1 + k8 * 8] = ov;
      }
    } else {
      const int n = tid >> 2, k8 = tid & 3;
      const int node = base + n;
      uint4 ov = make_uint4(0u, 0u, 0u, 0u);
      if (node < NN) {
        const float4 x0 = *(const float4*)&a32[node * 32 + k8 * 8];
        const float4 x1 = *(const float4*)&a32[node * 32 + k8 * 8 + 4];
        const float4 g0 = *(const float4*)&agg[node * 32 + k8 * 8];
        const float4 g1 = *(const float4*)&agg[node * 32 + k8 * 8 + 4];
        ov.x = pack2(x0.x + g0.x, x0.y + g0.y);
        ov.y = pack2(x0.z + g0.z, x0.w + g0.w);
        ov.z = pack2(x1.x + g1.x, x1.y + g1.y);
        ov.w = pack2(x1.z + g1.z, x1.w + g1.w);
      }
      *(uint4*)&hin[n * P1 + k8 * 8] = ov;
    }
    __syncthreads();
#pragma unroll
    for (int nt = 0; nt < 4; ++nt) {
      bf16x8 af[KS1];
#pragma unroll
      for (int kk = 0; kk < KS1; ++kk)
        af[kk] = *(const bf16x8*)&hin[(nt * 16 + c) * P1 + kk * 32 + g * 8];
      f32x4 acc0 = {0.f, 0.f, 0.f, 0.f}, acc1 = {0.f, 0.f, 0.f, 0.f};
#pragma unroll
      for (int kk = 0; kk < KS1; ++kk) {
        acc0 = __builtin_amdgcn_mfma_f32_16x16x32_bf16(af[kk], B1[0][kk], acc0, 0, 0, 0);
        acc1 = __builtin_amdgcn_mfma_f32_16x16x32_bf16(af[kk], B1[1][kk], acc1, 0, 0, 0);
      }
#pragma unroll
      for (int j = 0; j < 4; ++j) {
        const int row = nt * 16 + g * 4 + j;
        tls[row * 136 + cw + c]      = f2bf(fmaxf(acc0[j] + b1c0, 0.f));
        tls[row * 136 + cw + 16 + c] = f2bf(fmaxf(acc1[j] + b1c1, 0.f));
      }
    }
    __syncthreads();
#pragma unroll
    for (int nt = 0; nt < 4; ++nt) {
      bf16x8 af[4];
#pragma unroll
      for (int kk = 0; kk < 4; ++kk)
        af[kk] = *(const bf16x8*)&tls[(nt * 16 + c) * 136 + kk * 32 + g * 8];
      f32x4 acc0 = {0.f, 0.f, 0.f, 0.f}, acc1 = {0.f, 0.f, 0.f, 0.f};
#pragma unroll
      for (int kk = 0; kk < 4; ++kk) {
        acc0 = __builtin_amdgcn_mfma_f32_16x16x32_bf16(af[kk], B2[0][kk], acc0, 0, 0, 0);
        acc1 = __builtin_amdgcn_mfma_f32_16x16x32_bf16(af[kk], B2[1][kk], acc1, 0, 0, 0);
      }
#pragma unroll
      for (int j = 0; j < 4; ++j) {
        const int node = base + nt * 16 + g * 4 + j;
        if (node < NN) {
          const float v0 = acc0[j] + b2c0;
          const float v1 = acc1[j] + b2c1;
          outp[node * 128 + cw + c] = v0;
          outp[node * 128 + cw + 16 + c] = v1;
          lsum0 += v0; lsq0 += v0 * v0;
          lsum1 += v1; lsq1 += v1 * v1;
        }
      }
    }
  }
  lsum0 += __shfl_xor(lsum0, 16); lsum0 += __shfl_xor(lsum0, 32);
  lsum1 += __shfl_xor(lsum1, 16); lsum1 += __shfl_xor(lsum1, 32);
  lsq0  += __shfl_xor(lsq0, 16);  lsq0  += __shfl_xor(lsq0, 32);
  lsq1  += __shfl_xor(lsq1, 16);  lsq1  += __shfl_xor(lsq1, 32);
  if (lane < 16) {
    atomicAdd(&stats[cw + lane], lsum0);
    atomicAdd(&stats[cw + 16 + lane], lsum1);
    atomicAdd(&stats[128 + cw + lane], lsq0);
    atomicAdd(&stats[128 + cw + 16 + lane], lsq1);
  }
}

__global__ void bn_finalize(float* __restrict__ stats,
                            const float* __restrict__ gamma,
                            const float* __restrict__ beta)
{
  const int cc = threadIdx.x;
  const float inv_n = 1.0f / (float)NN;
  const float mu = stats[cc] * inv_n;
  float var = stats[128 + cc] * inv_n - mu * mu;
  var = fmaxf(var, 0.f);
  const float rs = rsqrtf(var + 1e-5f);
  const float sc = rs * gamma[cc];
  stats[256 + cc] = sc;
  stats[384 + cc] = beta[cc] - mu * sc;
}

__global__ __launch_bounds__(256) void bn_apply_bf16(
    const float* __restrict__ h, const float* __restrict__ stats,
    unsigned short* __restrict__ hb)
{
  const int idx = blockIdx.x * 256 + threadIdx.x;
  const int c4 = (idx & 31) * 4;
  const float4 sc = *(const float4*)&stats[256 + c4];
  const float4 sh = *(const float4*)&stats[384 + c4];
  const float4 v = ((const float4*)h)[idx];
  const float r0 = fmaxf(fmaf(v.x, sc.x, sh.x), 0.f);
  const float r1 = fmaxf(fmaf(v.y, sc.y, sh.y), 0.f);
  const float r2 = fmaxf(fmaf(v.z, sc.z, sh.z), 0.f);
  const float r3 = fmaxf(fmaf(v.w, sc.w, sh.w), 0.f);
  uint2 o;
  o.x = pack2(r0, r1);
  o.y = pack2(r2, r3);
  ((uint2*)hb)[idx] = o;
}

// ---------------------------------------------------------------------------
// Fused BN-apply + head: out = sigmoid(relu(relu(hpre*sc+sh)@W1+b1)@w2 + b2)
// ---------------------------------------------------------------------------
__global__ __launch_bounds__(256) void head_bn(
    const float* __restrict__ hpre, const float* __restrict__ stats,
    const unsigned short* __restrict__ W1t, const float* __restrict__ b1,
    const float* __restrict__ w2, const float* __restrict__ b2,
    float* __restrict__ out, int nChunks)
{
  __shared__ float pl[4][64];
  const int tid = threadIdx.x;
  const int w = tid >> 6;
  const int lane = tid & 63;
  const int c = lane & 15, g = lane >> 4;
  const int cw = w * 32;

  bf16x8 B1[2][4];
#pragma unroll
  for (int ct = 0; ct < 2; ++ct)
#pragma unroll
    for (int kk = 0; kk < 4; ++kk)
      B1[ct][kk] = *(const bf16x8*)&W1t[(cw + ct * 16 + c) * 128 + kk * 32 + g * 8];
  const float b1c0 = b1[cw + c], b1c1 = b1[cw + 16 + c];
  const float w2c0 = w2[cw + c], w2c1 = w2[cw + 16 + c];
  const float b2v = b2[0];
  float4 scq[4][2], shq[4][2];
#pragma unroll
  for (int kk = 0; kk < 4; ++kk) {
    const int cb = kk * 32 + g * 8;
    scq[kk][0] = *(const float4*)&stats[256 + cb];
    scq[kk][1] = *(const float4*)&stats[256 + cb + 4];
    shq[kk][0] = *(const float4*)&stats[384 + cb];
    shq[kk][1] = *(const float4*)&stats[384 + cb + 4];
  }

  for (int chunk = blockIdx.x; chunk < nChunks; chunk += gridDim.x) {
    const int base = chunk * 64;
    float p[4][4];
#pragma unroll
    for (int nt = 0; nt < 4; ++nt) {
      const int node = base + nt * 16 + c;
      bf16x8 af[4];
#pragma unroll
      for (int kk = 0; kk < 4; ++kk) {
        uint4 u = make_uint4(0u, 0u, 0u, 0u);
        if (node < NN) {
          const float4 v0 = *(const float4*)&hpre[(size_t)node * 128 + kk * 32 + g * 8];
          const float4 v1 = *(const float4*)&hpre[(size_t)node * 128 + kk * 32 + g * 8 + 4];
          const float4 s0 = scq[kk][0], s1 = scq[kk][1];
          const float4 h0 = shq[kk][0], h1 = shq[kk][1];
          u.x = pack2(fmaxf(fmaf(v0.x, s0.x, h0.x), 0.f),
                      fmaxf(fmaf(v0.y, s0.y, h0.y), 0.f));
          u.y = pack2(fmaxf(fmaf(v0.z, s0.z, h0.z), 0.f),
                      fmaxf(fmaf(v0.w, s0.w, h0.w), 0.f));
          u.z = pack2(fmaxf(fmaf(v1.x, s1.x, h1.x), 0.f),
                      fmaxf(fmaf(v1.y, s1.y, h1.y), 0.f));
          u.w = pack2(fmaxf(fmaf(v1.z, s1.z, h1.z), 0.f),
                      fmaxf(fmaf(v1.w, s1.w, h1.w), 0.f));
        }
        union { uint4 u4; bf16x8 v; } cv; cv.u4 = u;
        af[kk] = cv.v;
      }
      f32x4 acc0 = {0.f, 0.f, 0.f, 0.f}, acc1 = {0.f, 0.f, 0.f, 0.f};
#pragma unroll
      for (int kk = 0; kk < 4; ++kk) {
        acc0 = __builtin_amdgcn_mfma_f32_16x16x32_bf16(af[kk], B1[0][kk], acc0, 0, 0, 0);
        acc1 = __builtin_amdgcn_mfma_f32_16x16x32_bf16(af[kk], B1[1][kk], acc1, 0, 0, 0);
      }
#pragma unroll
      for (int j = 0; j < 4; ++j)
        p[nt][j] = fmaxf(acc0[j] + b1c0, 0.f) * w2c0 +
                   fmaxf(acc1[j] + b1c1, 0.f) * w2c1;
    }
#pragma unroll
    for (int dd = 1; dd <= 8; dd <<= 1)
#pragma unroll
      for (int nt = 0; nt < 4; ++nt)
#pragma unroll
        for (int j = 0; j < 4; ++j)
          p[nt][j] += __shfl_xor(p[nt][j], dd);
    if (c == 0) {
#pragma unroll
      for (int nt = 0; nt < 4; ++nt)
#pragma unroll
        for (int j = 0; j < 4; ++j)
          pl[w][nt * 16 + g * 4 + j] = p[nt][j];
    }
    __syncthreads();
    if (tid < 64) {
      const int node = base + tid;
      if (node < NN) {
        const float s = pl[0][tid] + pl[1][tid] + pl[2][tid] + pl[3][tid] + b2v;
        out[node] = 1.f / (1.f + expf(-s));
      }
    }
    __syncthreads();
  }
}

extern "C" void kernel_launch(void* const* d_in, const int* in_sizes, int n_in,
                              void* d_out, int out_size, void* d_ws, size_t ws_size,
                              hipStream_t stream)
{
  const float* x    = (const float*)d_in[0];
  const int*   ei   = (const int*)  d_in[1];
  const float* ea   = (const float*)d_in[2];
  const float* l0We = (const float*)d_in[3];
  const float* l0be = (const float*)d_in[4];
  const float* l0W1 = (const float*)d_in[5];
  const float* l0b1 = (const float*)d_in[6];
  const float* l0W2 = (const float*)d_in[7];
  const float* l0b2 = (const float*)d_in[8];
  const float* l0g  = (const float*)d_in[9];
  const float* l0bt = (const float*)d_in[10];
  const float* l1We = (const float*)d_in[11];
  const float* l1be = (const float*)d_in[12];
  const float* l1W1 = (const float*)d_in[13];
  const float* l1b1 = (const float*)d_in[14];
  const float* l1W2 = (const float*)d_in[15];
  const float* l1b2 = (const float*)d_in[16];
  const float* l1g  = (const float*)d_in[17];
  const float* l1bt = (const float*)d_in[18];
  const float* hW1  = (const float*)d_in[19];
  const float* hb1  = (const float*)d_in[20];
  const float* hW2  = (const float*)d_in[21];
  const float* hb2  = (const float*)d_in[22];
  float* out = (float*)d_out;

  // workspace layout (~201 MB; proven available in R9/R11/R12)
  float*  A    = (float*)d_ws;                         // NN*128 f32 (hpre)
  float*  AGG  = A + (size_t)NN * 128;                 // NN*128 f32
  unsigned short* hb = (unsigned short*)(AGG + (size_t)NN * 128);  // NN*128 bf16
  unsigned short* xb = hb + (size_t)NN * 128;          // NN*32 bf16
  uint32* deg     = (uint32*)(xb + (size_t)NN * 32);   // NN
  uint32* cnt     = deg + NN;                          // NN
  uint32* toff    = cnt + NN;                          // NN
  uint32* eoff    = toff + NN;                         // NN
  ull*    counter = (ull*)(eoff + NN);                 // 1 (pad 2)
  int*    snode   = (int*)(counter + 2);               // TMAX
  uint2*  esrc2   = (uint2*)(snode + TMAX);            // NE + 128 pad
  float*  st0     = (float*)(esrc2 + NE + 128);        // 512
  float*  st1     = st0 + 512;                         // 512
  unsigned short* W1t0 = (unsigned short*)(st1 + 512); // 32*128
  unsigned short* W2t0 = W1t0 + 4096;                  // 128*128
  unsigned short* W1t1 = W2t0 + 16384;
  unsigned short* W2t1 = W1t1 + 16384;
  unsigned short* hW1t = W2t1 + 16384;
  unsigned short* Wet0 = hW1t + 16384;                 // 32*16
  unsigned short* Wet1 = Wet0 + 512;                   // 128*16
  unsigned short* eabc = Wet1 + 2048;                  // NE*16 bf16 (51.2 MB)

  const size_t needed = (size_t)((char*)(eabc + (size_t)NE * 16) - (char*)d_ws);
  if (ws_size < needed) return;

  hipMemsetAsync(deg, 0, (size_t)2 * NN * 4, stream);          // deg, cnt
  hipMemsetAsync(counter, 0, 16, stream);
  hipMemsetAsync(snode, 0xFF, (size_t)TMAX * 4, stream);
  hipMemsetAsync(st0, 0, 4096, stream);                        // st0 + st1
  hipMemsetAsync(AGG, 0, (size_t)NN * 32 * 4, stream);         // layer-0 agg

  const int nChunks = (NN + 63) / 64;     // 1563
  const int eBlocks = (NE + 255) / 256;   // 6250

  // one combined conversion launch (5 weights + 2 edge-W + x)
  conv_all<<<16 + 64 * 4 + 2 + 8 + 1563, 256, 0, stream>>>(
      l0W1, l0W2, l1W1, l1W2, hW1, l0We, l1We, x,
      W1t0, W2t0, W1t1, W2t1, hW1t, Wet0, Wet1, xb);

  // CSR build
  hist_kernel<<<eBlocks, 256, 0, stream>>>(ei, deg);
  offsets2_kernel<<<(NN + 255) / 256, 256, 0, stream>>>(deg, toff, eoff, counter);
  snode_fill<<<(NN + 255) / 256, 256, 0, stream>>>(toff, deg, snode);
  fill_kernel<<<eBlocks, 256, 0, stream>>>(ei, eoff, cnt, esrc2);

  // layer 0: gathers ea, packs, writes eabc (coalesced) for layer 1
  flat_agg6<32, 2, true><<<NRANGES / 4, 256, 0, stream>>>(
      snode, toff, eoff, deg, esrc2, ea, eabc, xb, Wet0, l0be, counter, AGG);
  mlp_mfma<32, false><<<782, 256, 0, stream>>>(x, (const unsigned short*)nullptr,
      AGG, W1t0, l0b1, W2t0, l0b2, A, st0, nChunks);
  hipMemsetAsync(AGG, 0, (size_t)NN * 128 * 4, stream);   // re-zero for layer 1
  bn_finalize<<<1, 128, 0, stream>>>(st0, l0g, l0bt);
  bn_apply_bf16<<<(NN * 32) / 256, 256, 0, stream>>>(A, st0, hb);

  // layer 1: consumes pre-packed eabc
  flat_agg6<128, 4, false><<<NRANGES / 2, 256, 0, stream>>>(
      snode, toff, eoff, deg, esrc2, ea, eabc, hb, Wet1, l1be, counter, AGG);
  mlp_mfma<128, true><<<782, 256, 0, stream>>>((const float*)nullptr, hb,
      AGG, W1t1, l1b1, W2t1, l1b2, A, st1, nChunks);
  bn_finalize<<<1, 128, 0, stream>>>(st1, l1g, l1bt);

  // fused BN-apply + head
  head_bn<<<782, 256, 0, stream>>>(A, st1, hW1t, hb1, hW2, hb2, out, nChunks);
}

// Round 14
// 554.499 us; speedup vs baseline: 1.0440x; 1.0440x over previous
//
#include <hip/hip_runtime.h>

#define NN 100000
#define NE 1600000
#define TMAX 193760           // >= sum ceil(deg/16) worst case (193750)
#define NRANGES 24220         // TMAX / 8

typedef unsigned int uint32;
typedef unsigned long long ull;
typedef __attribute__((ext_vector_type(8))) short bf16x8;
typedef __attribute__((ext_vector_type(4))) float f32x4;

__device__ __forceinline__ unsigned short f2bf(float f) {
  unsigned int u = __float_as_uint(f);
  unsigned int r = (u + 0x7fffu + ((u >> 16) & 1u)) >> 16;  // RNE
  return (unsigned short)r;
}
__device__ __forceinline__ float bf2f(unsigned short u) {
  return __uint_as_float(((unsigned int)u) << 16);
}
__device__ __forceinline__ unsigned int pack2(float a, float b) {
  return (unsigned int)f2bf(a) | ((unsigned int)f2bf(b) << 16);
}
// round-half-up pack of two f32 -> bf16 pair (cheap, ~= RNE for random data)
__device__ __forceinline__ uint32 pack2ru(float a, float b) {
  const uint32 ua = __float_as_uint(a) + 0x8000u;
  const uint32 ub = __float_as_uint(b) + 0x8000u;
  return (ua >> 16) | (ub & 0xffff0000u);
}
// sum over the 16 lanes of each DPP row via row_ror adds (pure VALU, no LDS)
__device__ __forceinline__ float row16_sum(float x) {
  x += __int_as_float(__builtin_amdgcn_mov_dpp(__float_as_int(x), 0x128, 0xf, 0xf, false));
  x += __int_as_float(__builtin_amdgcn_mov_dpp(__float_as_int(x), 0x124, 0xf, 0xf, false));
  x += __int_as_float(__builtin_amdgcn_mov_dpp(__float_as_int(x), 0x122, 0xf, 0xf, false));
  x += __int_as_float(__builtin_amdgcn_mov_dpp(__float_as_int(x), 0x121, 0xf, 0xf, false));
  return x;
}

// ---------------------------------------------------------------------------
// Combined weight/activation conversion (one launch).
// ---------------------------------------------------------------------------
__device__ __forceinline__ void wconv_body(const float* __restrict__ src,
    unsigned short* __restrict__ dst, int K, int N, int b)
{
  const int i = b * 256 + threadIdx.x;
  if (i < K * N) {
    const int n = i / K, k = i - n * K;
    dst[i] = f2bf(src[k * N + n]);
  }
}

__global__ __launch_bounds__(256) void conv_all(
    const float* __restrict__ l0W1, const float* __restrict__ l0W2,
    const float* __restrict__ l1W1, const float* __restrict__ l1W2,
    const float* __restrict__ hW1,  const float* __restrict__ l0We,
    const float* __restrict__ l1We, const float* __restrict__ x,
    unsigned short* __restrict__ W1t0, unsigned short* __restrict__ W2t0,
    unsigned short* __restrict__ W1t1, unsigned short* __restrict__ W2t1,
    unsigned short* __restrict__ hW1t, unsigned short* __restrict__ Wet0,
    unsigned short* __restrict__ Wet1, unsigned short* __restrict__ xb)
{
  int b = blockIdx.x;
  if (b < 16)  { wconv_body(l0W1, W1t0, 32, 128, b); return; }  b -= 16;
  if (b < 64)  { wconv_body(l0W2, W2t0, 128, 128, b); return; } b -= 64;
  if (b < 64)  { wconv_body(l1W1, W1t1, 128, 128, b); return; } b -= 64;
  if (b < 64)  { wconv_body(l1W2, W2t1, 128, 128, b); return; } b -= 64;
  if (b < 64)  { wconv_body(hW1,  hW1t, 128, 128, b); return; } b -= 64;
  if (b < 2)   { wconv_body(l0We, Wet0, 16, 32, b); return; }   b -= 2;
  if (b < 8)   { wconv_body(l1We, Wet1, 16, 128, b); return; }  b -= 8;
  const int i = b * 256 + threadIdx.x;
  if (i * 8 < NN * 32) {
    const float4 a = ((const float4*)x)[i * 2];
    const float4 d = ((const float4*)x)[i * 2 + 1];
    uint4 o;
    o.x = pack2(a.x, a.y); o.y = pack2(a.z, a.w);
    o.z = pack2(d.x, d.y); o.w = pack2(d.z, d.w);
    ((uint4*)xb)[i] = o;
  }
}

// ---------------------------------------------------------------------------
// CSR build: histogram -> dual prefix scan (tiles, edges) -> snode -> fill
// ---------------------------------------------------------------------------
__global__ __launch_bounds__(256) void hist_kernel(
    const int* __restrict__ ei, uint32* __restrict__ deg)
{
  const int e = blockIdx.x * 256 + threadIdx.x;
  if (e < NE) atomicAdd(&deg[ei[NE + e]], 1u);
}

__global__ __launch_bounds__(256) void offsets2_kernel(
    const uint32* __restrict__ deg, uint32* __restrict__ toff,
    uint32* __restrict__ eoff, ull* __restrict__ counter)
{
  __shared__ ull s[256];
  __shared__ ull base;
  const int tid = threadIdx.x;
  const int n = blockIdx.x * 256 + tid;
  const uint32 d = (n < NN) ? deg[n] : 0u;
  const uint32 tc = (d + 15u) >> 4;
  const ull v = ((ull)tc << 32) | (ull)d;
  s[tid] = v;
  __syncthreads();
#pragma unroll
  for (int st = 1; st < 256; st <<= 1) {
    ull w = (tid >= st) ? s[tid - st] : 0ull;
    __syncthreads();
    s[tid] += w;
    __syncthreads();
  }
  if (tid == 255) base = atomicAdd(counter, s[255]);
  __syncthreads();
  if (n < NN) {
    const ull t = base + (s[tid] - v);
    toff[n] = (uint32)(t >> 32);
    eoff[n] = (uint32)t;
  }
}

__global__ __launch_bounds__(256) void snode_fill(
    const uint32* __restrict__ toff, const uint32* __restrict__ deg,
    int* __restrict__ snode)
{
  const int n = blockIdx.x * 256 + threadIdx.x;
  if (n < NN) {
    const uint32 t0 = toff[n];
    const uint32 tc = (deg[n] + 15u) >> 4;
    for (uint32 i = 0; i < tc; ++i) snode[t0 + i] = n;
  }
}

// single light scatter: 8B (edge id, src) per dense slot
__global__ __launch_bounds__(256) void fill_kernel(
    const int* __restrict__ ei, const uint32* __restrict__ eoff,
    uint32* __restrict__ cnt, uint2* __restrict__ esrc2)
{
  const int e = blockIdx.x * 256 + threadIdx.x;
  if (e < NE) {
    const int dst = ei[NE + e];
    const uint32 pos = eoff[dst] + atomicAdd(&cnt[dst], 1u);
    esrc2[pos] = make_uint2((uint32)e, (uint32)ei[e]);
  }
}

// ---------------------------------------------------------------------------
// flat_agg7: padded-tile aggregate (R12 structure + 4-deep pipeline).
//  GEA=true  (layer 0): gather ea f32, pack bf16, WRITE eabc coalesced
//  GEA=false (layer 1): read pre-packed eabc (dense, coalesced/L3-warm)
//  MFMA with C=0; h added in VALU after; poison-validity A[k17]=-1e38
//  bulk esrc2 preload + shfl issue (R12); DPP flush; 4-deep pipeline
// ---------------------------------------------------------------------------
template<int D, int NCT, bool GEA>
__global__ __launch_bounds__(256) void flat_agg7(
    const int* __restrict__ snode, const uint32* __restrict__ toff,
    const uint32* __restrict__ eoff, const uint32* __restrict__ deg,
    const uint2* __restrict__ esrc2, const float* __restrict__ ea,
    unsigned short* __restrict__ eabc,
    const unsigned short* __restrict__ hsrc,
    const unsigned short* __restrict__ Wet, const float* __restrict__ be,
    const ull* __restrict__ tot, float* __restrict__ agg)
{
  const int tid = threadIdx.x;
  const int wid = tid >> 6;
  const int lane = tid & 63;
  const int c = lane & 15;
  const int g = lane >> 4;
  constexpr bool HALF = (NCT * 16 != D);
  int range, ch0;
  if (HALF) { range = blockIdx.x * 2 + (wid >> 1); ch0 = (wid & 1) * (NCT * 16); }
  else      { range = blockIdx.x * 4 + wid;        ch0 = 0; }
  const int tile0 = range * 8;
  const uint32 ntile = (uint32)((*tot) >> 32);
  if ((uint32)tile0 >= ntile) return;   // dead range

  // W fragments; A row r <-> channel ch0 + (r>>2)*(4NCT) + ct*4 + (r&3)
  // k=16 carries be (B k16=1.0); k=17 carries -1e38 (B k17=1.0 iff invalid)
  bf16x8 wf[NCT];
#pragma unroll
  for (int ct = 0; ct < NCT; ++ct) {
    const int chA = ch0 + (c >> 2) * (NCT * 4) + ct * 4 + (c & 3);
    uint4 u = make_uint4(0u, 0u, 0u, 0u);
    if (g < 2) u = *(const uint4*)&Wet[chA * 16 + g * 8];
    else if (g == 2) u.x = (0xFE96u << 16) | (uint32)f2bf(be[chA]);
    union { uint4 u4; bf16x8 v; } cv; cv.u4 = u;
    wf[ct] = cv.v;
  }

  // per-tile metadata on lanes 0..7: pk = d0(7b) | rem(5b,<=16) | flags(2b)
  int sn8 = -1, pk8 = 0, p_ = 0;
  if (lane < 8) {
    sn8 = snode[tile0 + lane];
    if (sn8 >= 0) {
      const uint32 to = toff[sn8], dg = deg[sn8], eo = eoff[sn8];
      const int k = tile0 + lane - (int)to;
      p_ = (int)eo + k * 16;
      int rv = (int)dg - k * 16; if (rv > 16) rv = 16;
      const int fl = (k == 0 ? 1 : 0) |
                     ((k == (int)((dg + 15u) >> 4) - 1) ? 2 : 0);
      pk8 = (rv << 7) | (fl << 12);
    }
  }
  const int p0base = __shfl(p_, 0);   // lane 0 (tile0) is always real
  if (lane < 8 && sn8 >= 0) pk8 |= (p_ - p0base);

  // bulk preload: range spans <= 128 dense slots starting at p0base
  const uint2 q0 = esrc2[(size_t)p0base + lane];
  const uint2 q1 = esrc2[(size_t)p0base + 64 + lane];

  float acc[NCT][4];
#pragma unroll
  for (int ct = 0; ct < NCT; ++ct) {
    acc[ct][0] = 0.f; acc[ct][1] = 0.f; acc[ct][2] = 0.f; acc[ct][3] = 0.f;
  }
  int openNode = -1; bool openFull = false, openClosed = false;

  auto flushOpen = [&](bool storeOK) {
#pragma unroll
    for (int ct = 0; ct < NCT; ++ct)
#pragma unroll
      for (int j = 0; j < 4; ++j)
        acc[ct][j] = row16_sum(acc[ct][j]);
    float4 sv = make_float4(0.f, 0.f, 0.f, 0.f);
#pragma unroll
    for (int ct = 0; ct < NCT; ++ct)
      if (c == ct)
        sv = make_float4(acc[ct][0], acc[ct][1], acc[ct][2], acc[ct][3]);
    if (c < NCT) {
      float* p = &agg[(size_t)openNode * D + ch0 + g * (NCT * 4) + c * 4];
      if (storeOK) {
        *(float4*)p = sv;
      } else {
        atomicAdd(p + 0, sv.x); atomicAdd(p + 1, sv.y);
        atomicAdd(p + 2, sv.z); atomicAdd(p + 3, sv.w);
      }
    }
  };

  auto issue = [&](int t, float4& E0, float4& E1, uint4& afu,
                   uint4& h0, uint4& h1, int& n_, int& mt_) {
    n_ = __shfl(sn8, t);
    mt_ = __shfl(pk8, t);
    const int d0 = mt_ & 127;
    const int rem = (mt_ >> 7) & 31;
    const int idx = d0 + ((c < rem) ? c : 0);
    const int li = idx & 63;
    const uint32 sA = (uint32)__shfl((int)q0.y, li);
    const uint32 sB = (uint32)__shfl((int)q1.y, li);
    const int src = (int)((idx & 64) ? sB : sA);
    if constexpr (GEA) {
      const uint32 eA = (uint32)__shfl((int)q0.x, li);
      const uint32 eB = (uint32)__shfl((int)q1.x, li);
      const int e = (int)((idx & 64) ? eB : eA);
      if (g < 2) {
        E0 = *(const float4*)&ea[(size_t)e * 16 + g * 8];
        E1 = *(const float4*)&ea[(size_t)e * 16 + g * 8 + 4];
      }
    } else {
      if (g < 2) afu = *(const uint4*)&eabc[((size_t)p0base + idx) * 16 + g * 8];
    }
    h0 = *(const uint4*)&hsrc[(size_t)src * D + ch0 + g * (NCT * 4)];
    if constexpr (NCT == 4)
      h1 = *(const uint4*)&hsrc[(size_t)src * D + ch0 + g * (NCT * 4) + 8];
  };

  auto compute = [&](const float4 E0, const float4 E1, uint4 afu,
                     const uint4 h0, const uint4 h1, const int n, const int mt) {
    if (n < 0) return;
    const int rem = (mt >> 7) & 31;
    const int fl = mt >> 12;
    if (n != openNode) {
      if (openNode >= 0) {
        flushOpen(openFull);
#pragma unroll
        for (int ct = 0; ct < NCT; ++ct) {
          acc[ct][0] = 0.f; acc[ct][1] = 0.f;
          acc[ct][2] = 0.f; acc[ct][3] = 0.f;
        }
      }
      openNode = n; openFull = (fl & 1) != 0; openClosed = false;
    }
    if (fl & 2) openClosed = true;
    if constexpr (GEA) {
      afu.x = pack2ru(E0.x, E0.y); afu.y = pack2ru(E0.z, E0.w);
      afu.z = pack2ru(E1.x, E1.y); afu.w = pack2ru(E1.z, E1.w);
      if (g < 2) {
        const int d0 = mt & 127;
        const int idx = d0 + ((c < rem) ? c : 0);
        *(uint4*)&eabc[((size_t)p0base + idx) * 16 + g * 8] = afu;
      }
    }
    bf16x8 afv;
    {
      uint4 u = make_uint4(0u, 0u, 0u, 0u);
      if (g < 2) u = afu;
      else if (g == 2) u.x = (c < rem) ? 0x3f80u : 0x3f803f80u;
      union { uint4 u4; bf16x8 v; } cv; cv.u4 = u; afv = cv.v;
    }
#pragma unroll
    for (int ct = 0; ct < NCT; ++ct) {
      f32x4 pre = __builtin_amdgcn_mfma_f32_16x16x32_bf16(
          wf[ct], afv, (f32x4){0.f, 0.f, 0.f, 0.f}, 0, 0, 0);
      uint32 w0, w1;
      if constexpr (NCT == 4) {
        const uint4 hu = (ct < 2) ? h0 : h1;
        w0 = (ct & 1) ? hu.z : hu.x;
        w1 = (ct & 1) ? hu.w : hu.y;
      } else {
        w0 = (ct & 1) ? h0.z : h0.x;
        w1 = (ct & 1) ? h0.w : h0.y;
      }
      acc[ct][0] += fmaxf(pre[0] + bf2f((unsigned short)(w0 & 0xffffu)), 0.f);
      acc[ct][1] += fmaxf(pre[1] + bf2f((unsigned short)(w0 >> 16)), 0.f);
      acc[ct][2] += fmaxf(pre[2] + bf2f((unsigned short)(w1 & 0xffffu)), 0.f);
      acc[ct][3] += fmaxf(pre[3] + bf2f((unsigned short)(w1 >> 16)), 0.f);
    }
  };

  float4 eA0, eA1, eB0, eB1, eC0, eC1, eD0, eD1;
  uint4 aA = make_uint4(0,0,0,0), aB = make_uint4(0,0,0,0);
  uint4 aC = make_uint4(0,0,0,0), aD = make_uint4(0,0,0,0);
  uint4 h0A = make_uint4(0,0,0,0), h1A = make_uint4(0,0,0,0);
  uint4 h0B = make_uint4(0,0,0,0), h1B = make_uint4(0,0,0,0);
  uint4 h0C = make_uint4(0,0,0,0), h1C = make_uint4(0,0,0,0);
  uint4 h0D = make_uint4(0,0,0,0), h1D = make_uint4(0,0,0,0);
  int nA = -1, mA = 0, nB = -1, mB = 0, nC = -1, mC = 0, nD = -1, mD = 0;

  // 4-deep pipeline: 3 tiles of loads in flight ahead of each compute
  issue(0, eA0, eA1, aA, h0A, h1A, nA, mA);
  issue(1, eB0, eB1, aB, h0B, h1B, nB, mB);
  issue(2, eC0, eC1, aC, h0C, h1C, nC, mC);
  issue(3, eD0, eD1, aD, h0D, h1D, nD, mD);
  compute(eA0, eA1, aA, h0A, h1A, nA, mA); issue(4, eA0, eA1, aA, h0A, h1A, nA, mA);
  compute(eB0, eB1, aB, h0B, h1B, nB, mB); issue(5, eB0, eB1, aB, h0B, h1B, nB, mB);
  compute(eC0, eC1, aC, h0C, h1C, nC, mC); issue(6, eC0, eC1, aC, h0C, h1C, nC, mC);
  compute(eD0, eD1, aD, h0D, h1D, nD, mD); issue(7, eD0, eD1, aD, h0D, h1D, nD, mD);
  compute(eA0, eA1, aA, h0A, h1A, nA, mA);
  compute(eB0, eB1, aB, h0B, h1B, nB, mB);
  compute(eC0, eC1, aC, h0C, h1C, nC, mC);
  compute(eD0, eD1, aD, h0D, h1D, nD, mD);
  if (openNode >= 0) flushOpen(openFull && openClosed);
}

// ---------------------------------------------------------------------------
// MFMA node MLP: out = relu((a+agg)@W1+b1)@W2+b2, + BN stats.
// ---------------------------------------------------------------------------
template<int DIN, bool ABF16>
__global__ __launch_bounds__(256) void mlp_mfma(
    const float* __restrict__ a32, const unsigned short* __restrict__ abf,
    const float* __restrict__ agg,
    const unsigned short* __restrict__ W1t, const float* __restrict__ b1,
    const unsigned short* __restrict__ W2t, const float* __restrict__ b2,
    float* __restrict__ outp, float* __restrict__ stats, int nChunks)
{
  constexpr int P1 = (DIN == 128) ? 136 : 40;
  constexpr int KS1 = DIN / 32;
  __shared__ __align__(16) unsigned short hin[64 * P1];
  __shared__ __align__(16) unsigned short tls[64 * 136];
  const int tid = threadIdx.x;
  const int w = tid >> 6;
  const int lane = tid & 63;
  const int c = lane & 15, g = lane >> 4;
  const int cw = w * 32;

  bf16x8 B1[2][KS1], B2[2][4];
#pragma unroll
  for (int ct = 0; ct < 2; ++ct)
#pragma unroll
    for (int kk = 0; kk < KS1; ++kk)
      B1[ct][kk] = *(const bf16x8*)&W1t[(cw + ct * 16 + c) * DIN + kk * 32 + g * 8];
#pragma unroll
  for (int ct = 0; ct < 2; ++ct)
#pragma unroll
    for (int kk = 0; kk < 4; ++kk)
      B2[ct][kk] = *(const bf16x8*)&W2t[(cw + ct * 16 + c) * 128 + kk * 32 + g * 8];
  const float b1c0 = b1[cw + c], b1c1 = b1[cw + 16 + c];
  const float b2c0 = b2[cw + c], b2c1 = b2[cw + 16 + c];
  float lsum0 = 0.f, lsum1 = 0.f, lsq0 = 0.f, lsq1 = 0.f;

  for (int chunk = blockIdx.x; chunk < nChunks; chunk += gridDim.x) {
    const int base = chunk * 64;
    if constexpr (DIN == 128) {
#pragma unroll
      for (int p = 0; p < 4; ++p) {
        const int idx = tid + 256 * p;
        const int n = idx >> 4, k8 = idx & 15;
        const int node = base + n;
        uint4 ov = make_uint4(0u, 0u, 0u, 0u);
        if (node < NN) {
          const float4 g0 = *(const float4*)&agg[node * 128 + k8 * 8];
          const float4 g1 = *(const float4*)&agg[node * 128 + k8 * 8 + 4];
          const uint4 hv = *(const uint4*)&abf[node * 128 + k8 * 8];
          ov.x = pack2(bf2f((unsigned short)(hv.x & 0xffffu)) + g0.x,
                       bf2f((unsigned short)(hv.x >> 16)) + g0.y);
          ov.y = pack2(bf2f((unsigned short)(hv.y & 0xffffu)) + g0.z,
                       bf2f((unsigned short)(hv.y >> 16)) + g0.w);
          ov.z = pack2(bf2f((unsigned short)(hv.z & 0xffffu)) + g1.x,
                       bf2f((unsigned short)(hv.z >> 16)) + g1.y);
          ov.w = pack2(bf2f((unsigned short)(hv.w & 0xffffu)) + g1.z,
                       bf2f((unsigned short)(hv.w >> 16)) + g1.w);
        }
        *(uint4*)&hin[n * P1 + k8 * 8] = ov;
      }
    } else {
      const int n = tid >> 2, k8 = tid & 3;
      const int node = base + n;
      uint4 ov = make_uint4(0u, 0u, 0u, 0u);
      if (node < NN) {
        const float4 x0 = *(const float4*)&a32[node * 32 + k8 * 8];
        const float4 x1 = *(const float4*)&a32[node * 32 + k8 * 8 + 4];
        const float4 g0 = *(const float4*)&agg[node * 32 + k8 * 8];
        const float4 g1 = *(const float4*)&agg[node * 32 + k8 * 8 + 4];
        ov.x = pack2(x0.x + g0.x, x0.y + g0.y);
        ov.y = pack2(x0.z + g0.z, x0.w + g0.w);
        ov.z = pack2(x1.x + g1.x, x1.y + g1.y);
        ov.w = pack2(x1.z + g1.z, x1.w + g1.w);
      }
      *(uint4*)&hin[n * P1 + k8 * 8] = ov;
    }
    __syncthreads();
#pragma unroll
    for (int nt = 0; nt < 4; ++nt) {
      bf16x8 af[KS1];
#pragma unroll
      for (int kk = 0; kk < KS1; ++kk)
        af[kk] = *(const bf16x8*)&hin[(nt * 16 + c) * P1 + kk * 32 + g * 8];
      f32x4 acc0 = {0.f, 0.f, 0.f, 0.f}, acc1 = {0.f, 0.f, 0.f, 0.f};
#pragma unroll
      for (int kk = 0; kk < KS1; ++kk) {
        acc0 = __builtin_amdgcn_mfma_f32_16x16x32_bf16(af[kk], B1[0][kk], acc0, 0, 0, 0);
        acc1 = __builtin_amdgcn_mfma_f32_16x16x32_bf16(af[kk], B1[1][kk], acc1, 0, 0, 0);
      }
#pragma unroll
      for (int j = 0; j < 4; ++j) {
        const int row = nt * 16 + g * 4 + j;
        tls[row * 136 + cw + c]      = f2bf(fmaxf(acc0[j] + b1c0, 0.f));
        tls[row * 136 + cw + 16 + c] = f2bf(fmaxf(acc1[j] + b1c1, 0.f));
      }
    }
    __syncthreads();
#pragma unroll
    for (int nt = 0; nt < 4; ++nt) {
      bf16x8 af[4];
#pragma unroll
      for (int kk = 0; kk < 4; ++kk)
        af[kk] = *(const bf16x8*)&tls[(nt * 16 + c) * 136 + kk * 32 + g * 8];
      f32x4 acc0 = {0.f, 0.f, 0.f, 0.f}, acc1 = {0.f, 0.f, 0.f, 0.f};
#pragma unroll
      for (int kk = 0; kk < 4; ++kk) {
        acc0 = __builtin_amdgcn_mfma_f32_16x16x32_bf16(af[kk], B2[0][kk], acc0, 0, 0, 0);
        acc1 = __builtin_amdgcn_mfma_f32_16x16x32_bf16(af[kk], B2[1][kk], acc1, 0, 0, 0);
      }
#pragma unroll
      for (int j = 0; j < 4; ++j) {
        const int node = base + nt * 16 + g * 4 + j;
        if (node < NN) {
          const float v0 = acc0[j] + b2c0;
          const float v1 = acc1[j] + b2c1;
          outp[node * 128 + cw + c] = v0;
          outp[node * 128 + cw + 16 + c] = v1;
          lsum0 += v0; lsq0 += v0 * v0;
          lsum1 += v1; lsq1 += v1 * v1;
        }
      }
    }
  }
  lsum0 += __shfl_xor(lsum0, 16); lsum0 += __shfl_xor(lsum0, 32);
  lsum1 += __shfl_xor(lsum1, 16); lsum1 += __shfl_xor(lsum1, 32);
  lsq0  += __shfl_xor(lsq0, 16);  lsq0  += __shfl_xor(lsq0, 32);
  lsq1  += __shfl_xor(lsq1, 16);  lsq1  += __shfl_xor(lsq1, 32);
  if (lane < 16) {
    atomicAdd(&stats[cw + lane], lsum0);
    atomicAdd(&stats[cw + 16 + lane], lsum1);
    atomicAdd(&stats[128 + cw + lane], lsq0);
    atomicAdd(&stats[128 + cw + 16 + lane], lsq1);
  }
}

__global__ void bn_finalize(float* __restrict__ stats,
                            const float* __restrict__ gamma,
                            const float* __restrict__ beta)
{
  const int cc = threadIdx.x;
  const float inv_n = 1.0f / (float)NN;
  const float mu = stats[cc] * inv_n;
  float var = stats[128 + cc] * inv_n - mu * mu;
  var = fmaxf(var, 0.f);
  const float rs = rsqrtf(var + 1e-5f);
  const float sc = rs * gamma[cc];
  stats[256 + cc] = sc;
  stats[384 + cc] = beta[cc] - mu * sc;
}

__global__ __launch_bounds__(256) void bn_apply_bf16(
    const float* __restrict__ h, const float* __restrict__ stats,
    unsigned short* __restrict__ hb)
{
  const int idx = blockIdx.x * 256 + threadIdx.x;
  const int c4 = (idx & 31) * 4;
  const float4 sc = *(const float4*)&stats[256 + c4];
  const float4 sh = *(const float4*)&stats[384 + c4];
  const float4 v = ((const float4*)h)[idx];
  const float r0 = fmaxf(fmaf(v.x, sc.x, sh.x), 0.f);
  const float r1 = fmaxf(fmaf(v.y, sc.y, sh.y), 0.f);
  const float r2 = fmaxf(fmaf(v.z, sc.z, sh.z), 0.f);
  const float r3 = fmaxf(fmaf(v.w, sc.w, sh.w), 0.f);
  uint2 o;
  o.x = pack2(r0, r1);
  o.y = pack2(r2, r3);
  ((uint2*)hb)[idx] = o;
}

// ---------------------------------------------------------------------------
// Fused BN-apply + head: out = sigmoid(relu(relu(hpre*sc+sh)@W1+b1)@w2 + b2)
// ---------------------------------------------------------------------------
__global__ __launch_bounds__(256) void head_bn(
    const float* __restrict__ hpre, const float* __restrict__ stats,
    const unsigned short* __restrict__ W1t, const float* __restrict__ b1,
    const float* __restrict__ w2, const float* __restrict__ b2,
    float* __restrict__ out, int nChunks)
{
  __shared__ float pl[4][64];
  const int tid = threadIdx.x;
  const int w = tid >> 6;
  const int lane = tid & 63;
  const int c = lane & 15, g = lane >> 4;
  const int cw = w * 32;

  bf16x8 B1[2][4];
#pragma unroll
  for (int ct = 0; ct < 2; ++ct)
#pragma unroll
    for (int kk = 0; kk < 4; ++kk)
      B1[ct][kk] = *(const bf16x8*)&W1t[(cw + ct * 16 + c) * 128 + kk * 32 + g * 8];
  const float b1c0 = b1[cw + c], b1c1 = b1[cw + 16 + c];
  const float w2c0 = w2[cw + c], w2c1 = w2[cw + 16 + c];
  const float b2v = b2[0];
  float4 scq[4][2], shq[4][2];
#pragma unroll
  for (int kk = 0; kk < 4; ++kk) {
    const int cb = kk * 32 + g * 8;
    scq[kk][0] = *(const float4*)&stats[256 + cb];
    scq[kk][1] = *(const float4*)&stats[256 + cb + 4];
    shq[kk][0] = *(const float4*)&stats[384 + cb];
    shq[kk][1] = *(const float4*)&stats[384 + cb + 4];
  }

  for (int chunk = blockIdx.x; chunk < nChunks; chunk += gridDim.x) {
    const int base = chunk * 64;
    float p[4][4];
#pragma unroll
    for (int nt = 0; nt < 4; ++nt) {
      const int node = base + nt * 16 + c;
      bf16x8 af[4];
#pragma unroll
      for (int kk = 0; kk < 4; ++kk) {
        uint4 u = make_uint4(0u, 0u, 0u, 0u);
        if (node < NN) {
          const float4 v0 = *(const float4*)&hpre[(size_t)node * 128 + kk * 32 + g * 8];
          const float4 v1 = *(const float4*)&hpre[(size_t)node * 128 + kk * 32 + g * 8 + 4];
          const float4 s0 = scq[kk][0], s1 = scq[kk][1];
          const float4 h0 = shq[kk][0], h1 = shq[kk][1];
          u.x = pack2(fmaxf(fmaf(v0.x, s0.x, h0.x), 0.f),
                      fmaxf(fmaf(v0.y, s0.y, h0.y), 0.f));
          u.y = pack2(fmaxf(fmaf(v0.z, s0.z, h0.z), 0.f),
                      fmaxf(fmaf(v0.w, s0.w, h0.w), 0.f));
          u.z = pack2(fmaxf(fmaf(v1.x, s1.x, h1.x), 0.f),
                      fmaxf(fmaf(v1.y, s1.y, h1.y), 0.f));
          u.w = pack2(fmaxf(fmaf(v1.z, s1.z, h1.z), 0.f),
                      fmaxf(fmaf(v1.w, s1.w, h1.w), 0.f));
        }
        union { uint4 u4; bf16x8 v; } cv; cv.u4 = u;
        af[kk] = cv.v;
      }
      f32x4 acc0 = {0.f, 0.f, 0.f, 0.f}, acc1 = {0.f, 0.f, 0.f, 0.f};
#pragma unroll
      for (int kk = 0; kk < 4; ++kk) {
        acc0 = __builtin_amdgcn_mfma_f32_16x16x32_bf16(af[kk], B1[0][kk], acc0, 0, 0, 0);
        acc1 = __builtin_amdgcn_mfma_f32_16x16x32_bf16(af[kk], B1[1][kk], acc1, 0, 0, 0);
      }
#pragma unroll
      for (int j = 0; j < 4; ++j)
        p[nt][j] = fmaxf(acc0[j] + b1c0, 0.f) * w2c0 +
                   fmaxf(acc1[j] + b1c1, 0.f) * w2c1;
    }
#pragma unroll
    for (int dd = 1; dd <= 8; dd <<= 1)
#pragma unroll
      for (int nt = 0; nt < 4; ++nt)
#pragma unroll
        for (int j = 0; j < 4; ++j)
          p[nt][j] += __shfl_xor(p[nt][j], dd);
    if (c == 0) {
#pragma unroll
      for (int nt = 0; nt < 4; ++nt)
#pragma unroll
        for (int j = 0; j < 4; ++j)
          pl[w][nt * 16 + g * 4 + j] = p[nt][j];
    }
    __syncthreads();
    if (tid < 64) {
      const int node = base + tid;
      if (node < NN) {
        const float s = pl[0][tid] + pl[1][tid] + pl[2][tid] + pl[3][tid] + b2v;
        out[node] = 1.f / (1.f + expf(-s));
      }
    }
    __syncthreads();
  }
}

extern "C" void kernel_launch(void* const* d_in, const int* in_sizes, int n_in,
                              void* d_out, int out_size, void* d_ws, size_t ws_size,
                              hipStream_t stream)
{
  const float* x    = (const float*)d_in[0];
  const int*   ei   = (const int*)  d_in[1];
  const float* ea   = (const float*)d_in[2];
  const float* l0We = (const float*)d_in[3];
  const float* l0be = (const float*)d_in[4];
  const float* l0W1 = (const float*)d_in[5];
  const float* l0b1 = (const float*)d_in[6];
  const float* l0W2 = (const float*)d_in[7];
  const float* l0b2 = (const float*)d_in[8];
  const float* l0g  = (const float*)d_in[9];
  const float* l0bt = (const float*)d_in[10];
  const float* l1We = (const float*)d_in[11];
  const float* l1be = (const float*)d_in[12];
  const float* l1W1 = (const float*)d_in[13];
  const float* l1b1 = (const float*)d_in[14];
  const float* l1W2 = (const float*)d_in[15];
  const float* l1b2 = (const float*)d_in[16];
  const float* l1g  = (const float*)d_in[17];
  const float* l1bt = (const float*)d_in[18];
  const float* hW1  = (const float*)d_in[19];
  const float* hb1  = (const float*)d_in[20];
  const float* hW2  = (const float*)d_in[21];
  const float* hb2  = (const float*)d_in[22];
  float* out = (float*)d_out;

  // workspace layout (~201 MB; proven available in R9/R11/R12)
  float*  A    = (float*)d_ws;                         // NN*128 f32 (hpre)
  float*  AGG  = A + (size_t)NN * 128;                 // NN*128 f32
  unsigned short* hb = (unsigned short*)(AGG + (size_t)NN * 128);  // NN*128 bf16
  unsigned short* xb = hb + (size_t)NN * 128;          // NN*32 bf16
  uint32* deg     = (uint32*)(xb + (size_t)NN * 32);   // NN
  uint32* cnt     = deg + NN;                          // NN
  uint32* toff    = cnt + NN;                          // NN
  uint32* eoff    = toff + NN;                         // NN
  ull*    counter = (ull*)(eoff + NN);                 // 1 (pad 2)
  int*    snode   = (int*)(counter + 2);               // TMAX
  uint2*  esrc2   = (uint2*)(snode + TMAX);            // NE + 128 pad
  float*  st0     = (float*)(esrc2 + NE + 128);        // 512
  float*  st1     = st0 + 512;                         // 512
  unsigned short* W1t0 = (unsigned short*)(st1 + 512); // 32*128
  unsigned short* W2t0 = W1t0 + 4096;                  // 128*128
  unsigned short* W1t1 = W2t0 + 16384;
  unsigned short* W2t1 = W1t1 + 16384;
  unsigned short* hW1t = W2t1 + 16384;
  unsigned short* Wet0 = hW1t + 16384;                 // 32*16
  unsigned short* Wet1 = Wet0 + 512;                   // 128*16
  unsigned short* eabc = Wet1 + 2048;                  // NE*16 bf16 (51.2 MB)

  const size_t needed = (size_t)((char*)(eabc + (size_t)NE * 16) - (char*)d_ws);
  if (ws_size < needed) return;

  hipMemsetAsync(deg, 0, (size_t)2 * NN * 4, stream);          // deg, cnt
  hipMemsetAsync(counter, 0, 16, stream);
  hipMemsetAsync(snode, 0xFF, (size_t)TMAX * 4, stream);
  hipMemsetAsync(st0, 0, 4096, stream);                        // st0 + st1
  hipMemsetAsync(AGG, 0, (size_t)NN * 32 * 4, stream);         // layer-0 agg

  const int nChunks = (NN + 63) / 64;     // 1563
  const int eBlocks = (NE + 255) / 256;   // 6250

  // one combined conversion launch (5 weights + 2 edge-W + x)
  conv_all<<<16 + 64 * 4 + 2 + 8 + 1563, 256, 0, stream>>>(
      l0W1, l0W2, l1W1, l1W2, hW1, l0We, l1We, x,
      W1t0, W2t0, W1t1, W2t1, hW1t, Wet0, Wet1, xb);

  // CSR build
  hist_kernel<<<eBlocks, 256, 0, stream>>>(ei, deg);
  offsets2_kernel<<<(NN + 255) / 256, 256, 0, stream>>>(deg, toff, eoff, counter);
  snode_fill<<<(NN + 255) / 256, 256, 0, stream>>>(toff, deg, snode);
  fill_kernel<<<eBlocks, 256, 0, stream>>>(ei, eoff, cnt, esrc2);

  // layer 0: gathers ea, packs, writes eabc (coalesced) for layer 1
  flat_agg7<32, 2, true><<<NRANGES / 4, 256, 0, stream>>>(
      snode, toff, eoff, deg, esrc2, ea, eabc, xb, Wet0, l0be, counter, AGG);
  mlp_mfma<32, false><<<782, 256, 0, stream>>>(x, (const unsigned short*)nullptr,
      AGG, W1t0, l0b1, W2t0, l0b2, A, st0, nChunks);
  hipMemsetAsync(AGG, 0, (size_t)NN * 128 * 4, stream);   // re-zero for layer 1
  bn_finalize<<<1, 128, 0, stream>>>(st0, l0g, l0bt);
  bn_apply_bf16<<<(NN * 32) / 256, 256, 0, stream>>>(A, st0, hb);

  // layer 1: consumes pre-packed eabc
  flat_agg7<128, 4, false><<<NRANGES / 2, 256, 0, stream>>>(
      snode, toff, eoff, deg, esrc2, ea, eabc, hb, Wet1, l1be, counter, AGG);
  mlp_mfma<128, true><<<782, 256, 0, stream>>>((const float*)nullptr, hb,
      AGG, W1t1, l1b1, W2t1, l1b2, A, st1, nChunks);
  bn_finalize<<<1, 128, 0, stream>>>(st1, l1g, l1bt);

  // fused BN-apply + head
  head_bn<<<782, 256, 0, stream>>>(A, st1, hW1t, hb1, hW2, hb2, out, nChunks);
}

// Round 15
// 541.284 us; speedup vs baseline: 1.0695x; 1.0244x over previous
//
#include <hip/hip_runtime.h>

#define NN 100000
#define NE 1600000
#define TMAX 193760           // >= sum ceil(deg/16) worst case (193750)
#define NRANGES 24220         // TMAX / 8

typedef unsigned int uint32;
typedef unsigned long long ull;
typedef __attribute__((ext_vector_type(8))) short bf16x8;
typedef __attribute__((ext_vector_type(4))) float f32x4;

__device__ __forceinline__ unsigned short f2bf(float f) {
  unsigned int u = __float_as_uint(f);
  unsigned int r = (u + 0x7fffu + ((u >> 16) & 1u)) >> 16;  // RNE
  return (unsigned short)r;
}
__device__ __forceinline__ float bf2f(unsigned short u) {
  return __uint_as_float(((unsigned int)u) << 16);
}
__device__ __forceinline__ unsigned int pack2(float a, float b) {
  return (unsigned int)f2bf(a) | ((unsigned int)f2bf(b) << 16);
}
// round-half-up pack of two f32 -> bf16 pair (cheap, ~= RNE for random data)
__device__ __forceinline__ uint32 pack2ru(float a, float b) {
  const uint32 ua = __float_as_uint(a) + 0x8000u;
  const uint32 ub = __float_as_uint(b) + 0x8000u;
  return (ua >> 16) | (ub & 0xffff0000u);
}

// ---------------------------------------------------------------------------
// Combined weight/activation conversion (one launch).
// ---------------------------------------------------------------------------
__device__ __forceinline__ void wconv_body(const float* __restrict__ src,
    unsigned short* __restrict__ dst, int K, int N, int b)
{
  const int i = b * 256 + threadIdx.x;
  if (i < K * N) {
    const int n = i / K, k = i - n * K;
    dst[i] = f2bf(src[k * N + n]);
  }
}

__global__ __launch_bounds__(256) void conv_all(
    const float* __restrict__ l0W1, const float* __restrict__ l0W2,
    const float* __restrict__ l1W1, const float* __restrict__ l1W2,
    const float* __restrict__ hW1,  const float* __restrict__ l0We,
    const float* __restrict__ l1We, const float* __restrict__ x,
    unsigned short* __restrict__ W1t0, unsigned short* __restrict__ W2t0,
    unsigned short* __restrict__ W1t1, unsigned short* __restrict__ W2t1,
    unsigned short* __restrict__ hW1t, unsigned short* __restrict__ Wet0,
    unsigned short* __restrict__ Wet1, unsigned short* __restrict__ xb)
{
  int b = blockIdx.x;
  if (b < 16)  { wconv_body(l0W1, W1t0, 32, 128, b); return; }  b -= 16;
  if (b < 64)  { wconv_body(l0W2, W2t0, 128, 128, b); return; } b -= 64;
  if (b < 64)  { wconv_body(l1W1, W1t1, 128, 128, b); return; } b -= 64;
  if (b < 64)  { wconv_body(l1W2, W2t1, 128, 128, b); return; } b -= 64;
  if (b < 64)  { wconv_body(hW1,  hW1t, 128, 128, b); return; } b -= 64;
  if (b < 2)   { wconv_body(l0We, Wet0, 16, 32, b); return; }   b -= 2;
  if (b < 8)   { wconv_body(l1We, Wet1, 16, 128, b); return; }  b -= 8;
  const int i = b * 256 + threadIdx.x;
  if (i * 8 < NN * 32) {
    const float4 a = ((const float4*)x)[i * 2];
    const float4 d = ((const float4*)x)[i * 2 + 1];
    uint4 o;
    o.x = pack2(a.x, a.y); o.y = pack2(a.z, a.w);
    o.z = pack2(d.x, d.y); o.w = pack2(d.z, d.w);
    ((uint4*)xb)[i] = o;
  }
}

// ---------------------------------------------------------------------------
// CSR build: histogram -> dual prefix scan (tiles, edges) -> snode -> fill
// ---------------------------------------------------------------------------
__global__ __launch_bounds__(256) void hist_kernel(
    const int* __restrict__ ei, uint32* __restrict__ deg)
{
  const int e = blockIdx.x * 256 + threadIdx.x;
  if (e < NE) atomicAdd(&deg[ei[NE + e]], 1u);
}

__global__ __launch_bounds__(256) void offsets2_kernel(
    const uint32* __restrict__ deg, uint32* __restrict__ toff,
    uint32* __restrict__ eoff, ull* __restrict__ counter)
{
  __shared__ ull s[256];
  __shared__ ull base;
  const int tid = threadIdx.x;
  const int n = blockIdx.x * 256 + tid;
  const uint32 d = (n < NN) ? deg[n] : 0u;
  const uint32 tc = (d + 15u) >> 4;
  const ull v = ((ull)tc << 32) | (ull)d;
  s[tid] = v;
  __syncthreads();
#pragma unroll
  for (int st = 1; st < 256; st <<= 1) {
    ull w = (tid >= st) ? s[tid - st] : 0ull;
    __syncthreads();
    s[tid] += w;
    __syncthreads();
  }
  if (tid == 255) base = atomicAdd(counter, s[255]);
  __syncthreads();
  if (n < NN) {
    const ull t = base + (s[tid] - v);
    toff[n] = (uint32)(t >> 32);
    eoff[n] = (uint32)t;
  }
}

__global__ __launch_bounds__(256) void snode_fill(
    const uint32* __restrict__ toff, const uint32* __restrict__ deg,
    int* __restrict__ snode)
{
  const int n = blockIdx.x * 256 + threadIdx.x;
  if (n < NN) {
    const uint32 t0 = toff[n];
    const uint32 tc = (deg[n] + 15u) >> 4;
    for (uint32 i = 0; i < tc; ++i) snode[t0 + i] = n;
  }
}

// single light scatter: 8B (edge id, src) per dense slot
__global__ __launch_bounds__(256) void fill_kernel(
    const int* __restrict__ ei, const uint32* __restrict__ eoff,
    uint32* __restrict__ cnt, uint2* __restrict__ esrc2)
{
  const int e = blockIdx.x * 256 + threadIdx.x;
  if (e < NE) {
    const int dst = ei[NE + e];
    const uint32 pos = eoff[dst] + atomicAdd(&cnt[dst], 1u);
    esrc2[pos] = make_uint2((uint32)e, (uint32)ei[e]);
  }
}

// ---------------------------------------------------------------------------
// flat_agg8: TRANSPOSED padded-tile aggregate. One full wave per tile.
//  MFMA(A = ea_tile[16 edges x K], B = WeT[K x 16 ch]) -> D[row=edge][col=ch]
//  Lane (c,g), reg j  ->  edge 4g+j, channel c*NB+ct (per B-tile ct).
//  A[k16]=1.0, A[k17]=(invalid edge ? -1e38 : 0); B[k16]=be, B[k17]=1.0.
//  acc[NB] scalars per lane; node flush = 2 shfl_xor per value + coalesced
//  float4 store from g==0 lanes (atomics at range boundaries).
//  GEA=true (layer 0): gather ea f32, pack bf16, write eabc coalesced.
//  GEA=false (layer 1): read pre-packed eabc. 3-deep pipeline.
// ---------------------------------------------------------------------------
template<int D, int NB, bool GEA>
__global__ __launch_bounds__(256) void flat_agg8(
    const int* __restrict__ snode, const uint32* __restrict__ toff,
    const uint32* __restrict__ eoff, const uint32* __restrict__ deg,
    const uint2* __restrict__ esrc2, const float* __restrict__ ea,
    unsigned short* __restrict__ eabc,
    const unsigned short* __restrict__ hsrc,
    const unsigned short* __restrict__ Wet, const float* __restrict__ be,
    const ull* __restrict__ tot, float* __restrict__ agg)
{
  const int tid = threadIdx.x;
  const int wid = tid >> 6;
  const int lane = tid & 63;
  const int c = lane & 15;
  const int g = lane >> 4;
  const int range = blockIdx.x * 4 + wid;
  const int tile0 = range * 8;
  const uint32 ntile = (uint32)((*tot) >> 32);
  if ((uint32)tile0 >= ntile) return;   // dead range

  // B fragments (weights): col c -> channel c*NB+ct; k16=be, k17=1.0
  bf16x8 wf[NB];
#pragma unroll
  for (int ct = 0; ct < NB; ++ct) {
    const int ch = c * NB + ct;
    uint4 u = make_uint4(0u, 0u, 0u, 0u);
    if (g < 2) u = *(const uint4*)&Wet[ch * 16 + g * 8];
    else if (g == 2) u.x = (0x3f80u << 16) | (uint32)f2bf(be[ch]);
    union { uint4 u4; bf16x8 v; } cv; cv.u4 = u;
    wf[ct] = cv.v;
  }

  // per-tile metadata on lanes 0..7: pk = d0(7b) | rem(5b,<=16) | flags(2b)
  int sn8 = -1, pk8 = 0, p_ = 0;
  if (lane < 8) {
    sn8 = snode[tile0 + lane];
    if (sn8 >= 0) {
      const uint32 to = toff[sn8], dg = deg[sn8], eo = eoff[sn8];
      const int k = tile0 + lane - (int)to;
      p_ = (int)eo + k * 16;
      int rv = (int)dg - k * 16; if (rv > 16) rv = 16;
      const int fl = (k == 0 ? 1 : 0) |
                     ((k == (int)((dg + 15u) >> 4) - 1) ? 2 : 0);
      pk8 = (rv << 7) | (fl << 12);
    }
  }
  const int p0base = __shfl(p_, 0);   // lane 0 (tile0) is always real
  if (lane < 8 && sn8 >= 0) pk8 |= (p_ - p0base);

  // bulk preload: range spans <= 128 dense slots starting at p0base
  const uint2 q0 = esrc2[(size_t)p0base + lane];
  const uint2 q1 = esrc2[(size_t)p0base + 64 + lane];

  float acc[NB];
#pragma unroll
  for (int ct = 0; ct < NB; ++ct) acc[ct] = 0.f;
  int openNode = -1; bool openFull = false, openClosed = false;

  auto flushOpen = [&](bool storeOK) {
#pragma unroll
    for (int ct = 0; ct < NB; ++ct) {
      acc[ct] += __shfl_xor(acc[ct], 16);
      acc[ct] += __shfl_xor(acc[ct], 32);
    }
    if (g == 0) {
      float* p = &agg[(size_t)openNode * D + c * NB];
      if (storeOK) {
        if constexpr (NB == 8) {
          *(float4*)p = make_float4(acc[0], acc[1], acc[2], acc[3]);
          *(float4*)(p + 4) = make_float4(acc[4], acc[5], acc[6], acc[7]);
        } else {
          *(float2*)p = make_float2(acc[0], acc[1]);
        }
      } else {
#pragma unroll
        for (int ct = 0; ct < NB; ++ct) atomicAdd(p + ct, acc[ct]);
      }
    }
  };

  auto issue = [&](int t, float4& E0, float4& E1, uint4& afu,
                   uint4* h, int& n_, int& mt_) {
    n_ = __shfl(sn8, t);
    mt_ = __shfl(pk8, t);
    const int d0 = mt_ & 127;
    const int rem = (mt_ >> 7) & 31;
    const int idxA = d0 + ((c < rem) ? c : 0);
    if constexpr (GEA) {
      const int liA = idxA & 63;
      const uint32 eA_ = (uint32)__shfl((int)q0.x, liA);
      const uint32 eB_ = (uint32)__shfl((int)q1.x, liA);
      const int e = (int)((idxA & 64) ? eB_ : eA_);
      if (g < 2) {
        E0 = *(const float4*)&ea[(size_t)e * 16 + g * 8];
        E1 = *(const float4*)&ea[(size_t)e * 16 + g * 8 + 4];
      }
    } else {
      if (g < 2) afu = *(const uint4*)&eabc[((size_t)p0base + idxA) * 16 + g * 8];
    }
    // h for this lane's 4 edges (4g..4g+3), channels c*NB..c*NB+NB-1
#pragma unroll
    for (int j = 0; j < 4; ++j) {
      const int cj = 4 * g + j;
      const int idxj = d0 + ((cj < rem) ? cj : 0);
      const int lij = idxj & 63;
      const uint32 s0_ = (uint32)__shfl((int)q0.y, lij);
      const uint32 s1_ = (uint32)__shfl((int)q1.y, lij);
      const int src = (int)((idxj & 64) ? s1_ : s0_);
      if constexpr (D == 128)
        h[j] = *(const uint4*)&hsrc[(size_t)src * 128 + c * 8];
      else
        h[j].x = *(const uint32*)&hsrc[(size_t)src * 32 + c * 2];
    }
  };

  auto compute = [&](const float4 E0, const float4 E1, uint4 afu,
                     const uint4* h, const int n, const int mt) {
    if (n < 0) return;
    const int rem = (mt >> 7) & 31;
    const int fl = mt >> 12;
    if (n != openNode) {
      if (openNode >= 0) {
        flushOpen(openFull);
#pragma unroll
        for (int ct = 0; ct < NB; ++ct) acc[ct] = 0.f;
      }
      openNode = n; openFull = (fl & 1) != 0; openClosed = false;
    }
    if (fl & 2) openClosed = true;
    if constexpr (GEA) {
      afu.x = pack2ru(E0.x, E0.y); afu.y = pack2ru(E0.z, E0.w);
      afu.z = pack2ru(E1.x, E1.y); afu.w = pack2ru(E1.z, E1.w);
      if (g < 2) {
        const int d0 = mt & 127;
        const int idxA = d0 + ((c < rem) ? c : 0);
        *(uint4*)&eabc[((size_t)p0base + idxA) * 16 + g * 8] = afu;
      }
    }
    bf16x8 afv;   // A operand: edge rows; k16=1.0, k17 = poison if invalid
    {
      uint4 u = make_uint4(0u, 0u, 0u, 0u);
      if (g < 2) u = afu;
      else if (g == 2) u.x = 0x3f80u | (((c < rem) ? 0u : 0xFE96u) << 16);
      union { uint4 u4; bf16x8 v; } cv; cv.u4 = u; afv = cv.v;
    }
#pragma unroll
    for (int ct = 0; ct < NB; ++ct) {
      f32x4 pre = __builtin_amdgcn_mfma_f32_16x16x32_bf16(
          afv, wf[ct], (f32x4){0.f, 0.f, 0.f, 0.f}, 0, 0, 0);
#pragma unroll
      for (int j = 0; j < 4; ++j) {
        uint32 wv;
        if constexpr (D == 128) {
          const int q = ct >> 1;
          wv = (q == 0) ? h[j].x : (q == 1) ? h[j].y : (q == 2) ? h[j].z : h[j].w;
        } else {
          wv = h[j].x;
        }
        const unsigned short hu = (unsigned short)((ct & 1) ? (wv >> 16)
                                                            : (wv & 0xffffu));
        acc[ct] += fmaxf(pre[j] + bf2f(hu), 0.f);
      }
    }
  };

  float4 eA0, eA1, eB0, eB1, eC0, eC1;
  uint4 aA = make_uint4(0,0,0,0), aB = make_uint4(0,0,0,0), aC = make_uint4(0,0,0,0);
  uint4 hA[4], hB[4], hC[4];
#pragma unroll
  for (int j = 0; j < 4; ++j) {
    hA[j] = make_uint4(0,0,0,0); hB[j] = make_uint4(0,0,0,0);
    hC[j] = make_uint4(0,0,0,0);
  }
  int nA = -1, mA = 0, nB_ = -1, mB = 0, nC = -1, mC = 0;

  // 3-deep pipeline: 2 tiles of loads in flight ahead of each compute
  issue(0, eA0, eA1, aA, hA, nA, mA);
  issue(1, eB0, eB1, aB, hB, nB_, mB);
  issue(2, eC0, eC1, aC, hC, nC, mC);
  compute(eA0, eA1, aA, hA, nA, mA); issue(3, eA0, eA1, aA, hA, nA, mA);
  compute(eB0, eB1, aB, hB, nB_, mB); issue(4, eB0, eB1, aB, hB, nB_, mB);
  compute(eC0, eC1, aC, hC, nC, mC); issue(5, eC0, eC1, aC, hC, nC, mC);
  compute(eA0, eA1, aA, hA, nA, mA); issue(6, eA0, eA1, aA, hA, nA, mA);
  compute(eB0, eB1, aB, hB, nB_, mB); issue(7, eB0, eB1, aB, hB, nB_, mB);
  compute(eC0, eC1, aC, hC, nC, mC);
  compute(eA0, eA1, aA, hA, nA, mA);
  compute(eB0, eB1, aB, hB, nB_, mB);
  if (openNode >= 0) flushOpen(openFull && openClosed);
}

// ---------------------------------------------------------------------------
// MFMA node MLP: out = relu((a+agg)@W1+b1)@W2+b2, + BN stats.
// ---------------------------------------------------------------------------
template<int DIN, bool ABF16>
__global__ __launch_bounds__(256) void mlp_mfma(
    const float* __restrict__ a32, const unsigned short* __restrict__ abf,
    const float* __restrict__ agg,
    const unsigned short* __restrict__ W1t, const float* __restrict__ b1,
    const unsigned short* __restrict__ W2t, const float* __restrict__ b2,
    float* __restrict__ outp, float* __restrict__ stats, int nChunks)
{
  constexpr int P1 = (DIN == 128) ? 136 : 40;
  constexpr int KS1 = DIN / 32;
  __shared__ __align__(16) unsigned short hin[64 * P1];
  __shared__ __align__(16) unsigned short tls[64 * 136];
  const int tid = threadIdx.x;
  const int w = tid >> 6;
  const int lane = tid & 63;
  const int c = lane & 15, g = lane >> 4;
  const int cw = w * 32;

  bf16x8 B1[2][KS1], B2[2][4];
#pragma unroll
  for (int ct = 0; ct < 2; ++ct)
#pragma unroll
    for (int kk = 0; kk < KS1; ++kk)
      B1[ct][kk] = *(const bf16x8*)&W1t[(cw + ct * 16 + c) * DIN + kk * 32 + g * 8];
#pragma unroll
  for (int ct = 0; ct < 2; ++ct)
#pragma unroll
    for (int kk = 0; kk < 4; ++kk)
      B2[ct][kk] = *(const bf16x8*)&W2t[(cw + ct * 16 + c) * 128 + kk * 32 + g * 8];
  const float b1c0 = b1[cw + c], b1c1 = b1[cw + 16 + c];
  const float b2c0 = b2[cw + c], b2c1 = b2[cw + 16 + c];
  float lsum0 = 0.f, lsum1 = 0.f, lsq0 = 0.f, lsq1 = 0.f;

  for (int chunk = blockIdx.x; chunk < nChunks; chunk += gridDim.x) {
    const int base = chunk * 64;
    if constexpr (DIN == 128) {
#pragma unroll
      for (int p = 0; p < 4; ++p) {
        const int idx = tid + 256 * p;
        const int n = idx >> 4, k8 = idx & 15;
        const int node = base + n;
        uint4 ov = make_uint4(0u, 0u, 0u, 0u);
        if (node < NN) {
          const float4 g0 = *(const float4*)&agg[node * 128 + k8 * 8];
          const float4 g1 = *(const float4*)&agg[node * 128 + k8 * 8 + 4];
          const uint4 hv = *(const uint4*)&abf[node * 128 + k8 * 8];
          ov.x = pack2(bf2f((unsigned short)(hv.x & 0xffffu)) + g0.x,
                       bf2f((unsigned short)(hv.x >> 16)) + g0.y);
          ov.y = pack2(bf2f((unsigned short)(hv.y & 0xffffu)) + g0.z,
                       bf2f((unsigned short)(hv.y >> 16)) + g0.w);
          ov.z = pack2(bf2f((unsigned short)(hv.z & 0xffffu)) + g1.x,
                       bf2f((unsigned short)(hv.z >> 16)) + g1.y);
          ov.w = pack2(bf2f((unsigned short)(hv.w & 0xffffu)) + g1.z,
                       bf2f((unsigned short)(hv.w >> 16)) + g1.w);
        }
        *(uint4*)&hin[n * P1 + k8 * 8] = ov;
      }
    } else {
      const int n = tid >> 2, k8 = tid & 3;
      const int node = base + n;
      uint4 ov = make_uint4(0u, 0u, 0u, 0u);
      if (node < NN) {
        const float4 x0 = *(const float4*)&a32[node * 32 + k8 * 8];
        const float4 x1 = *(const float4*)&a32[node * 32 + k8 * 8 + 4];
        const float4 g0 = *(const float4*)&agg[node * 32 + k8 * 8];
        const float4 g1 = *(const float4*)&agg[node * 32 + k8 * 8 + 4];
        ov.x = pack2(x0.x + g0.x, x0.y + g0.y);
        ov.y = pack2(x0.z + g0.z, x0.w + g0.w);
        ov.z = pack2(x1.x + g1.x, x1.y + g1.y);
        ov.w = pack2(x1.z + g1.z, x1.w + g1.w);
      }
      *(uint4*)&hin[n * P1 + k8 * 8] = ov;
    }
    __syncthreads();
#pragma unroll
    for (int nt = 0; nt < 4; ++nt) {
      bf16x8 af[KS1];
#pragma unroll
      for (int kk = 0; kk < KS1; ++kk)
        af[kk] = *(const bf16x8*)&hin[(nt * 16 + c) * P1 + kk * 32 + g * 8];
      f32x4 acc0 = {0.f, 0.f, 0.f, 0.f}, acc1 = {0.f, 0.f, 0.f, 0.f};
#pragma unroll
      for (int kk = 0; kk < KS1; ++kk) {
        acc0 = __builtin_amdgcn_mfma_f32_16x16x32_bf16(af[kk], B1[0][kk], acc0, 0, 0, 0);
        acc1 = __builtin_amdgcn_mfma_f32_16x16x32_bf16(af[kk], B1[1][kk], acc1, 0, 0, 0);
      }
#pragma unroll
      for (int j = 0; j < 4; ++j) {
        const int row = nt * 16 + g * 4 + j;
        tls[row * 136 + cw + c]      = f2bf(fmaxf(acc0[j] + b1c0, 0.f));
        tls[row * 136 + cw + 16 + c] = f2bf(fmaxf(acc1[j] + b1c1, 0.f));
      }
    }
    __syncthreads();
#pragma unroll
    for (int nt = 0; nt < 4; ++nt) {
      bf16x8 af[4];
#pragma unroll
      for (int kk = 0; kk < 4; ++kk)
        af[kk] = *(const bf16x8*)&tls[(nt * 16 + c) * 136 + kk * 32 + g * 8];
      f32x4 acc0 = {0.f, 0.f, 0.f, 0.f}, acc1 = {0.f, 0.f, 0.f, 0.f};
#pragma unroll
      for (int kk = 0; kk < 4; ++kk) {
        acc0 = __builtin_amdgcn_mfma_f32_16x16x32_bf16(af[kk], B2[0][kk], acc0, 0, 0, 0);
        acc1 = __builtin_amdgcn_mfma_f32_16x16x32_bf16(af[kk], B2[1][kk], acc1, 0, 0, 0);
      }
#pragma unroll
      for (int j = 0; j < 4; ++j) {
        const int node = base + nt * 16 + g * 4 + j;
        if (node < NN) {
          const float v0 = acc0[j] + b2c0;
          const float v1 = acc1[j] + b2c1;
          outp[node * 128 + cw + c] = v0;
          outp[node * 128 + cw + 16 + c] = v1;
          lsum0 += v0; lsq0 += v0 * v0;
          lsum1 += v1; lsq1 += v1 * v1;
        }
      }
    }
  }
  lsum0 += __shfl_xor(lsum0, 16); lsum0 += __shfl_xor(lsum0, 32);
  lsum1 += __shfl_xor(lsum1, 16); lsum1 += __shfl_xor(lsum1, 32);
  lsq0  += __shfl_xor(lsq0, 16);  lsq0  += __shfl_xor(lsq0, 32);
  lsq1  += __shfl_xor(lsq1, 16);  lsq1  += __shfl_xor(lsq1, 32);
  if (lane < 16) {
    atomicAdd(&stats[cw + lane], lsum0);
    atomicAdd(&stats[cw + 16 + lane], lsum1);
    atomicAdd(&stats[128 + cw + lane], lsq0);
    atomicAdd(&stats[128 + cw + 16 + lane], lsq1);
  }
}

__global__ void bn_finalize(float* __restrict__ stats,
                            const float* __restrict__ gamma,
                            const float* __restrict__ beta)
{
  const int cc = threadIdx.x;
  const float inv_n = 1.0f / (float)NN;
  const float mu = stats[cc] * inv_n;
  float var = stats[128 + cc] * inv_n - mu * mu;
  var = fmaxf(var, 0.f);
  const float rs = rsqrtf(var + 1e-5f);
  const float sc = rs * gamma[cc];
  stats[256 + cc] = sc;
  stats[384 + cc] = beta[cc] - mu * sc;
}

__global__ __launch_bounds__(256) void bn_apply_bf16(
    const float* __restrict__ h, const float* __restrict__ stats,
    unsigned short* __restrict__ hb)
{
  const int idx = blockIdx.x * 256 + threadIdx.x;
  const int c4 = (idx & 31) * 4;
  const float4 sc = *(const float4*)&stats[256 + c4];
  const float4 sh = *(const float4*)&stats[384 + c4];
  const float4 v = ((const float4*)h)[idx];
  const float r0 = fmaxf(fmaf(v.x, sc.x, sh.x), 0.f);
  const float r1 = fmaxf(fmaf(v.y, sc.y, sh.y), 0.f);
  const float r2 = fmaxf(fmaf(v.z, sc.z, sh.z), 0.f);
  const float r3 = fmaxf(fmaf(v.w, sc.w, sh.w), 0.f);
  uint2 o;
  o.x = pack2(r0, r1);
  o.y = pack2(r2, r3);
  ((uint2*)hb)[idx] = o;
}

// ---------------------------------------------------------------------------
// Fused BN-apply + head: out = sigmoid(relu(relu(hpre*sc+sh)@W1+b1)@w2 + b2)
// ---------------------------------------------------------------------------
__global__ __launch_bounds__(256) void head_bn(
    const float* __restrict__ hpre, const float* __restrict__ stats,
    const unsigned short* __restrict__ W1t, const float* __restrict__ b1,
    const float* __restrict__ w2, const float* __restrict__ b2,
    float* __restrict__ out, int nChunks)
{
  __shared__ float pl[4][64];
  const int tid = threadIdx.x;
  const int w = tid >> 6;
  const int lane = tid & 63;
  const int c = lane & 15, g = lane >> 4;
  const int cw = w * 32;

  bf16x8 B1[2][4];
#pragma unroll
  for (int ct = 0; ct < 2; ++ct)
#pragma unroll
    for (int kk = 0; kk < 4; ++kk)
      B1[ct][kk] = *(const bf16x8*)&W1t[(cw + ct * 16 + c) * 128 + kk * 32 + g * 8];
  const float b1c0 = b1[cw + c], b1c1 = b1[cw + 16 + c];
  const float w2c0 = w2[cw + c], w2c1 = w2[cw + 16 + c];
  const float b2v = b2[0];
  float4 scq[4][2], shq[4][2];
#pragma unroll
  for (int kk = 0; kk < 4; ++kk) {
    const int cb = kk * 32 + g * 8;
    scq[kk][0] = *(const float4*)&stats[256 + cb];
    scq[kk][1] = *(const float4*)&stats[256 + cb + 4];
    shq[kk][0] = *(const float4*)&stats[384 + cb];
    shq[kk][1] = *(const float4*)&stats[384 + cb + 4];
  }

  for (int chunk = blockIdx.x; chunk < nChunks; chunk += gridDim.x) {
    const int base = chunk * 64;
    float p[4][4];
#pragma unroll
    for (int nt = 0; nt < 4; ++nt) {
      const int node = base + nt * 16 + c;
      bf16x8 af[4];
#pragma unroll
      for (int kk = 0; kk < 4; ++kk) {
        uint4 u = make_uint4(0u, 0u, 0u, 0u);
        if (node < NN) {
          const float4 v0 = *(const float4*)&hpre[(size_t)node * 128 + kk * 32 + g * 8];
          const float4 v1 = *(const float4*)&hpre[(size_t)node * 128 + kk * 32 + g * 8 + 4];
          const float4 s0 = scq[kk][0], s1 = scq[kk][1];
          const float4 h0 = shq[kk][0], h1 = shq[kk][1];
          u.x = pack2(fmaxf(fmaf(v0.x, s0.x, h0.x), 0.f),
                      fmaxf(fmaf(v0.y, s0.y, h0.y), 0.f));
          u.y = pack2(fmaxf(fmaf(v0.z, s0.z, h0.z), 0.f),
                      fmaxf(fmaf(v0.w, s0.w, h0.w), 0.f));
          u.z = pack2(fmaxf(fmaf(v1.x, s1.x, h1.x), 0.f),
                      fmaxf(fmaf(v1.y, s1.y, h1.y), 0.f));
          u.w = pack2(fmaxf(fmaf(v1.z, s1.z, h1.z), 0.f),
                      fmaxf(fmaf(v1.w, s1.w, h1.w), 0.f));
        }
        union { uint4 u4; bf16x8 v; } cv; cv.u4 = u;
        af[kk] = cv.v;
      }
      f32x4 acc0 = {0.f, 0.f, 0.f, 0.f}, acc1 = {0.f, 0.f, 0.f, 0.f};
#pragma unroll
      for (int kk = 0; kk < 4; ++kk) {
        acc0 = __builtin_amdgcn_mfma_f32_16x16x32_bf16(af[kk], B1[0][kk], acc0, 0, 0, 0);
        acc1 = __builtin_amdgcn_mfma_f32_16x16x32_bf16(af[kk], B1[1][kk], acc1, 0, 0, 0);
      }
#pragma unroll
      for (int j = 0; j < 4; ++j)
        p[nt][j] = fmaxf(acc0[j] + b1c0, 0.f) * w2c0 +
                   fmaxf(acc1[j] + b1c1, 0.f) * w2c1;
    }
#pragma unroll
    for (int dd = 1; dd <= 8; dd <<= 1)
#pragma unroll
      for (int nt = 0; nt < 4; ++nt)
#pragma unroll
        for (int j = 0; j < 4; ++j)
          p[nt][j] += __shfl_xor(p[nt][j], dd);
    if (c == 0) {
#pragma unroll
      for (int nt = 0; nt < 4; ++nt)
#pragma unroll
        for (int j = 0; j < 4; ++j)
          pl[w][nt * 16 + g * 4 + j] = p[nt][j];
    }
    __syncthreads();
    if (tid < 64) {
      const int node = base + tid;
      if (node < NN) {
        const float s = pl[0][tid] + pl[1][tid] + pl[2][tid] + pl[3][tid] + b2v;
        out[node] = 1.f / (1.f + expf(-s));
      }
    }
    __syncthreads();
  }
}

extern "C" void kernel_launch(void* const* d_in, const int* in_sizes, int n_in,
                              void* d_out, int out_size, void* d_ws, size_t ws_size,
                              hipStream_t stream)
{
  const float* x    = (const float*)d_in[0];
  const int*   ei   = (const int*)  d_in[1];
  const float* ea   = (const float*)d_in[2];
  const float* l0We = (const float*)d_in[3];
  const float* l0be = (const float*)d_in[4];
  const float* l0W1 = (const float*)d_in[5];
  const float* l0b1 = (const float*)d_in[6];
  const float* l0W2 = (const float*)d_in[7];
  const float* l0b2 = (const float*)d_in[8];
  const float* l0g  = (const float*)d_in[9];
  const float* l0bt = (const float*)d_in[10];
  const float* l1We = (const float*)d_in[11];
  const float* l1be = (const float*)d_in[12];
  const float* l1W1 = (const float*)d_in[13];
  const float* l1b1 = (const float*)d_in[14];
  const float* l1W2 = (const float*)d_in[15];
  const float* l1b2 = (const float*)d_in[16];
  const float* l1g  = (const float*)d_in[17];
  const float* l1bt = (const float*)d_in[18];
  const float* hW1  = (const float*)d_in[19];
  const float* hb1  = (const float*)d_in[20];
  const float* hW2  = (const float*)d_in[21];
  const float* hb2  = (const float*)d_in[22];
  float* out = (float*)d_out;

  // workspace layout (~201 MB; proven available in R9/R11/R12/R14)
  float*  A    = (float*)d_ws;                         // NN*128 f32 (hpre)
  float*  AGG  = A + (size_t)NN * 128;                 // NN*128 f32
  unsigned short* hb = (unsigned short*)(AGG + (size_t)NN * 128);  // NN*128 bf16
  unsigned short* xb = hb + (size_t)NN * 128;          // NN*32 bf16
  uint32* deg     = (uint32*)(xb + (size_t)NN * 32);   // NN
  uint32* cnt     = deg + NN;                          // NN
  uint32* toff    = cnt + NN;                          // NN
  uint32* eoff    = toff + NN;                         // NN
  ull*    counter = (ull*)(eoff + NN);                 // 1 (pad 2)
  int*    snode   = (int*)(counter + 2);               // TMAX
  uint2*  esrc2   = (uint2*)(snode + TMAX);            // NE + 128 pad
  float*  st0     = (float*)(esrc2 + NE + 128);        // 512
  float*  st1     = st0 + 512;                         // 512
  unsigned short* W1t0 = (unsigned short*)(st1 + 512); // 32*128
  unsigned short* W2t0 = W1t0 + 4096;                  // 128*128
  unsigned short* W1t1 = W2t0 + 16384;
  unsigned short* W2t1 = W1t1 + 16384;
  unsigned short* hW1t = W2t1 + 16384;
  unsigned short* Wet0 = hW1t + 16384;                 // 32*16
  unsigned short* Wet1 = Wet0 + 512;                   // 128*16
  unsigned short* eabc = Wet1 + 2048;                  // NE*16 bf16 (51.2 MB)

  const size_t needed = (size_t)((char*)(eabc + (size_t)NE * 16) - (char*)d_ws);
  if (ws_size < needed) return;

  hipMemsetAsync(deg, 0, (size_t)2 * NN * 4, stream);          // deg, cnt
  hipMemsetAsync(counter, 0, 16, stream);
  hipMemsetAsync(snode, 0xFF, (size_t)TMAX * 4, stream);
  hipMemsetAsync(st0, 0, 4096, stream);                        // st0 + st1
  hipMemsetAsync(AGG, 0, (size_t)NN * 32 * 4, stream);         // layer-0 agg

  const int nChunks = (NN + 63) / 64;     // 1563
  const int eBlocks = (NE + 255) / 256;   // 6250

  // one combined conversion launch (5 weights + 2 edge-W + x)
  conv_all<<<16 + 64 * 4 + 2 + 8 + 1563, 256, 0, stream>>>(
      l0W1, l0W2, l1W1, l1W2, hW1, l0We, l1We, x,
      W1t0, W2t0, W1t1, W2t1, hW1t, Wet0, Wet1, xb);

  // CSR build
  hist_kernel<<<eBlocks, 256, 0, stream>>>(ei, deg);
  offsets2_kernel<<<(NN + 255) / 256, 256, 0, stream>>>(deg, toff, eoff, counter);
  snode_fill<<<(NN + 255) / 256, 256, 0, stream>>>(toff, deg, snode);
  fill_kernel<<<eBlocks, 256, 0, stream>>>(ei, eoff, cnt, esrc2);

  // layer 0: gathers ea, packs, writes eabc (coalesced) for layer 1
  flat_agg8<32, 2, true><<<NRANGES / 4, 256, 0, stream>>>(
      snode, toff, eoff, deg, esrc2, ea, eabc, xb, Wet0, l0be, counter, AGG);
  mlp_mfma<32, false><<<782, 256, 0, stream>>>(x, (const unsigned short*)nullptr,
      AGG, W1t0, l0b1, W2t0, l0b2, A, st0, nChunks);
  hipMemsetAsync(AGG, 0, (size_t)NN * 128 * 4, stream);   // re-zero for layer 1
  bn_finalize<<<1, 128, 0, stream>>>(st0, l0g, l0bt);
  bn_apply_bf16<<<(NN * 32) / 256, 256, 0, stream>>>(A, st0, hb);

  // layer 1: consumes pre-packed eabc (one full wave per tile)
  flat_agg8<128, 8, false><<<NRANGES / 4, 256, 0, stream>>>(
      snode, toff, eoff, deg, esrc2, ea, eabc, hb, Wet1, l1be, counter, AGG);
  mlp_mfma<128, true><<<782, 256, 0, stream>>>((const float*)nullptr, hb,
      AGG, W1t1, l1b1, W2t1, l1b2, A, st1, nChunks);
  bn_finalize<<<1, 128, 0, stream>>>(st1, l1g, l1bt);

  // fused BN-apply + head
  head_bn<<<782, 256, 0, stream>>>(A, st1, hW1t, hb1, hW2, hb2, out, nChunks);
}

// Round 16
// 533.169 us; speedup vs baseline: 1.0858x; 1.0152x over previous
//
#include <hip/hip_runtime.h>

#define NN 100000
#define NE 1600000
#define TMAX 193760           // >= sum ceil(deg/16) worst case (193750)
#define NRANGES 24220         // TMAX / 8

typedef unsigned int uint32;
typedef unsigned long long ull;
typedef __attribute__((ext_vector_type(8))) short bf16x8;
typedef __attribute__((ext_vector_type(4))) float f32x4;

__device__ __forceinline__ unsigned short f2bf(float f) {
  unsigned int u = __float_as_uint(f);
  unsigned int r = (u + 0x7fffu + ((u >> 16) & 1u)) >> 16;  // RNE
  return (unsigned short)r;
}
__device__ __forceinline__ float bf2f(unsigned short u) {
  return __uint_as_float(((unsigned int)u) << 16);
}
__device__ __forceinline__ unsigned int pack2(float a, float b) {
  return (unsigned int)f2bf(a) | ((unsigned int)f2bf(b) << 16);
}
// round-half-up pack of two f32 -> bf16 pair (cheap, ~= RNE for random data)
__device__ __forceinline__ uint32 pack2ru(float a, float b) {
  const uint32 ua = __float_as_uint(a) + 0x8000u;
  const uint32 ub = __float_as_uint(b) + 0x8000u;
  return (ua >> 16) | (ub & 0xffff0000u);
}

// ---------------------------------------------------------------------------
// Combined weight/activation conversion (one launch).
// ---------------------------------------------------------------------------
__device__ __forceinline__ void wconv_body(const float* __restrict__ src,
    unsigned short* __restrict__ dst, int K, int N, int b)
{
  const int i = b * 256 + threadIdx.x;
  if (i < K * N) {
    const int n = i / K, k = i - n * K;
    dst[i] = f2bf(src[k * N + n]);
  }
}

__global__ __launch_bounds__(256) void conv_all(
    const float* __restrict__ l0W1, const float* __restrict__ l0W2,
    const float* __restrict__ l1W1, const float* __restrict__ l1W2,
    const float* __restrict__ hW1,  const float* __restrict__ l0We,
    const float* __restrict__ l1We, const float* __restrict__ x,
    unsigned short* __restrict__ W1t0, unsigned short* __restrict__ W2t0,
    unsigned short* __restrict__ W1t1, unsigned short* __restrict__ W2t1,
    unsigned short* __restrict__ hW1t, unsigned short* __restrict__ Wet0,
    unsigned short* __restrict__ Wet1, unsigned short* __restrict__ xb)
{
  int b = blockIdx.x;
  if (b < 16)  { wconv_body(l0W1, W1t0, 32, 128, b); return; }  b -= 16;
  if (b < 64)  { wconv_body(l0W2, W2t0, 128, 128, b); return; } b -= 64;
  if (b < 64)  { wconv_body(l1W1, W1t1, 128, 128, b); return; } b -= 64;
  if (b < 64)  { wconv_body(l1W2, W2t1, 128, 128, b); return; } b -= 64;
  if (b < 64)  { wconv_body(hW1,  hW1t, 128, 128, b); return; } b -= 64;
  if (b < 2)   { wconv_body(l0We, Wet0, 16, 32, b); return; }   b -= 2;
  if (b < 8)   { wconv_body(l1We, Wet1, 16, 128, b); return; }  b -= 8;
  const int i = b * 256 + threadIdx.x;
  if (i * 8 < NN * 32) {
    const float4 a = ((const float4*)x)[i * 2];
    const float4 d = ((const float4*)x)[i * 2 + 1];
    uint4 o;
    o.x = pack2(a.x, a.y); o.y = pack2(a.z, a.w);
    o.z = pack2(d.x, d.y); o.w = pack2(d.z, d.w);
    ((uint4*)xb)[i] = o;
  }
}

// ---------------------------------------------------------------------------
// CSR build: histogram -> dual prefix scan (tiles, edges) -> snode -> fill
// ---------------------------------------------------------------------------
__global__ __launch_bounds__(256) void hist_kernel(
    const int* __restrict__ ei, uint32* __restrict__ deg)
{
  const int e = blockIdx.x * 256 + threadIdx.x;
  if (e < NE) atomicAdd(&deg[ei[NE + e]], 1u);
}

__global__ __launch_bounds__(256) void offsets2_kernel(
    const uint32* __restrict__ deg, uint32* __restrict__ toff,
    uint32* __restrict__ eoff, ull* __restrict__ counter)
{
  __shared__ ull s[256];
  __shared__ ull base;
  const int tid = threadIdx.x;
  const int n = blockIdx.x * 256 + tid;
  const uint32 d = (n < NN) ? deg[n] : 0u;
  const uint32 tc = (d + 15u) >> 4;
  const ull v = ((ull)tc << 32) | (ull)d;
  s[tid] = v;
  __syncthreads();
#pragma unroll
  for (int st = 1; st < 256; st <<= 1) {
    ull w = (tid >= st) ? s[tid - st] : 0ull;
    __syncthreads();
    s[tid] += w;
    __syncthreads();
  }
  if (tid == 255) base = atomicAdd(counter, s[255]);
  __syncthreads();
  if (n < NN) {
    const ull t = base + (s[tid] - v);
    toff[n] = (uint32)(t >> 32);
    eoff[n] = (uint32)t;
  }
}

__global__ __launch_bounds__(256) void snode_fill(
    const uint32* __restrict__ toff, const uint32* __restrict__ deg,
    int* __restrict__ snode)
{
  const int n = blockIdx.x * 256 + threadIdx.x;
  if (n < NN) {
    const uint32 t0 = toff[n];
    const uint32 tc = (deg[n] + 15u) >> 4;
    for (uint32 i = 0; i < tc; ++i) snode[t0 + i] = n;
  }
}

// single light scatter: 8B (edge id, src) per dense slot
__global__ __launch_bounds__(256) void fill_kernel(
    const int* __restrict__ ei, const uint32* __restrict__ eoff,
    uint32* __restrict__ cnt, uint2* __restrict__ esrc2)
{
  const int e = blockIdx.x * 256 + threadIdx.x;
  if (e < NE) {
    const int dst = ei[NE + e];
    const uint32 pos = eoff[dst] + atomicAdd(&cnt[dst], 1u);
    esrc2[pos] = make_uint2((uint32)e, (uint32)ei[e]);
  }
}

// ---------------------------------------------------------------------------
// flat_agg9: TRANSPOSED padded-tile aggregate (R15) + template pipeline DEPTH.
//  DEPTH=3 for GEA layer 0 (long random-gather latency needs in-flight cover)
//  DEPTH=2 for layer 1 (short eabc latency; fewer live regs -> 8 waves/SIMD)
// ---------------------------------------------------------------------------
template<int D, int NB, bool GEA, int DEPTH>
__global__ __launch_bounds__(256) void flat_agg9(
    const int* __restrict__ snode, const uint32* __restrict__ toff,
    const uint32* __restrict__ eoff, const uint32* __restrict__ deg,
    const uint2* __restrict__ esrc2, const float* __restrict__ ea,
    unsigned short* __restrict__ eabc,
    const unsigned short* __restrict__ hsrc,
    const unsigned short* __restrict__ Wet, const float* __restrict__ be,
    const ull* __restrict__ tot, float* __restrict__ agg)
{
  const int tid = threadIdx.x;
  const int wid = tid >> 6;
  const int lane = tid & 63;
  const int c = lane & 15;
  const int g = lane >> 4;
  const int range = blockIdx.x * 4 + wid;
  const int tile0 = range * 8;
  const uint32 ntile = (uint32)((*tot) >> 32);
  if ((uint32)tile0 >= ntile) return;   // dead range

  // B fragments (weights): col c -> channel c*NB+ct; k16=be, k17=1.0
  bf16x8 wf[NB];
#pragma unroll
  for (int ct = 0; ct < NB; ++ct) {
    const int ch = c * NB + ct;
    uint4 u = make_uint4(0u, 0u, 0u, 0u);
    if (g < 2) u = *(const uint4*)&Wet[ch * 16 + g * 8];
    else if (g == 2) u.x = (0x3f80u << 16) | (uint32)f2bf(be[ch]);
    union { uint4 u4; bf16x8 v; } cv; cv.u4 = u;
    wf[ct] = cv.v;
  }

  // per-tile metadata on lanes 0..7: pk = d0(7b) | rem(5b,<=16) | flags(2b)
  int sn8 = -1, pk8 = 0, p_ = 0;
  if (lane < 8) {
    sn8 = snode[tile0 + lane];
    if (sn8 >= 0) {
      const uint32 to = toff[sn8], dg = deg[sn8], eo = eoff[sn8];
      const int k = tile0 + lane - (int)to;
      p_ = (int)eo + k * 16;
      int rv = (int)dg - k * 16; if (rv > 16) rv = 16;
      const int fl = (k == 0 ? 1 : 0) |
                     ((k == (int)((dg + 15u) >> 4) - 1) ? 2 : 0);
      pk8 = (rv << 7) | (fl << 12);
    }
  }
  const int p0base = __shfl(p_, 0);   // lane 0 (tile0) is always real
  if (lane < 8 && sn8 >= 0) pk8 |= (p_ - p0base);

  // bulk preload: range spans <= 128 dense slots starting at p0base
  const uint2 q0 = esrc2[(size_t)p0base + lane];
  const uint2 q1 = esrc2[(size_t)p0base + 64 + lane];

  float acc[NB];
#pragma unroll
  for (int ct = 0; ct < NB; ++ct) acc[ct] = 0.f;
  int openNode = -1; bool openFull = false, openClosed = false;

  auto flushOpen = [&](bool storeOK) {
#pragma unroll
    for (int ct = 0; ct < NB; ++ct) {
      acc[ct] += __shfl_xor(acc[ct], 16);
      acc[ct] += __shfl_xor(acc[ct], 32);
    }
    if (g == 0) {
      float* p = &agg[(size_t)openNode * D + c * NB];
      if (storeOK) {
        if constexpr (NB == 8) {
          *(float4*)p = make_float4(acc[0], acc[1], acc[2], acc[3]);
          *(float4*)(p + 4) = make_float4(acc[4], acc[5], acc[6], acc[7]);
        } else {
          *(float2*)p = make_float2(acc[0], acc[1]);
        }
      } else {
#pragma unroll
        for (int ct = 0; ct < NB; ++ct) atomicAdd(p + ct, acc[ct]);
      }
    }
  };

  auto issue = [&](int t, float4& E0, float4& E1, uint4& afu,
                   uint4* h, int& n_, int& mt_) {
    n_ = __shfl(sn8, t);
    mt_ = __shfl(pk8, t);
    const int d0 = mt_ & 127;
    const int rem = (mt_ >> 7) & 31;
    const int idxA = d0 + ((c < rem) ? c : 0);
    if constexpr (GEA) {
      const int liA = idxA & 63;
      const uint32 eA_ = (uint32)__shfl((int)q0.x, liA);
      const uint32 eB_ = (uint32)__shfl((int)q1.x, liA);
      const int e = (int)((idxA & 64) ? eB_ : eA_);
      if (g < 2) {
        E0 = *(const float4*)&ea[(size_t)e * 16 + g * 8];
        E1 = *(const float4*)&ea[(size_t)e * 16 + g * 8 + 4];
      }
    } else {
      if (g < 2) afu = *(const uint4*)&eabc[((size_t)p0base + idxA) * 16 + g * 8];
    }
    // h for this lane's 4 edges (4g..4g+3), channels c*NB..c*NB+NB-1
#pragma unroll
    for (int j = 0; j < 4; ++j) {
      const int cj = 4 * g + j;
      const int idxj = d0 + ((cj < rem) ? cj : 0);
      const int lij = idxj & 63;
      const uint32 s0_ = (uint32)__shfl((int)q0.y, lij);
      const uint32 s1_ = (uint32)__shfl((int)q1.y, lij);
      const int src = (int)((idxj & 64) ? s1_ : s0_);
      if constexpr (D == 128)
        h[j] = *(const uint4*)&hsrc[(size_t)src * 128 + c * 8];
      else
        h[j].x = *(const uint32*)&hsrc[(size_t)src * 32 + c * 2];
    }
  };

  auto compute = [&](const float4 E0, const float4 E1, uint4 afu,
                     const uint4* h, const int n, const int mt) {
    if (n < 0) return;
    const int rem = (mt >> 7) & 31;
    const int fl = mt >> 12;
    if (n != openNode) {
      if (openNode >= 0) {
        flushOpen(openFull);
#pragma unroll
        for (int ct = 0; ct < NB; ++ct) acc[ct] = 0.f;
      }
      openNode = n; openFull = (fl & 1) != 0; openClosed = false;
    }
    if (fl & 2) openClosed = true;
    if constexpr (GEA) {
      afu.x = pack2ru(E0.x, E0.y); afu.y = pack2ru(E0.z, E0.w);
      afu.z = pack2ru(E1.x, E1.y); afu.w = pack2ru(E1.z, E1.w);
      if (g < 2) {
        const int d0 = mt & 127;
        const int idxA = d0 + ((c < rem) ? c : 0);
        *(uint4*)&eabc[((size_t)p0base + idxA) * 16 + g * 8] = afu;
      }
    }
    bf16x8 afv;   // A operand: edge rows; k16=1.0, k17 = poison if invalid
    {
      uint4 u = make_uint4(0u, 0u, 0u, 0u);
      if (g < 2) u = afu;
      else if (g == 2) u.x = 0x3f80u | (((c < rem) ? 0u : 0xFE96u) << 16);
      union { uint4 u4; bf16x8 v; } cv; cv.u4 = u; afv = cv.v;
    }
#pragma unroll
    for (int ct = 0; ct < NB; ++ct) {
      f32x4 pre = __builtin_amdgcn_mfma_f32_16x16x32_bf16(
          afv, wf[ct], (f32x4){0.f, 0.f, 0.f, 0.f}, 0, 0, 0);
#pragma unroll
      for (int j = 0; j < 4; ++j) {
        uint32 wv;
        if constexpr (D == 128) {
          const int q = ct >> 1;
          wv = (q == 0) ? h[j].x : (q == 1) ? h[j].y : (q == 2) ? h[j].z : h[j].w;
        } else {
          wv = h[j].x;
        }
        const unsigned short hu = (unsigned short)((ct & 1) ? (wv >> 16)
                                                            : (wv & 0xffffu));
        acc[ct] += fmaxf(pre[j] + bf2f(hu), 0.f);
      }
    }
  };

  float4 eA0, eA1, eB0, eB1, eC0, eC1;
  uint4 aA = make_uint4(0,0,0,0), aB = make_uint4(0,0,0,0), aC = make_uint4(0,0,0,0);
  uint4 hA[4], hB[4], hC[4];
#pragma unroll
  for (int j = 0; j < 4; ++j) {
    hA[j] = make_uint4(0,0,0,0); hB[j] = make_uint4(0,0,0,0);
    hC[j] = make_uint4(0,0,0,0);
  }
  int nA = -1, mA = 0, nB_ = -1, mB = 0, nC = -1, mC = 0;

  if constexpr (DEPTH == 3) {
    issue(0, eA0, eA1, aA, hA, nA, mA);
    issue(1, eB0, eB1, aB, hB, nB_, mB);
    issue(2, eC0, eC1, aC, hC, nC, mC);
    compute(eA0, eA1, aA, hA, nA, mA); issue(3, eA0, eA1, aA, hA, nA, mA);
    compute(eB0, eB1, aB, hB, nB_, mB); issue(4, eB0, eB1, aB, hB, nB_, mB);
    compute(eC0, eC1, aC, hC, nC, mC); issue(5, eC0, eC1, aC, hC, nC, mC);
    compute(eA0, eA1, aA, hA, nA, mA); issue(6, eA0, eA1, aA, hA, nA, mA);
    compute(eB0, eB1, aB, hB, nB_, mB); issue(7, eB0, eB1, aB, hB, nB_, mB);
    compute(eC0, eC1, aC, hC, nC, mC);
    compute(eA0, eA1, aA, hA, nA, mA);
    compute(eB0, eB1, aB, hB, nB_, mB);
  } else {
    issue(0, eA0, eA1, aA, hA, nA, mA);
    issue(1, eB0, eB1, aB, hB, nB_, mB);
    compute(eA0, eA1, aA, hA, nA, mA); issue(2, eA0, eA1, aA, hA, nA, mA);
    compute(eB0, eB1, aB, hB, nB_, mB); issue(3, eB0, eB1, aB, hB, nB_, mB);
    compute(eA0, eA1, aA, hA, nA, mA); issue(4, eA0, eA1, aA, hA, nA, mA);
    compute(eB0, eB1, aB, hB, nB_, mB); issue(5, eB0, eB1, aB, hB, nB_, mB);
    compute(eA0, eA1, aA, hA, nA, mA); issue(6, eA0, eA1, aA, hA, nA, mA);
    compute(eB0, eB1, aB, hB, nB_, mB); issue(7, eB0, eB1, aB, hB, nB_, mB);
    compute(eA0, eA1, aA, hA, nA, mA);
    compute(eB0, eB1, aB, hB, nB_, mB);
  }
  if (openNode >= 0) flushOpen(openFull && openClosed);
}

// ---------------------------------------------------------------------------
// MFMA node MLP: out = relu((a+agg)@W1+b1)@W2+b2, + BN stats.
// ---------------------------------------------------------------------------
template<int DIN, bool ABF16>
__global__ __launch_bounds__(256) void mlp_mfma(
    const float* __restrict__ a32, const unsigned short* __restrict__ abf,
    const float* __restrict__ agg,
    const unsigned short* __restrict__ W1t, const float* __restrict__ b1,
    const unsigned short* __restrict__ W2t, const float* __restrict__ b2,
    float* __restrict__ outp, float* __restrict__ stats, int nChunks)
{
  constexpr int P1 = (DIN == 128) ? 136 : 40;
  constexpr int KS1 = DIN / 32;
  __shared__ __align__(16) unsigned short hin[64 * P1];
  __shared__ __align__(16) unsigned short tls[64 * 136];
  const int tid = threadIdx.x;
  const int w = tid >> 6;
  const int lane = tid & 63;
  const int c = lane & 15, g = lane >> 4;
  const int cw = w * 32;

  bf16x8 B1[2][KS1], B2[2][4];
#pragma unroll
  for (int ct = 0; ct < 2; ++ct)
#pragma unroll
    for (int kk = 0; kk < KS1; ++kk)
      B1[ct][kk] = *(const bf16x8*)&W1t[(cw + ct * 16 + c) * DIN + kk * 32 + g * 8];
#pragma unroll
  for (int ct = 0; ct < 2; ++ct)
#pragma unroll
    for (int kk = 0; kk < 4; ++kk)
      B2[ct][kk] = *(const bf16x8*)&W2t[(cw + ct * 16 + c) * 128 + kk * 32 + g * 8];
  const float b1c0 = b1[cw + c], b1c1 = b1[cw + 16 + c];
  const float b2c0 = b2[cw + c], b2c1 = b2[cw + 16 + c];
  float lsum0 = 0.f, lsum1 = 0.f, lsq0 = 0.f, lsq1 = 0.f;

  for (int chunk = blockIdx.x; chunk < nChunks; chunk += gridDim.x) {
    const int base = chunk * 64;
    if constexpr (DIN == 128) {
#pragma unroll
      for (int p = 0; p < 4; ++p) {
        const int idx = tid + 256 * p;
        const int n = idx >> 4, k8 = idx & 15;
        const int node = base + n;
        uint4 ov = make_uint4(0u, 0u, 0u, 0u);
        if (node < NN) {
          const float4 g0 = *(const float4*)&agg[node * 128 + k8 * 8];
          const float4 g1 = *(const float4*)&agg[node * 128 + k8 * 8 + 4];
          const uint4 hv = *(const uint4*)&abf[node * 128 + k8 * 8];
          ov.x = pack2(bf2f((unsigned short)(hv.x & 0xffffu)) + g0.x,
                       bf2f((unsigned short)(hv.x >> 16)) + g0.y);
          ov.y = pack2(bf2f((unsigned short)(hv.y & 0xffffu)) + g0.z,
                       bf2f((unsigned short)(hv.y >> 16)) + g0.w);
          ov.z = pack2(bf2f((unsigned short)(hv.z & 0xffffu)) + g1.x,
                       bf2f((unsigned short)(hv.z >> 16)) + g1.y);
          ov.w = pack2(bf2f((unsigned short)(hv.w & 0xffffu)) + g1.z,
                       bf2f((unsigned short)(hv.w >> 16)) + g1.w);
        }
        *(uint4*)&hin[n * P1 + k8 * 8] = ov;
      }
    } else {
      const int n = tid >> 2, k8 = tid & 3;
      const int node = base + n;
      uint4 ov = make_uint4(0u, 0u, 0u, 0u);
      if (node < NN) {
        const float4 x0 = *(const float4*)&a32[node * 32 + k8 * 8];
        const float4 x1 = *(const float4*)&a32[node * 32 + k8 * 8 + 4];
        const float4 g0 = *(const float4*)&agg[node * 32 + k8 * 8];
        const float4 g1 = *(const float4*)&agg[node * 32 + k8 * 8 + 4];
        ov.x = pack2(x0.x + g0.x, x0.y + g0.y);
        ov.y = pack2(x0.z + g0.z, x0.w + g0.w);
        ov.z = pack2(x1.x + g1.x, x1.y + g1.y);
        ov.w = pack2(x1.z + g1.z, x1.w + g1.w);
      }
      *(uint4*)&hin[n * P1 + k8 * 8] = ov;
    }
    __syncthreads();
#pragma unroll
    for (int nt = 0; nt < 4; ++nt) {
      bf16x8 af[KS1];
#pragma unroll
      for (int kk = 0; kk < KS1; ++kk)
        af[kk] = *(const bf16x8*)&hin[(nt * 16 + c) * P1 + kk * 32 + g * 8];
      f32x4 acc0 = {0.f, 0.f, 0.f, 0.f}, acc1 = {0.f, 0.f, 0.f, 0.f};
#pragma unroll
      for (int kk = 0; kk < KS1; ++kk) {
        acc0 = __builtin_amdgcn_mfma_f32_16x16x32_bf16(af[kk], B1[0][kk], acc0, 0, 0, 0);
        acc1 = __builtin_amdgcn_mfma_f32_16x16x32_bf16(af[kk], B1[1][kk], acc1, 0, 0, 0);
      }
#pragma unroll
      for (int j = 0; j < 4; ++j) {
        const int row = nt * 16 + g * 4 + j;
        tls[row * 136 + cw + c]      = f2bf(fmaxf(acc0[j] + b1c0, 0.f));
        tls[row * 136 + cw + 16 + c] = f2bf(fmaxf(acc1[j] + b1c1, 0.f));
      }
    }
    __syncthreads();
#pragma unroll
    for (int nt = 0; nt < 4; ++nt) {
      bf16x8 af[4];
#pragma unroll
      for (int kk = 0; kk < 4; ++kk)
        af[kk] = *(const bf16x8*)&tls[(nt * 16 + c) * 136 + kk * 32 + g * 8];
      f32x4 acc0 = {0.f, 0.f, 0.f, 0.f}, acc1 = {0.f, 0.f, 0.f, 0.f};
#pragma unroll
      for (int kk = 0; kk < 4; ++kk) {
        acc0 = __builtin_amdgcn_mfma_f32_16x16x32_bf16(af[kk], B2[0][kk], acc0, 0, 0, 0);
        acc1 = __builtin_amdgcn_mfma_f32_16x16x32_bf16(af[kk], B2[1][kk], acc1, 0, 0, 0);
      }
#pragma unroll
      for (int j = 0; j < 4; ++j) {
        const int node = base + nt * 16 + g * 4 + j;
        if (node < NN) {
          const float v0 = acc0[j] + b2c0;
          const float v1 = acc1[j] + b2c1;
          outp[node * 128 + cw + c] = v0;
          outp[node * 128 + cw + 16 + c] = v1;
          lsum0 += v0; lsq0 += v0 * v0;
          lsum1 += v1; lsq1 += v1 * v1;
        }
      }
    }
  }
  lsum0 += __shfl_xor(lsum0, 16); lsum0 += __shfl_xor(lsum0, 32);
  lsum1 += __shfl_xor(lsum1, 16); lsum1 += __shfl_xor(lsum1, 32);
  lsq0  += __shfl_xor(lsq0, 16);  lsq0  += __shfl_xor(lsq0, 32);
  lsq1  += __shfl_xor(lsq1, 16);  lsq1  += __shfl_xor(lsq1, 32);
  if (lane < 16) {
    atomicAdd(&stats[cw + lane], lsum0);
    atomicAdd(&stats[cw + 16 + lane], lsum1);
    atomicAdd(&stats[128 + cw + lane], lsq0);
    atomicAdd(&stats[128 + cw + 16 + lane], lsq1);
  }
}

__global__ void bn_finalize(float* __restrict__ stats,
                            const float* __restrict__ gamma,
                            const float* __restrict__ beta)
{
  const int cc = threadIdx.x;
  const float inv_n = 1.0f / (float)NN;
  const float mu = stats[cc] * inv_n;
  float var = stats[128 + cc] * inv_n - mu * mu;
  var = fmaxf(var, 0.f);
  const float rs = rsqrtf(var + 1e-5f);
  const float sc = rs * gamma[cc];
  stats[256 + cc] = sc;
  stats[384 + cc] = beta[cc] - mu * sc;
}

__global__ __launch_bounds__(256) void bn_apply_bf16(
    const float* __restrict__ h, const float* __restrict__ stats,
    unsigned short* __restrict__ hb)
{
  const int idx = blockIdx.x * 256 + threadIdx.x;
  const int c4 = (idx & 31) * 4;
  const float4 sc = *(const float4*)&stats[256 + c4];
  const float4 sh = *(const float4*)&stats[384 + c4];
  const float4 v = ((const float4*)h)[idx];
  const float r0 = fmaxf(fmaf(v.x, sc.x, sh.x), 0.f);
  const float r1 = fmaxf(fmaf(v.y, sc.y, sh.y), 0.f);
  const float r2 = fmaxf(fmaf(v.z, sc.z, sh.z), 0.f);
  const float r3 = fmaxf(fmaf(v.w, sc.w, sh.w), 0.f);
  uint2 o;
  o.x = pack2(r0, r1);
  o.y = pack2(r2, r3);
  ((uint2*)hb)[idx] = o;
}

// ---------------------------------------------------------------------------
// Fused BN-apply + head: out = sigmoid(relu(relu(hpre*sc+sh)@W1+b1)@w2 + b2)
// ---------------------------------------------------------------------------
__global__ __launch_bounds__(256) void head_bn(
    const float* __restrict__ hpre, const float* __restrict__ stats,
    const unsigned short* __restrict__ W1t, const float* __restrict__ b1,
    const float* __restrict__ w2, const float* __restrict__ b2,
    float* __restrict__ out, int nChunks)
{
  __shared__ float pl[4][64];
  const int tid = threadIdx.x;
  const int w = tid >> 6;
  const int lane = tid & 63;
  const int c = lane & 15, g = lane >> 4;
  const int cw = w * 32;

  bf16x8 B1[2][4];
#pragma unroll
  for (int ct = 0; ct < 2; ++ct)
#pragma unroll
    for (int kk = 0; kk < 4; ++kk)
      B1[ct][kk] = *(const bf16x8*)&W1t[(cw + ct * 16 + c) * 128 + kk * 32 + g * 8];
  const float b1c0 = b1[cw + c], b1c1 = b1[cw + 16 + c];
  const float w2c0 = w2[cw + c], w2c1 = w2[cw + 16 + c];
  const float b2v = b2[0];
  float4 scq[4][2], shq[4][2];
#pragma unroll
  for (int kk = 0; kk < 4; ++kk) {
    const int cb = kk * 32 + g * 8;
    scq[kk][0] = *(const float4*)&stats[256 + cb];
    scq[kk][1] = *(const float4*)&stats[256 + cb + 4];
    shq[kk][0] = *(const float4*)&stats[384 + cb];
    shq[kk][1] = *(const float4*)&stats[384 + cb + 4];
  }

  for (int chunk = blockIdx.x; chunk < nChunks; chunk += gridDim.x) {
    const int base = chunk * 64;
    float p[4][4];
#pragma unroll
    for (int nt = 0; nt < 4; ++nt) {
      const int node = base + nt * 16 + c;
      bf16x8 af[4];
#pragma unroll
      for (int kk = 0; kk < 4; ++kk) {
        uint4 u = make_uint4(0u, 0u, 0u, 0u);
        if (node < NN) {
          const float4 v0 = *(const float4*)&hpre[(size_t)node * 128 + kk * 32 + g * 8];
          const float4 v1 = *(const float4*)&hpre[(size_t)node * 128 + kk * 32 + g * 8 + 4];
          const float4 s0 = scq[kk][0], s1 = scq[kk][1];
          const float4 h0 = shq[kk][0], h1 = shq[kk][1];
          u.x = pack2(fmaxf(fmaf(v0.x, s0.x, h0.x), 0.f),
                      fmaxf(fmaf(v0.y, s0.y, h0.y), 0.f));
          u.y = pack2(fmaxf(fmaf(v0.z, s0.z, h0.z), 0.f),
                      fmaxf(fmaf(v0.w, s0.w, h0.w), 0.f));
          u.z = pack2(fmaxf(fmaf(v1.x, s1.x, h1.x), 0.f),
                      fmaxf(fmaf(v1.y, s1.y, h1.y), 0.f));
          u.w = pack2(fmaxf(fmaf(v1.z, s1.z, h1.z), 0.f),
                      fmaxf(fmaf(v1.w, s1.w, h1.w), 0.f));
        }
        union { uint4 u4; bf16x8 v; } cv; cv.u4 = u;
        af[kk] = cv.v;
      }
      f32x4 acc0 = {0.f, 0.f, 0.f, 0.f}, acc1 = {0.f, 0.f, 0.f, 0.f};
#pragma unroll
      for (int kk = 0; kk < 4; ++kk) {
        acc0 = __builtin_amdgcn_mfma_f32_16x16x32_bf16(af[kk], B1[0][kk], acc0, 0, 0, 0);
        acc1 = __builtin_amdgcn_mfma_f32_16x16x32_bf16(af[kk], B1[1][kk], acc1, 0, 0, 0);
      }
#pragma unroll
      for (int j = 0; j < 4; ++j)
        p[nt][j] = fmaxf(acc0[j] + b1c0, 0.f) * w2c0 +
                   fmaxf(acc1[j] + b1c1, 0.f) * w2c1;
    }
#pragma unroll
    for (int dd = 1; dd <= 8; dd <<= 1)
#pragma unroll
      for (int nt = 0; nt < 4; ++nt)
#pragma unroll
        for (int j = 0; j < 4; ++j)
          p[nt][j] += __shfl_xor(p[nt][j], dd);
    if (c == 0) {
#pragma unroll
      for (int nt = 0; nt < 4; ++nt)
#pragma unroll
        for (int j = 0; j < 4; ++j)
          pl[w][nt * 16 + g * 4 + j] = p[nt][j];
    }
    __syncthreads();
    if (tid < 64) {
      const int node = base + tid;
      if (node < NN) {
        const float s = pl[0][tid] + pl[1][tid] + pl[2][tid] + pl[3][tid] + b2v;
        out[node] = 1.f / (1.f + expf(-s));
      }
    }
    __syncthreads();
  }
}

extern "C" void kernel_launch(void* const* d_in, const int* in_sizes, int n_in,
                              void* d_out, int out_size, void* d_ws, size_t ws_size,
                              hipStream_t stream)
{
  const float* x    = (const float*)d_in[0];
  const int*   ei   = (const int*)  d_in[1];
  const float* ea   = (const float*)d_in[2];
  const float* l0We = (const float*)d_in[3];
  const float* l0be = (const float*)d_in[4];
  const float* l0W1 = (const float*)d_in[5];
  const float* l0b1 = (const float*)d_in[6];
  const float* l0W2 = (const float*)d_in[7];
  const float* l0b2 = (const float*)d_in[8];
  const float* l0g  = (const float*)d_in[9];
  const float* l0bt = (const float*)d_in[10];
  const float* l1We = (const float*)d_in[11];
  const float* l1be = (const float*)d_in[12];
  const float* l1W1 = (const float*)d_in[13];
  const float* l1b1 = (const float*)d_in[14];
  const float* l1W2 = (const float*)d_in[15];
  const float* l1b2 = (const float*)d_in[16];
  const float* l1g  = (const float*)d_in[17];
  const float* l1bt = (const float*)d_in[18];
  const float* hW1  = (const float*)d_in[19];
  const float* hb1  = (const float*)d_in[20];
  const float* hW2  = (const float*)d_in[21];
  const float* hb2  = (const float*)d_in[22];
  float* out = (float*)d_out;

  // workspace layout (~201 MB; proven available R9-R15)
  float*  A    = (float*)d_ws;                         // NN*128 f32 (hpre)
  float*  AGG  = A + (size_t)NN * 128;                 // NN*128 f32
  unsigned short* hb = (unsigned short*)(AGG + (size_t)NN * 128);  // NN*128 bf16
  unsigned short* xb = hb + (size_t)NN * 128;          // NN*32 bf16
  uint32* deg     = (uint32*)(xb + (size_t)NN * 32);   // NN
  uint32* cnt     = deg + NN;                          // NN
  uint32* toff    = cnt + NN;                          // NN
  uint32* eoff    = toff + NN;                         // NN
  ull*    counter = (ull*)(eoff + NN);                 // 1 (pad 2)
  int*    snode   = (int*)(counter + 2);               // TMAX
  uint2*  esrc2   = (uint2*)(snode + TMAX);            // NE + 128 pad
  float*  st0     = (float*)(esrc2 + NE + 128);        // 512
  float*  st1     = st0 + 512;                         // 512
  unsigned short* W1t0 = (unsigned short*)(st1 + 512); // 32*128
  unsigned short* W2t0 = W1t0 + 4096;                  // 128*128
  unsigned short* W1t1 = W2t0 + 16384;
  unsigned short* W2t1 = W1t1 + 16384;
  unsigned short* hW1t = W2t1 + 16384;
  unsigned short* Wet0 = hW1t + 16384;                 // 32*16
  unsigned short* Wet1 = Wet0 + 512;                   // 128*16
  unsigned short* eabc = Wet1 + 2048;                  // NE*16 bf16 (51.2 MB)

  const size_t needed = (size_t)((char*)(eabc + (size_t)NE * 16) - (char*)d_ws);
  if (ws_size < needed) return;

  hipMemsetAsync(deg, 0, (size_t)2 * NN * 4, stream);          // deg, cnt
  hipMemsetAsync(counter, 0, 16, stream);
  hipMemsetAsync(snode, 0xFF, (size_t)TMAX * 4, stream);
  hipMemsetAsync(st0, 0, 4096, stream);                        // st0 + st1
  hipMemsetAsync(AGG, 0, (size_t)NN * 32 * 4, stream);         // layer-0 agg

  const int nChunks = (NN + 63) / 64;     // 1563
  const int eBlocks = (NE + 255) / 256;   // 6250

  // one combined conversion launch (5 weights + 2 edge-W + x)
  conv_all<<<16 + 64 * 4 + 2 + 8 + 1563, 256, 0, stream>>>(
      l0W1, l0W2, l1W1, l1W2, hW1, l0We, l1We, x,
      W1t0, W2t0, W1t1, W2t1, hW1t, Wet0, Wet1, xb);

  // CSR build
  hist_kernel<<<eBlocks, 256, 0, stream>>>(ei, deg);
  offsets2_kernel<<<(NN + 255) / 256, 256, 0, stream>>>(deg, toff, eoff, counter);
  snode_fill<<<(NN + 255) / 256, 256, 0, stream>>>(toff, deg, snode);
  fill_kernel<<<eBlocks, 256, 0, stream>>>(ei, eoff, cnt, esrc2);

  // layer 0: gathers ea (long latency) -> depth-3 pipeline
  flat_agg9<32, 2, true, 3><<<NRANGES / 4, 256, 0, stream>>>(
      snode, toff, eoff, deg, esrc2, ea, eabc, xb, Wet0, l0be, counter, AGG);
  mlp_mfma<32, false><<<782, 256, 0, stream>>>(x, (const unsigned short*)nullptr,
      AGG, W1t0, l0b1, W2t0, l0b2, A, st0, nChunks);
  hipMemsetAsync(AGG, 0, (size_t)NN * 128 * 4, stream);   // re-zero for layer 1
  bn_finalize<<<1, 128, 0, stream>>>(st0, l0g, l0bt);
  bn_apply_bf16<<<(NN * 32) / 256, 256, 0, stream>>>(A, st0, hb);

  // layer 1: eabc path (short latency) -> depth-2, fewer regs, more waves
  flat_agg9<128, 8, false, 2><<<NRANGES / 4, 256, 0, stream>>>(
      snode, toff, eoff, deg, esrc2, ea, eabc, hb, Wet1, l1be, counter, AGG);
  mlp_mfma<128, true><<<782, 256, 0, stream>>>((const float*)nullptr, hb,
      AGG, W1t1, l1b1, W2t1, l1b2, A, st1, nChunks);
  bn_finalize<<<1, 128, 0, stream>>>(st1, l1g, l1bt);

  // fused BN-apply + head
  head_bn<<<782, 256, 0, stream>>>(A, st1, hW1t, hb1, hW2, hb2, out, nChunks);
}

// Round 17
// 526.056 us; speedup vs baseline: 1.1005x; 1.0135x over previous
//
#include <hip/hip_runtime.h>

#define NN 100000
#define NE 1600000
#define TMAX 193760           // >= sum ceil(deg/16) worst case (193750)
#define NRANGES 24220         // TMAX / 8

typedef unsigned int uint32;
typedef unsigned long long ull;
typedef __attribute__((ext_vector_type(8))) short bf16x8;
typedef __attribute__((ext_vector_type(4))) float f32x4;

__device__ __forceinline__ unsigned short f2bf(float f) {
  unsigned int u = __float_as_uint(f);
  unsigned int r = (u + 0x7fffu + ((u >> 16) & 1u)) >> 16;  // RNE
  return (unsigned short)r;
}
__device__ __forceinline__ float bf2f(unsigned short u) {
  return __uint_as_float(((unsigned int)u) << 16);
}
__device__ __forceinline__ unsigned int pack2(float a, float b) {
  return (unsigned int)f2bf(a) | ((unsigned int)f2bf(b) << 16);
}
// round-half-up pack of two f32 -> bf16 pair (cheap, ~= RNE for random data)
__device__ __forceinline__ uint32 pack2ru(float a, float b) {
  const uint32 ua = __float_as_uint(a) + 0x8000u;
  const uint32 ub = __float_as_uint(b) + 0x8000u;
  return (ua >> 16) | (ub & 0xffff0000u);
}

// ---------------------------------------------------------------------------
// Combined weight/activation conversion + degree histogram (one launch).
// ---------------------------------------------------------------------------
__device__ __forceinline__ void wconv_body(const float* __restrict__ src,
    unsigned short* __restrict__ dst, int K, int N, int b)
{
  const int i = b * 256 + threadIdx.x;
  if (i < K * N) {
    const int n = i / K, k = i - n * K;
    dst[i] = f2bf(src[k * N + n]);
  }
}

__global__ __launch_bounds__(256) void conv_hist(
    const float* __restrict__ l0W1, const float* __restrict__ l0W2,
    const float* __restrict__ l1W1, const float* __restrict__ l1W2,
    const float* __restrict__ hW1,  const float* __restrict__ l0We,
    const float* __restrict__ l1We, const float* __restrict__ x,
    unsigned short* __restrict__ W1t0, unsigned short* __restrict__ W2t0,
    unsigned short* __restrict__ W1t1, unsigned short* __restrict__ W2t1,
    unsigned short* __restrict__ hW1t, unsigned short* __restrict__ Wet0,
    unsigned short* __restrict__ Wet1, unsigned short* __restrict__ xb,
    const int* __restrict__ ei, uint32* __restrict__ deg)
{
  int b = blockIdx.x;
  if (b < 16)  { wconv_body(l0W1, W1t0, 32, 128, b); return; }  b -= 16;
  if (b < 64)  { wconv_body(l0W2, W2t0, 128, 128, b); return; } b -= 64;
  if (b < 64)  { wconv_body(l1W1, W1t1, 128, 128, b); return; } b -= 64;
  if (b < 64)  { wconv_body(l1W2, W2t1, 128, 128, b); return; } b -= 64;
  if (b < 64)  { wconv_body(hW1,  hW1t, 128, 128, b); return; } b -= 64;
  if (b < 2)   { wconv_body(l0We, Wet0, 16, 32, b); return; }   b -= 2;
  if (b < 8)   { wconv_body(l1We, Wet1, 16, 128, b); return; }  b -= 8;
  if (b < 1563) {
    const int i = b * 256 + threadIdx.x;
    if (i * 8 < NN * 32) {
      const float4 a = ((const float4*)x)[i * 2];
      const float4 d = ((const float4*)x)[i * 2 + 1];
      uint4 o;
      o.x = pack2(a.x, a.y); o.y = pack2(a.z, a.w);
      o.z = pack2(d.x, d.y); o.w = pack2(d.z, d.w);
      ((uint4*)xb)[i] = o;
    }
    return;
  }
  b -= 1563;
  // histogram: 6250 blocks
  const int e = b * 256 + threadIdx.x;
  if (e < NE) atomicAdd(&deg[ei[NE + e]], 1u);
}

// ---------------------------------------------------------------------------
// CSR build: dual prefix scan (tiles, edges) -> snode + fill (merged)
// ---------------------------------------------------------------------------
__global__ __launch_bounds__(256) void offsets2_kernel(
    const uint32* __restrict__ deg, uint32* __restrict__ toff,
    uint32* __restrict__ eoff, ull* __restrict__ counter)
{
  __shared__ ull s[256];
  __shared__ ull base;
  const int tid = threadIdx.x;
  const int n = blockIdx.x * 256 + tid;
  const uint32 d = (n < NN) ? deg[n] : 0u;
  const uint32 tc = (d + 15u) >> 4;
  const ull v = ((ull)tc << 32) | (ull)d;
  s[tid] = v;
  __syncthreads();
#pragma unroll
  for (int st = 1; st < 256; st <<= 1) {
    ull w = (tid >= st) ? s[tid - st] : 0ull;
    __syncthreads();
    s[tid] += w;
    __syncthreads();
  }
  if (tid == 255) base = atomicAdd(counter, s[255]);
  __syncthreads();
  if (n < NN) {
    const ull t = base + (s[tid] - v);
    toff[n] = (uint32)(t >> 32);
    eoff[n] = (uint32)t;
  }
}

// merged: snode map fill (391 blocks) + edge slot fill (6250 blocks)
__global__ __launch_bounds__(256) void snode_and_fill(
    const uint32* __restrict__ toff, const uint32* __restrict__ deg,
    int* __restrict__ snode, const int* __restrict__ ei,
    const uint32* __restrict__ eoff, uint32* __restrict__ cnt,
    uint2* __restrict__ esrc2)
{
  int b = blockIdx.x;
  if (b < (NN + 255) / 256) {
    const int n = b * 256 + threadIdx.x;
    if (n < NN) {
      const uint32 t0 = toff[n];
      const uint32 tc = (deg[n] + 15u) >> 4;
      for (uint32 i = 0; i < tc; ++i) snode[t0 + i] = n;
    }
    return;
  }
  b -= (NN + 255) / 256;
  const int e = b * 256 + threadIdx.x;
  if (e < NE) {
    const int dst = ei[NE + e];
    const uint32 pos = eoff[dst] + atomicAdd(&cnt[dst], 1u);
    esrc2[pos] = make_uint2((uint32)e, (uint32)ei[e]);
  }
}

// ---------------------------------------------------------------------------
// flat_agg9: TRANSPOSED padded-tile aggregate + template pipeline DEPTH.
//  DEPTH=3 for GEA layer 0; DEPTH=2 for layer 1 (R16, unchanged).
// ---------------------------------------------------------------------------
template<int D, int NB, bool GEA, int DEPTH>
__global__ __launch_bounds__(256) void flat_agg9(
    const int* __restrict__ snode, const uint32* __restrict__ toff,
    const uint32* __restrict__ eoff, const uint32* __restrict__ deg,
    const uint2* __restrict__ esrc2, const float* __restrict__ ea,
    unsigned short* __restrict__ eabc,
    const unsigned short* __restrict__ hsrc,
    const unsigned short* __restrict__ Wet, const float* __restrict__ be,
    const ull* __restrict__ tot, float* __restrict__ agg)
{
  const int tid = threadIdx.x;
  const int wid = tid >> 6;
  const int lane = tid & 63;
  const int c = lane & 15;
  const int g = lane >> 4;
  const int range = blockIdx.x * 4 + wid;
  const int tile0 = range * 8;
  const uint32 ntile = (uint32)((*tot) >> 32);
  if ((uint32)tile0 >= ntile) return;   // dead range

  // B fragments (weights): col c -> channel c*NB+ct; k16=be, k17=1.0
  bf16x8 wf[NB];
#pragma unroll
  for (int ct = 0; ct < NB; ++ct) {
    const int ch = c * NB + ct;
    uint4 u = make_uint4(0u, 0u, 0u, 0u);
    if (g < 2) u = *(const uint4*)&Wet[ch * 16 + g * 8];
    else if (g == 2) u.x = (0x3f80u << 16) | (uint32)f2bf(be[ch]);
    union { uint4 u4; bf16x8 v; } cv; cv.u4 = u;
    wf[ct] = cv.v;
  }

  // per-tile metadata on lanes 0..7: pk = d0(7b) | rem(5b,<=16) | flags(2b)
  int sn8 = -1, pk8 = 0, p_ = 0;
  if (lane < 8) {
    sn8 = snode[tile0 + lane];
    if (sn8 >= 0) {
      const uint32 to = toff[sn8], dg = deg[sn8], eo = eoff[sn8];
      const int k = tile0 + lane - (int)to;
      p_ = (int)eo + k * 16;
      int rv = (int)dg - k * 16; if (rv > 16) rv = 16;
      const int fl = (k == 0 ? 1 : 0) |
                     ((k == (int)((dg + 15u) >> 4) - 1) ? 2 : 0);
      pk8 = (rv << 7) | (fl << 12);
    }
  }
  const int p0base = __shfl(p_, 0);   // lane 0 (tile0) is always real
  if (lane < 8 && sn8 >= 0) pk8 |= (p_ - p0base);

  // bulk preload: range spans <= 128 dense slots starting at p0base
  const uint2 q0 = esrc2[(size_t)p0base + lane];
  const uint2 q1 = esrc2[(size_t)p0base + 64 + lane];

  float acc[NB];
#pragma unroll
  for (int ct = 0; ct < NB; ++ct) acc[ct] = 0.f;
  int openNode = -1; bool openFull = false, openClosed = false;

  auto flushOpen = [&](bool storeOK) {
#pragma unroll
    for (int ct = 0; ct < NB; ++ct) {
      acc[ct] += __shfl_xor(acc[ct], 16);
      acc[ct] += __shfl_xor(acc[ct], 32);
    }
    if (g == 0) {
      float* p = &agg[(size_t)openNode * D + c * NB];
      if (storeOK) {
        if constexpr (NB == 8) {
          *(float4*)p = make_float4(acc[0], acc[1], acc[2], acc[3]);
          *(float4*)(p + 4) = make_float4(acc[4], acc[5], acc[6], acc[7]);
        } else {
          *(float2*)p = make_float2(acc[0], acc[1]);
        }
      } else {
#pragma unroll
        for (int ct = 0; ct < NB; ++ct) atomicAdd(p + ct, acc[ct]);
      }
    }
  };

  auto issue = [&](int t, float4& E0, float4& E1, uint4& afu,
                   uint4* h, int& n_, int& mt_) {
    n_ = __shfl(sn8, t);
    mt_ = __shfl(pk8, t);
    const int d0 = mt_ & 127;
    const int rem = (mt_ >> 7) & 31;
    const int idxA = d0 + ((c < rem) ? c : 0);
    if constexpr (GEA) {
      const int liA = idxA & 63;
      const uint32 eA_ = (uint32)__shfl((int)q0.x, liA);
      const uint32 eB_ = (uint32)__shfl((int)q1.x, liA);
      const int e = (int)((idxA & 64) ? eB_ : eA_);
      if (g < 2) {
        E0 = *(const float4*)&ea[(size_t)e * 16 + g * 8];
        E1 = *(const float4*)&ea[(size_t)e * 16 + g * 8 + 4];
      }
    } else {
      if (g < 2) afu = *(const uint4*)&eabc[((size_t)p0base + idxA) * 16 + g * 8];
    }
    // h for this lane's 4 edges (4g..4g+3), channels c*NB..c*NB+NB-1
#pragma unroll
    for (int j = 0; j < 4; ++j) {
      const int cj = 4 * g + j;
      const int idxj = d0 + ((cj < rem) ? cj : 0);
      const int lij = idxj & 63;
      const uint32 s0_ = (uint32)__shfl((int)q0.y, lij);
      const uint32 s1_ = (uint32)__shfl((int)q1.y, lij);
      const int src = (int)((idxj & 64) ? s1_ : s0_);
      if constexpr (D == 128)
        h[j] = *(const uint4*)&hsrc[(size_t)src * 128 + c * 8];
      else
        h[j].x = *(const uint32*)&hsrc[(size_t)src * 32 + c * 2];
    }
  };

  auto compute = [&](const float4 E0, const float4 E1, uint4 afu,
                     const uint4* h, const int n, const int mt) {
    if (n < 0) return;
    const int rem = (mt >> 7) & 31;
    const int fl = mt >> 12;
    if (n != openNode) {
      if (openNode >= 0) {
        flushOpen(openFull);
#pragma unroll
        for (int ct = 0; ct < NB; ++ct) acc[ct] = 0.f;
      }
      openNode = n; openFull = (fl & 1) != 0; openClosed = false;
    }
    if (fl & 2) openClosed = true;
    if constexpr (GEA) {
      afu.x = pack2ru(E0.x, E0.y); afu.y = pack2ru(E0.z, E0.w);
      afu.z = pack2ru(E1.x, E1.y); afu.w = pack2ru(E1.z, E1.w);
      if (g < 2) {
        const int d0 = mt & 127;
        const int idxA = d0 + ((c < rem) ? c : 0);
        *(uint4*)&eabc[((size_t)p0base + idxA) * 16 + g * 8] = afu;
      }
    }
    bf16x8 afv;   // A operand: edge rows; k16=1.0, k17 = poison if invalid
    {
      uint4 u = make_uint4(0u, 0u, 0u, 0u);
      if (g < 2) u = afu;
      else if (g == 2) u.x = 0x3f80u | (((c < rem) ? 0u : 0xFE96u) << 16);
      union { uint4 u4; bf16x8 v; } cv; cv.u4 = u; afv = cv.v;
    }
#pragma unroll
    for (int ct = 0; ct < NB; ++ct) {
      f32x4 pre = __builtin_amdgcn_mfma_f32_16x16x32_bf16(
          afv, wf[ct], (f32x4){0.f, 0.f, 0.f, 0.f}, 0, 0, 0);
#pragma unroll
      for (int j = 0; j < 4; ++j) {
        uint32 wv;
        if constexpr (D == 128) {
          const int q = ct >> 1;
          wv = (q == 0) ? h[j].x : (q == 1) ? h[j].y : (q == 2) ? h[j].z : h[j].w;
        } else {
          wv = h[j].x;
        }
        const unsigned short hu = (unsigned short)((ct & 1) ? (wv >> 16)
                                                            : (wv & 0xffffu));
        acc[ct] += fmaxf(pre[j] + bf2f(hu), 0.f);
      }
    }
  };

  float4 eA0, eA1, eB0, eB1, eC0, eC1;
  uint4 aA = make_uint4(0,0,0,0), aB = make_uint4(0,0,0,0), aC = make_uint4(0,0,0,0);
  uint4 hA[4], hB[4], hC[4];
#pragma unroll
  for (int j = 0; j < 4; ++j) {
    hA[j] = make_uint4(0,0,0,0); hB[j] = make_uint4(0,0,0,0);
    hC[j] = make_uint4(0,0,0,0);
  }
  int nA = -1, mA = 0, nB_ = -1, mB = 0, nC = -1, mC = 0;

  if constexpr (DEPTH == 3) {
    issue(0, eA0, eA1, aA, hA, nA, mA);
    issue(1, eB0, eB1, aB, hB, nB_, mB);
    issue(2, eC0, eC1, aC, hC, nC, mC);
    compute(eA0, eA1, aA, hA, nA, mA); issue(3, eA0, eA1, aA, hA, nA, mA);
    compute(eB0, eB1, aB, hB, nB_, mB); issue(4, eB0, eB1, aB, hB, nB_, mB);
    compute(eC0, eC1, aC, hC, nC, mC); issue(5, eC0, eC1, aC, hC, nC, mC);
    compute(eA0, eA1, aA, hA, nA, mA); issue(6, eA0, eA1, aA, hA, nA, mA);
    compute(eB0, eB1, aB, hB, nB_, mB); issue(7, eB0, eB1, aB, hB, nB_, mB);
    compute(eC0, eC1, aC, hC, nC, mC);
    compute(eA0, eA1, aA, hA, nA, mA);
    compute(eB0, eB1, aB, hB, nB_, mB);
  } else {
    issue(0, eA0, eA1, aA, hA, nA, mA);
    issue(1, eB0, eB1, aB, hB, nB_, mB);
    compute(eA0, eA1, aA, hA, nA, mA); issue(2, eA0, eA1, aA, hA, nA, mA);
    compute(eB0, eB1, aB, hB, nB_, mB); issue(3, eB0, eB1, aB, hB, nB_, mB);
    compute(eA0, eA1, aA, hA, nA, mA); issue(4, eA0, eA1, aA, hA, nA, mA);
    compute(eB0, eB1, aB, hB, nB_, mB); issue(5, eB0, eB1, aB, hB, nB_, mB);
    compute(eA0, eA1, aA, hA, nA, mA); issue(6, eA0, eA1, aA, hA, nA, mA);
    compute(eB0, eB1, aB, hB, nB_, mB); issue(7, eB0, eB1, aB, hB, nB_, mB);
    compute(eA0, eA1, aA, hA, nA, mA);
    compute(eB0, eB1, aB, hB, nB_, mB);
  }
  if (openNode >= 0) flushOpen(openFull && openClosed);
}

// ---------------------------------------------------------------------------
// MFMA node MLP: out = relu((a+agg)@W1+b1)@W2+b2, + BN stats.
// OUTB: write pre-BN output as bf16 (stats still from f32).
// ---------------------------------------------------------------------------
template<int DIN, bool ABF16, bool OUTB>
__global__ __launch_bounds__(256) void mlp_mfma(
    const float* __restrict__ a32, const unsigned short* __restrict__ abf,
    const float* __restrict__ agg,
    const unsigned short* __restrict__ W1t, const float* __restrict__ b1,
    const unsigned short* __restrict__ W2t, const float* __restrict__ b2,
    float* __restrict__ outp, unsigned short* __restrict__ outpb,
    float* __restrict__ stats, int nChunks)
{
  constexpr int P1 = (DIN == 128) ? 136 : 40;
  constexpr int KS1 = DIN / 32;
  __shared__ __align__(16) unsigned short hin[64 * P1];
  __shared__ __align__(16) unsigned short tls[64 * 136];
  const int tid = threadIdx.x;
  const int w = tid >> 6;
  const int lane = tid & 63;
  const int c = lane & 15, g = lane >> 4;
  const int cw = w * 32;

  bf16x8 B1[2][KS1], B2[2][4];
#pragma unroll
  for (int ct = 0; ct < 2; ++ct)
#pragma unroll
    for (int kk = 0; kk < KS1; ++kk)
      B1[ct][kk] = *(const bf16x8*)&W1t[(cw + ct * 16 + c) * DIN + kk * 32 + g * 8];
#pragma unroll
  for (int ct = 0; ct < 2; ++ct)
#pragma unroll
    for (int kk = 0; kk < 4; ++kk)
      B2[ct][kk] = *(const bf16x8*)&W2t[(cw + ct * 16 + c) * 128 + kk * 32 + g * 8];
  const float b1c0 = b1[cw + c], b1c1 = b1[cw + 16 + c];
  const float b2c0 = b2[cw + c], b2c1 = b2[cw + 16 + c];
  float lsum0 = 0.f, lsum1 = 0.f, lsq0 = 0.f, lsq1 = 0.f;

  for (int chunk = blockIdx.x; chunk < nChunks; chunk += gridDim.x) {
    const int base = chunk * 64;
    if constexpr (DIN == 128) {
#pragma unroll
      for (int p = 0; p < 4; ++p) {
        const int idx = tid + 256 * p;
        const int n = idx >> 4, k8 = idx & 15;
        const int node = base + n;
        uint4 ov = make_uint4(0u, 0u, 0u, 0u);
        if (node < NN) {
          const float4 g0 = *(const float4*)&agg[node * 128 + k8 * 8];
          const float4 g1 = *(const float4*)&agg[node * 128 + k8 * 8 + 4];
          const uint4 hv = *(const uint4*)&abf[node * 128 + k8 * 8];
          ov.x = pack2(bf2f((unsigned short)(hv.x & 0xffffu)) + g0.x,
                       bf2f((unsigned short)(hv.x >> 16)) + g0.y);
          ov.y = pack2(bf2f((unsigned short)(hv.y & 0xffffu)) + g0.z,
                       bf2f((unsigned short)(hv.y >> 16)) + g0.w);
          ov.z = pack2(bf2f((unsigned short)(hv.z & 0xffffu)) + g1.x,
                       bf2f((unsigned short)(hv.z >> 16)) + g1.y);
          ov.w = pack2(bf2f((unsigned short)(hv.w & 0xffffu)) + g1.z,
                       bf2f((unsigned short)(hv.w >> 16)) + g1.w);
        }
        *(uint4*)&hin[n * P1 + k8 * 8] = ov;
      }
    } else {
      const int n = tid >> 2, k8 = tid & 3;
      const int node = base + n;
      uint4 ov = make_uint4(0u, 0u, 0u, 0u);
      if (node < NN) {
        const float4 x0 = *(const float4*)&a32[node * 32 + k8 * 8];
        const float4 x1 = *(const float4*)&a32[node * 32 + k8 * 8 + 4];
        const float4 g0 = *(const float4*)&agg[node * 32 + k8 * 8];
        const float4 g1 = *(const float4*)&agg[node * 32 + k8 * 8 + 4];
        ov.x = pack2(x0.x + g0.x, x0.y + g0.y);
        ov.y = pack2(x0.z + g0.z, x0.w + g0.w);
        ov.z = pack2(x1.x + g1.x, x1.y + g1.y);
        ov.w = pack2(x1.z + g1.z, x1.w + g1.w);
      }
      *(uint4*)&hin[n * P1 + k8 * 8] = ov;
    }
    __syncthreads();
#pragma unroll
    for (int nt = 0; nt < 4; ++nt) {
      bf16x8 af[KS1];
#pragma unroll
      for (int kk = 0; kk < KS1; ++kk)
        af[kk] = *(const bf16x8*)&hin[(nt * 16 + c) * P1 + kk * 32 + g * 8];
      f32x4 acc0 = {0.f, 0.f, 0.f, 0.f}, acc1 = {0.f, 0.f, 0.f, 0.f};
#pragma unroll
      for (int kk = 0; kk < KS1; ++kk) {
        acc0 = __builtin_amdgcn_mfma_f32_16x16x32_bf16(af[kk], B1[0][kk], acc0, 0, 0, 0);
        acc1 = __builtin_amdgcn_mfma_f32_16x16x32_bf16(af[kk], B1[1][kk], acc1, 0, 0, 0);
      }
#pragma unroll
      for (int j = 0; j < 4; ++j) {
        const int row = nt * 16 + g * 4 + j;
        tls[row * 136 + cw + c]      = f2bf(fmaxf(acc0[j] + b1c0, 0.f));
        tls[row * 136 + cw + 16 + c] = f2bf(fmaxf(acc1[j] + b1c1, 0.f));
      }
    }
    __syncthreads();
#pragma unroll
    for (int nt = 0; nt < 4; ++nt) {
      bf16x8 af[4];
#pragma unroll
      for (int kk = 0; kk < 4; ++kk)
        af[kk] = *(const bf16x8*)&tls[(nt * 16 + c) * 136 + kk * 32 + g * 8];
      f32x4 acc0 = {0.f, 0.f, 0.f, 0.f}, acc1 = {0.f, 0.f, 0.f, 0.f};
#pragma unroll
      for (int kk = 0; kk < 4; ++kk) {
        acc0 = __builtin_amdgcn_mfma_f32_16x16x32_bf16(af[kk], B2[0][kk], acc0, 0, 0, 0);
        acc1 = __builtin_amdgcn_mfma_f32_16x16x32_bf16(af[kk], B2[1][kk], acc1, 0, 0, 0);
      }
#pragma unroll
      for (int j = 0; j < 4; ++j) {
        const int node = base + nt * 16 + g * 4 + j;
        if (node < NN) {
          const float v0 = acc0[j] + b2c0;
          const float v1 = acc1[j] + b2c1;
          if constexpr (OUTB) {
            outpb[(size_t)node * 128 + cw + c] = f2bf(v0);
            outpb[(size_t)node * 128 + cw + 16 + c] = f2bf(v1);
          } else {
            outp[(size_t)node * 128 + cw + c] = v0;
            outp[(size_t)node * 128 + cw + 16 + c] = v1;
          }
          lsum0 += v0; lsq0 += v0 * v0;
          lsum1 += v1; lsq1 += v1 * v1;
        }
      }
    }
  }
  lsum0 += __shfl_xor(lsum0, 16); lsum0 += __shfl_xor(lsum0, 32);
  lsum1 += __shfl_xor(lsum1, 16); lsum1 += __shfl_xor(lsum1, 32);
  lsq0  += __shfl_xor(lsq0, 16);  lsq0  += __shfl_xor(lsq0, 32);
  lsq1  += __shfl_xor(lsq1, 16);  lsq1  += __shfl_xor(lsq1, 32);
  if (lane < 16) {
    atomicAdd(&stats[cw + lane], lsum0);
    atomicAdd(&stats[cw + 16 + lane], lsum1);
    atomicAdd(&stats[128 + cw + lane], lsq0);
    atomicAdd(&stats[128 + cw + 16 + lane], lsq1);
  }
}

__global__ void bn_finalize(float* __restrict__ stats,
                            const float* __restrict__ gamma,
                            const float* __restrict__ beta)
{
  const int cc = threadIdx.x;
  const float inv_n = 1.0f / (float)NN;
  const float mu = stats[cc] * inv_n;
  float var = stats[128 + cc] * inv_n - mu * mu;
  var = fmaxf(var, 0.f);
  const float rs = rsqrtf(var + 1e-5f);
  const float sc = rs * gamma[cc];
  stats[256 + cc] = sc;
  stats[384 + cc] = beta[cc] - mu * sc;
}

__global__ __launch_bounds__(256) void bn_apply_bf16(
    const float* __restrict__ h, const float* __restrict__ stats,
    unsigned short* __restrict__ hb)
{
  const int idx = blockIdx.x * 256 + threadIdx.x;
  const int c4 = (idx & 31) * 4;
  const float4 sc = *(const float4*)&stats[256 + c4];
  const float4 sh = *(const float4*)&stats[384 + c4];
  const float4 v = ((const float4*)h)[idx];
  const float r0 = fmaxf(fmaf(v.x, sc.x, sh.x), 0.f);
  const float r1 = fmaxf(fmaf(v.y, sc.y, sh.y), 0.f);
  const float r2 = fmaxf(fmaf(v.z, sc.z, sh.z), 0.f);
  const float r3 = fmaxf(fmaf(v.w, sc.w, sh.w), 0.f);
  uint2 o;
  o.x = pack2(r0, r1);
  o.y = pack2(r2, r3);
  ((uint2*)hb)[idx] = o;
}

// ---------------------------------------------------------------------------
// Fused BN-apply + head, hpre in BF16:
//   out = sigmoid(relu(relu(bf16(hpre)*sc+sh)@W1+b1)@w2 + b2)
// ---------------------------------------------------------------------------
__global__ __launch_bounds__(256) void head_bn(
    const unsigned short* __restrict__ hpreb, const float* __restrict__ stats,
    const unsigned short* __restrict__ W1t, const float* __restrict__ b1,
    const float* __restrict__ w2, const float* __restrict__ b2,
    float* __restrict__ out, int nChunks)
{
  __shared__ float pl[4][64];
  const int tid = threadIdx.x;
  const int w = tid >> 6;
  const int lane = tid & 63;
  const int c = lane & 15, g = lane >> 4;
  const int cw = w * 32;

  bf16x8 B1[2][4];
#pragma unroll
  for (int ct = 0; ct < 2; ++ct)
#pragma unroll
    for (int kk = 0; kk < 4; ++kk)
      B1[ct][kk] = *(const bf16x8*)&W1t[(cw + ct * 16 + c) * 128 + kk * 32 + g * 8];
  const float b1c0 = b1[cw + c], b1c1 = b1[cw + 16 + c];
  const float w2c0 = w2[cw + c], w2c1 = w2[cw + 16 + c];
  const float b2v = b2[0];
  float4 scq[4][2], shq[4][2];
#pragma unroll
  for (int kk = 0; kk < 4; ++kk) {
    const int cb = kk * 32 + g * 8;
    scq[kk][0] = *(const float4*)&stats[256 + cb];
    scq[kk][1] = *(const float4*)&stats[256 + cb + 4];
    shq[kk][0] = *(const float4*)&stats[384 + cb];
    shq[kk][1] = *(const float4*)&stats[384 + cb + 4];
  }

  for (int chunk = blockIdx.x; chunk < nChunks; chunk += gridDim.x) {
    const int base = chunk * 64;
    float p[4][4];
#pragma unroll
    for (int nt = 0; nt < 4; ++nt) {
      const int node = base + nt * 16 + c;
      bf16x8 af[4];
#pragma unroll
      for (int kk = 0; kk < 4; ++kk) {
        uint4 u = make_uint4(0u, 0u, 0u, 0u);
        if (node < NN) {
          const uint4 hv = *(const uint4*)&hpreb[(size_t)node * 128 + kk * 32 + g * 8];
          const float4 s0 = scq[kk][0], s1 = scq[kk][1];
          const float4 h0 = shq[kk][0], h1 = shq[kk][1];
          const float t0 = bf2f((unsigned short)(hv.x & 0xffffu));
          const float t1 = bf2f((unsigned short)(hv.x >> 16));
          const float t2 = bf2f((unsigned short)(hv.y & 0xffffu));
          const float t3 = bf2f((unsigned short)(hv.y >> 16));
          const float t4 = bf2f((unsigned short)(hv.z & 0xffffu));
          const float t5 = bf2f((unsigned short)(hv.z >> 16));
          const float t6 = bf2f((unsigned short)(hv.w & 0xffffu));
          const float t7 = bf2f((unsigned short)(hv.w >> 16));
          u.x = pack2(fmaxf(fmaf(t0, s0.x, h0.x), 0.f),
                      fmaxf(fmaf(t1, s0.y, h0.y), 0.f));
          u.y = pack2(fmaxf(fmaf(t2, s0.z, h0.z), 0.f),
                      fmaxf(fmaf(t3, s0.w, h0.w), 0.f));
          u.z = pack2(fmaxf(fmaf(t4, s1.x, h1.x), 0.f),
                      fmaxf(fmaf(t5, s1.y, h1.y), 0.f));
          u.w = pack2(fmaxf(fmaf(t6, s1.z, h1.z), 0.f),
                      fmaxf(fmaf(t7, s1.w, h1.w), 0.f));
        }
        union { uint4 u4; bf16x8 v; } cv; cv.u4 = u;
        af[kk] = cv.v;
      }
      f32x4 acc0 = {0.f, 0.f, 0.f, 0.f}, acc1 = {0.f, 0.f, 0.f, 0.f};
#pragma unroll
      for (int kk = 0; kk < 4; ++kk) {
        acc0 = __builtin_amdgcn_mfma_f32_16x16x32_bf16(af[kk], B1[0][kk], acc0, 0, 0, 0);
        acc1 = __builtin_amdgcn_mfma_f32_16x16x32_bf16(af[kk], B1[1][kk], acc1, 0, 0, 0);
      }
#pragma unroll
      for (int j = 0; j < 4; ++j)
        p[nt][j] = fmaxf(acc0[j] + b1c0, 0.f) * w2c0 +
                   fmaxf(acc1[j] + b1c1, 0.f) * w2c1;
    }
#pragma unroll
    for (int dd = 1; dd <= 8; dd <<= 1)
#pragma unroll
      for (int nt = 0; nt < 4; ++nt)
#pragma unroll
        for (int j = 0; j < 4; ++j)
          p[nt][j] += __shfl_xor(p[nt][j], dd);
    if (c == 0) {
#pragma unroll
      for (int nt = 0; nt < 4; ++nt)
#pragma unroll
        for (int j = 0; j < 4; ++j)
          pl[w][nt * 16 + g * 4 + j] = p[nt][j];
    }
    __syncthreads();
    if (tid < 64) {
      const int node = base + tid;
      if (node < NN) {
        const float s = pl[0][tid] + pl[1][tid] + pl[2][tid] + pl[3][tid] + b2v;
        out[node] = 1.f / (1.f + expf(-s));
      }
    }
    __syncthreads();
  }
}

extern "C" void kernel_launch(void* const* d_in, const int* in_sizes, int n_in,
                              void* d_out, int out_size, void* d_ws, size_t ws_size,
                              hipStream_t stream)
{
  const float* x    = (const float*)d_in[0];
  const int*   ei   = (const int*)  d_in[1];
  const float* ea   = (const float*)d_in[2];
  const float* l0We = (const float*)d_in[3];
  const float* l0be = (const float*)d_in[4];
  const float* l0W1 = (const float*)d_in[5];
  const float* l0b1 = (const float*)d_in[6];
  const float* l0W2 = (const float*)d_in[7];
  const float* l0b2 = (const float*)d_in[8];
  const float* l0g  = (const float*)d_in[9];
  const float* l0bt = (const float*)d_in[10];
  const float* l1We = (const float*)d_in[11];
  const float* l1be = (const float*)d_in[12];
  const float* l1W1 = (const float*)d_in[13];
  const float* l1b1 = (const float*)d_in[14];
  const float* l1W2 = (const float*)d_in[15];
  const float* l1b2 = (const float*)d_in[16];
  const float* l1g  = (const float*)d_in[17];
  const float* l1bt = (const float*)d_in[18];
  const float* hW1  = (const float*)d_in[19];
  const float* hb1  = (const float*)d_in[20];
  const float* hW2  = (const float*)d_in[21];
  const float* hb2  = (const float*)d_in[22];
  float* out = (float*)d_out;

  // workspace layout (~201 MB; proven available R9-R16)
  float*  A    = (float*)d_ws;                         // NN*128 f32 (hpre0) / bf16 hpre1
  float*  AGG  = A + (size_t)NN * 128;                 // NN*128 f32
  unsigned short* hb = (unsigned short*)(AGG + (size_t)NN * 128);  // NN*128 bf16
  unsigned short* xb = hb + (size_t)NN * 128;          // NN*32 bf16
  uint32* deg     = (uint32*)(xb + (size_t)NN * 32);   // NN
  uint32* cnt     = deg + NN;                          // NN
  uint32* toff    = cnt + NN;                          // NN
  uint32* eoff    = toff + NN;                         // NN
  ull*    counter = (ull*)(eoff + NN);                 // 1 (pad 2)
  int*    snode   = (int*)(counter + 2);               // TMAX
  uint2*  esrc2   = (uint2*)(snode + TMAX);            // NE + 128 pad
  float*  st0     = (float*)(esrc2 + NE + 128);        // 512
  float*  st1     = st0 + 512;                         // 512
  unsigned short* W1t0 = (unsigned short*)(st1 + 512); // 32*128
  unsigned short* W2t0 = W1t0 + 4096;                  // 128*128
  unsigned short* W1t1 = W2t0 + 16384;
  unsigned short* W2t1 = W1t1 + 16384;
  unsigned short* hW1t = W2t1 + 16384;
  unsigned short* Wet0 = hW1t + 16384;                 // 32*16
  unsigned short* Wet1 = Wet0 + 512;                   // 128*16
  unsigned short* eabc = Wet1 + 2048;                  // NE*16 bf16 (51.2 MB)
  unsigned short* Ab = (unsigned short*)A;             // bf16 view (hpre1)

  const size_t needed = (size_t)((char*)(eabc + (size_t)NE * 16) - (char*)d_ws);
  if (ws_size < needed) return;

  hipMemsetAsync(deg, 0, (size_t)2 * NN * 4, stream);          // deg, cnt
  hipMemsetAsync(counter, 0, 16, stream);
  hipMemsetAsync(snode, 0xFF, (size_t)TMAX * 4, stream);
  hipMemsetAsync(st0, 0, 4096, stream);                        // st0 + st1
  hipMemsetAsync(AGG, 0, (size_t)NN * 32 * 4, stream);         // layer-0 agg

  const int nChunks = (NN + 63) / 64;     // 1563
  const int eBlocks = (NE + 255) / 256;   // 6250
  const int nBlocks = (NN + 255) / 256;   // 391

  // combined conversion + degree histogram (one launch)
  conv_hist<<<16 + 64 * 4 + 2 + 8 + 1563 + eBlocks, 256, 0, stream>>>(
      l0W1, l0W2, l1W1, l1W2, hW1, l0We, l1We, x,
      W1t0, W2t0, W1t1, W2t1, hW1t, Wet0, Wet1, xb, ei, deg);

  offsets2_kernel<<<nBlocks, 256, 0, stream>>>(deg, toff, eoff, counter);
  snode_and_fill<<<nBlocks + eBlocks, 256, 0, stream>>>(
      toff, deg, snode, ei, eoff, cnt, esrc2);

  // layer 0: gathers ea (long latency) -> depth-3 pipeline
  flat_agg9<32, 2, true, 3><<<NRANGES / 4, 256, 0, stream>>>(
      snode, toff, eoff, deg, esrc2, ea, eabc, xb, Wet0, l0be, counter, AGG);
  mlp_mfma<32, false, false><<<782, 256, 0, stream>>>(
      x, (const unsigned short*)nullptr, AGG, W1t0, l0b1, W2t0, l0b2,
      A, (unsigned short*)nullptr, st0, nChunks);
  hipMemsetAsync(AGG, 0, (size_t)NN * 128 * 4, stream);   // re-zero for layer 1
  bn_finalize<<<1, 128, 0, stream>>>(st0, l0g, l0bt);
  bn_apply_bf16<<<(NN * 32) / 256, 256, 0, stream>>>(A, st0, hb);

  // layer 1: eabc path (short latency) -> depth-2; writes hpre1 as BF16
  flat_agg9<128, 8, false, 2><<<NRANGES / 4, 256, 0, stream>>>(
      snode, toff, eoff, deg, esrc2, ea, eabc, hb, Wet1, l1be, counter, AGG);
  mlp_mfma<128, true, true><<<782, 256, 0, stream>>>(
      (const float*)nullptr, hb, AGG, W1t1, l1b1, W2t1, l1b2,
      (float*)nullptr, Ab, st1, nChunks);
  bn_finalize<<<1, 128, 0, stream>>>(st1, l1g, l1bt);

  // fused BN-apply + head (bf16 hpre)
  head_bn<<<782, 256, 0, stream>>>(Ab, st1, hW1t, hb1, hW2, hb2, out, nChunks);
}

// Round 18
// 514.277 us; speedup vs baseline: 1.1257x; 1.0229x over previous
//
#include <hip/hip_runtime.h>

#define NN 100000
#define NE 1600000
#define TMAX 193760           // >= sum ceil(deg/16) worst case (193750)
#define NRANGES 24220         // TMAX / 8

typedef unsigned int uint32;
typedef unsigned long long ull;
typedef __attribute__((ext_vector_type(8))) short bf16x8;
typedef __attribute__((ext_vector_type(4))) float f32x4;

__device__ __forceinline__ unsigned short f2bf(float f) {
  unsigned int u = __float_as_uint(f);
  unsigned int r = (u + 0x7fffu + ((u >> 16) & 1u)) >> 16;  // RNE
  return (unsigned short)r;
}
__device__ __forceinline__ float bf2f(unsigned short u) {
  return __uint_as_float(((unsigned int)u) << 16);
}
__device__ __forceinline__ unsigned int pack2(float a, float b) {
  return (unsigned int)f2bf(a) | ((unsigned int)f2bf(b) << 16);
}
// round-half-up pack of two f32 -> bf16 pair (cheap, ~= RNE for random data)
__device__ __forceinline__ uint32 pack2ru(float a, float b) {
  const uint32 ua = __float_as_uint(a) + 0x8000u;
  const uint32 ub = __float_as_uint(b) + 0x8000u;
  return (ua >> 16) | (ub & 0xffff0000u);
}

// ---------------------------------------------------------------------------
// Combined weight/activation conversion + degree histogram (one launch).
// ---------------------------------------------------------------------------
__device__ __forceinline__ void wconv_body(const float* __restrict__ src,
    unsigned short* __restrict__ dst, int K, int N, int b)
{
  const int i = b * 256 + threadIdx.x;
  if (i < K * N) {
    const int n = i / K, k = i - n * K;
    dst[i] = f2bf(src[k * N + n]);
  }
}

__global__ __launch_bounds__(256) void conv_hist(
    const float* __restrict__ l0W1, const float* __restrict__ l0W2,
    const float* __restrict__ l1W1, const float* __restrict__ l1W2,
    const float* __restrict__ hW1,  const float* __restrict__ l0We,
    const float* __restrict__ l1We, const float* __restrict__ x,
    unsigned short* __restrict__ W1t0, unsigned short* __restrict__ W2t0,
    unsigned short* __restrict__ W1t1, unsigned short* __restrict__ W2t1,
    unsigned short* __restrict__ hW1t, unsigned short* __restrict__ Wet0,
    unsigned short* __restrict__ Wet1, unsigned short* __restrict__ xb,
    const int* __restrict__ ei, uint32* __restrict__ deg)
{
  int b = blockIdx.x;
  if (b < 16)  { wconv_body(l0W1, W1t0, 32, 128, b); return; }  b -= 16;
  if (b < 64)  { wconv_body(l0W2, W2t0, 128, 128, b); return; } b -= 64;
  if (b < 64)  { wconv_body(l1W1, W1t1, 128, 128, b); return; } b -= 64;
  if (b < 64)  { wconv_body(l1W2, W2t1, 128, 128, b); return; } b -= 64;
  if (b < 64)  { wconv_body(hW1,  hW1t, 128, 128, b); return; } b -= 64;
  if (b < 2)   { wconv_body(l0We, Wet0, 16, 32, b); return; }   b -= 2;
  if (b < 8)   { wconv_body(l1We, Wet1, 16, 128, b); return; }  b -= 8;
  if (b < 1563) {
    const int i = b * 256 + threadIdx.x;
    if (i * 8 < NN * 32) {
      const float4 a = ((const float4*)x)[i * 2];
      const float4 d = ((const float4*)x)[i * 2 + 1];
      uint4 o;
      o.x = pack2(a.x, a.y); o.y = pack2(a.z, a.w);
      o.z = pack2(d.x, d.y); o.w = pack2(d.z, d.w);
      ((uint4*)xb)[i] = o;
    }
    return;
  }
  b -= 1563;
  const int e = b * 256 + threadIdx.x;
  if (e < NE) atomicAdd(&deg[ei[NE + e]], 1u);
}

// ---------------------------------------------------------------------------
// CSR build: dual prefix scan (tiles, edges) -> snode + fill (merged)
// ---------------------------------------------------------------------------
__global__ __launch_bounds__(256) void offsets2_kernel(
    const uint32* __restrict__ deg, uint32* __restrict__ toff,
    uint32* __restrict__ eoff, ull* __restrict__ counter)
{
  __shared__ ull s[256];
  __shared__ ull base;
  const int tid = threadIdx.x;
  const int n = blockIdx.x * 256 + tid;
  const uint32 d = (n < NN) ? deg[n] : 0u;
  const uint32 tc = (d + 15u) >> 4;
  const ull v = ((ull)tc << 32) | (ull)d;
  s[tid] = v;
  __syncthreads();
#pragma unroll
  for (int st = 1; st < 256; st <<= 1) {
    ull w = (tid >= st) ? s[tid - st] : 0ull;
    __syncthreads();
    s[tid] += w;
    __syncthreads();
  }
  if (tid == 255) base = atomicAdd(counter, s[255]);
  __syncthreads();
  if (n < NN) {
    const ull t = base + (s[tid] - v);
    toff[n] = (uint32)(t >> 32);
    eoff[n] = (uint32)t;
  }
}

// merged: snode map fill (391 blocks) + edge slot fill (6250 blocks)
__global__ __launch_bounds__(256) void snode_and_fill(
    const uint32* __restrict__ toff, const uint32* __restrict__ deg,
    int* __restrict__ snode, const int* __restrict__ ei,
    const uint32* __restrict__ eoff, uint32* __restrict__ cnt,
    uint2* __restrict__ esrc2)
{
  int b = blockIdx.x;
  if (b < (NN + 255) / 256) {
    const int n = b * 256 + threadIdx.x;
    if (n < NN) {
      const uint32 t0 = toff[n];
      const uint32 tc = (deg[n] + 15u) >> 4;
      for (uint32 i = 0; i < tc; ++i) snode[t0 + i] = n;
    }
    return;
  }
  b -= (NN + 255) / 256;
  const int e = b * 256 + threadIdx.x;
  if (e < NE) {
    const int dst = ei[NE + e];
    const uint32 pos = eoff[dst] + atomicAdd(&cnt[dst], 1u);
    esrc2[pos] = make_uint2((uint32)e, (uint32)ei[e]);
  }
}

// ---------------------------------------------------------------------------
// flat_agg9: TRANSPOSED padded-tile aggregate + template pipeline DEPTH.
//  DEPTH=3 for GEA layer 0; DEPTH=2 for layer 1 (unchanged from R16).
// ---------------------------------------------------------------------------
template<int D, int NB, bool GEA, int DEPTH>
__global__ __launch_bounds__(256) void flat_agg9(
    const int* __restrict__ snode, const uint32* __restrict__ toff,
    const uint32* __restrict__ eoff, const uint32* __restrict__ deg,
    const uint2* __restrict__ esrc2, const float* __restrict__ ea,
    unsigned short* __restrict__ eabc,
    const unsigned short* __restrict__ hsrc,
    const unsigned short* __restrict__ Wet, const float* __restrict__ be,
    const ull* __restrict__ tot, float* __restrict__ agg)
{
  const int tid = threadIdx.x;
  const int wid = tid >> 6;
  const int lane = tid & 63;
  const int c = lane & 15;
  const int g = lane >> 4;
  const int range = blockIdx.x * 4 + wid;
  const int tile0 = range * 8;
  const uint32 ntile = (uint32)((*tot) >> 32);
  if ((uint32)tile0 >= ntile) return;   // dead range

  // B fragments (weights): col c -> channel c*NB+ct; k16=be, k17=1.0
  bf16x8 wf[NB];
#pragma unroll
  for (int ct = 0; ct < NB; ++ct) {
    const int ch = c * NB + ct;
    uint4 u = make_uint4(0u, 0u, 0u, 0u);
    if (g < 2) u = *(const uint4*)&Wet[ch * 16 + g * 8];
    else if (g == 2) u.x = (0x3f80u << 16) | (uint32)f2bf(be[ch]);
    union { uint4 u4; bf16x8 v; } cv; cv.u4 = u;
    wf[ct] = cv.v;
  }

  // per-tile metadata on lanes 0..7: pk = d0(7b) | rem(5b,<=16) | flags(2b)
  int sn8 = -1, pk8 = 0, p_ = 0;
  if (lane < 8) {
    sn8 = snode[tile0 + lane];
    if (sn8 >= 0) {
      const uint32 to = toff[sn8], dg = deg[sn8], eo = eoff[sn8];
      const int k = tile0 + lane - (int)to;
      p_ = (int)eo + k * 16;
      int rv = (int)dg - k * 16; if (rv > 16) rv = 16;
      const int fl = (k == 0 ? 1 : 0) |
                     ((k == (int)((dg + 15u) >> 4) - 1) ? 2 : 0);
      pk8 = (rv << 7) | (fl << 12);
    }
  }
  const int p0base = __shfl(p_, 0);   // lane 0 (tile0) is always real
  if (lane < 8 && sn8 >= 0) pk8 |= (p_ - p0base);

  // bulk preload: range spans <= 128 dense slots starting at p0base
  const uint2 q0 = esrc2[(size_t)p0base + lane];
  const uint2 q1 = esrc2[(size_t)p0base + 64 + lane];

  float acc[NB];
#pragma unroll
  for (int ct = 0; ct < NB; ++ct) acc[ct] = 0.f;
  int openNode = -1; bool openFull = false, openClosed = false;

  auto flushOpen = [&](bool storeOK) {
#pragma unroll
    for (int ct = 0; ct < NB; ++ct) {
      acc[ct] += __shfl_xor(acc[ct], 16);
      acc[ct] += __shfl_xor(acc[ct], 32);
    }
    if (g == 0) {
      float* p = &agg[(size_t)openNode * D + c * NB];
      if (storeOK) {
        if constexpr (NB == 8) {
          *(float4*)p = make_float4(acc[0], acc[1], acc[2], acc[3]);
          *(float4*)(p + 4) = make_float4(acc[4], acc[5], acc[6], acc[7]);
        } else {
          *(float2*)p = make_float2(acc[0], acc[1]);
        }
      } else {
#pragma unroll
        for (int ct = 0; ct < NB; ++ct) atomicAdd(p + ct, acc[ct]);
      }
    }
  };

  auto issue = [&](int t, float4& E0, float4& E1, uint4& afu,
                   uint4* h, int& n_, int& mt_) {
    n_ = __shfl(sn8, t);
    mt_ = __shfl(pk8, t);
    const int d0 = mt_ & 127;
    const int rem = (mt_ >> 7) & 31;
    const int idxA = d0 + ((c < rem) ? c : 0);
    if constexpr (GEA) {
      const int liA = idxA & 63;
      const uint32 eA_ = (uint32)__shfl((int)q0.x, liA);
      const uint32 eB_ = (uint32)__shfl((int)q1.x, liA);
      const int e = (int)((idxA & 64) ? eB_ : eA_);
      if (g < 2) {
        E0 = *(const float4*)&ea[(size_t)e * 16 + g * 8];
        E1 = *(const float4*)&ea[(size_t)e * 16 + g * 8 + 4];
      }
    } else {
      if (g < 2) afu = *(const uint4*)&eabc[((size_t)p0base + idxA) * 16 + g * 8];
    }
    // h for this lane's 4 edges (4g..4g+3), channels c*NB..c*NB+NB-1
#pragma unroll
    for (int j = 0; j < 4; ++j) {
      const int cj = 4 * g + j;
      const int idxj = d0 + ((cj < rem) ? cj : 0);
      const int lij = idxj & 63;
      const uint32 s0_ = (uint32)__shfl((int)q0.y, lij);
      const uint32 s1_ = (uint32)__shfl((int)q1.y, lij);
      const int src = (int)((idxj & 64) ? s1_ : s0_);
      if constexpr (D == 128)
        h[j] = *(const uint4*)&hsrc[(size_t)src * 128 + c * 8];
      else
        h[j].x = *(const uint32*)&hsrc[(size_t)src * 32 + c * 2];
    }
  };

  auto compute = [&](const float4 E0, const float4 E1, uint4 afu,
                     const uint4* h, const int n, const int mt) {
    if (n < 0) return;
    const int rem = (mt >> 7) & 31;
    const int fl = mt >> 12;
    if (n != openNode) {
      if (openNode >= 0) {
        flushOpen(openFull);
#pragma unroll
        for (int ct = 0; ct < NB; ++ct) acc[ct] = 0.f;
      }
      openNode = n; openFull = (fl & 1) != 0; openClosed = false;
    }
    if (fl & 2) openClosed = true;
    if constexpr (GEA) {
      afu.x = pack2ru(E0.x, E0.y); afu.y = pack2ru(E0.z, E0.w);
      afu.z = pack2ru(E1.x, E1.y); afu.w = pack2ru(E1.z, E1.w);
      if (g < 2) {
        const int d0 = mt & 127;
        const int idxA = d0 + ((c < rem) ? c : 0);
        *(uint4*)&eabc[((size_t)p0base + idxA) * 16 + g * 8] = afu;
      }
    }
    bf16x8 afv;   // A operand: edge rows; k16=1.0, k17 = poison if invalid
    {
      uint4 u = make_uint4(0u, 0u, 0u, 0u);
      if (g < 2) u = afu;
      else if (g == 2) u.x = 0x3f80u | (((c < rem) ? 0u : 0xFE96u) << 16);
      union { uint4 u4; bf16x8 v; } cv; cv.u4 = u; afv = cv.v;
    }
#pragma unroll
    for (int ct = 0; ct < NB; ++ct) {
      f32x4 pre = __builtin_amdgcn_mfma_f32_16x16x32_bf16(
          afv, wf[ct], (f32x4){0.f, 0.f, 0.f, 0.f}, 0, 0, 0);
#pragma unroll
      for (int j = 0; j < 4; ++j) {
        uint32 wv;
        if constexpr (D == 128) {
          const int q = ct >> 1;
          wv = (q == 0) ? h[j].x : (q == 1) ? h[j].y : (q == 2) ? h[j].z : h[j].w;
        } else {
          wv = h[j].x;
        }
        const unsigned short hu = (unsigned short)((ct & 1) ? (wv >> 16)
                                                            : (wv & 0xffffu));
        acc[ct] += fmaxf(pre[j] + bf2f(hu), 0.f);
      }
    }
  };

  float4 eA0, eA1, eB0, eB1, eC0, eC1;
  uint4 aA = make_uint4(0,0,0,0), aB = make_uint4(0,0,0,0), aC = make_uint4(0,0,0,0);
  uint4 hA[4], hB[4], hC[4];
#pragma unroll
  for (int j = 0; j < 4; ++j) {
    hA[j] = make_uint4(0,0,0,0); hB[j] = make_uint4(0,0,0,0);
    hC[j] = make_uint4(0,0,0,0);
  }
  int nA = -1, mA = 0, nB_ = -1, mB = 0, nC = -1, mC = 0;

  if constexpr (DEPTH == 3) {
    issue(0, eA0, eA1, aA, hA, nA, mA);
    issue(1, eB0, eB1, aB, hB, nB_, mB);
    issue(2, eC0, eC1, aC, hC, nC, mC);
    compute(eA0, eA1, aA, hA, nA, mA); issue(3, eA0, eA1, aA, hA, nA, mA);
    compute(eB0, eB1, aB, hB, nB_, mB); issue(4, eB0, eB1, aB, hB, nB_, mB);
    compute(eC0, eC1, aC, hC, nC, mC); issue(5, eC0, eC1, aC, hC, nC, mC);
    compute(eA0, eA1, aA, hA, nA, mA); issue(6, eA0, eA1, aA, hA, nA, mA);
    compute(eB0, eB1, aB, hB, nB_, mB); issue(7, eB0, eB1, aB, hB, nB_, mB);
    compute(eC0, eC1, aC, hC, nC, mC);
    compute(eA0, eA1, aA, hA, nA, mA);
    compute(eB0, eB1, aB, hB, nB_, mB);
  } else {
    issue(0, eA0, eA1, aA, hA, nA, mA);
    issue(1, eB0, eB1, aB, hB, nB_, mB);
    compute(eA0, eA1, aA, hA, nA, mA); issue(2, eA0, eA1, aA, hA, nA, mA);
    compute(eB0, eB1, aB, hB, nB_, mB); issue(3, eB0, eB1, aB, hB, nB_, mB);
    compute(eA0, eA1, aA, hA, nA, mA); issue(4, eA0, eA1, aA, hA, nA, mA);
    compute(eB0, eB1, aB, hB, nB_, mB); issue(5, eB0, eB1, aB, hB, nB_, mB);
    compute(eA0, eA1, aA, hA, nA, mA); issue(6, eA0, eA1, aA, hA, nA, mA);
    compute(eB0, eB1, aB, hB, nB_, mB); issue(7, eB0, eB1, aB, hB, nB_, mB);
    compute(eA0, eA1, aA, hA, nA, mA);
    compute(eB0, eB1, aB, hB, nB_, mB);
  }
  if (openNode >= 0) flushOpen(openFull && openClosed);
}

// ---------------------------------------------------------------------------
// MFMA node MLP: out = relu((a+agg)@W1+b1)@W2+b2, + BN stats.
// OUTB: write pre-BN output as bf16 (stats still from f32).
// ---------------------------------------------------------------------------
template<int DIN, bool ABF16, bool OUTB>
__global__ __launch_bounds__(256) void mlp_mfma(
    const float* __restrict__ a32, const unsigned short* __restrict__ abf,
    const float* __restrict__ agg,
    const unsigned short* __restrict__ W1t, const float* __restrict__ b1,
    const unsigned short* __restrict__ W2t, const float* __restrict__ b2,
    float* __restrict__ outp, unsigned short* __restrict__ outpb,
    float* __restrict__ stats, int nChunks)
{
  constexpr int P1 = (DIN == 128) ? 136 : 40;
  constexpr int KS1 = DIN / 32;
  __shared__ __align__(16) unsigned short hin[64 * P1];
  __shared__ __align__(16) unsigned short tls[64 * 136];
  const int tid = threadIdx.x;
  const int w = tid >> 6;
  const int lane = tid & 63;
  const int c = lane & 15, g = lane >> 4;
  const int cw = w * 32;

  bf16x8 B1[2][KS1], B2[2][4];
#pragma unroll
  for (int ct = 0; ct < 2; ++ct)
#pragma unroll
    for (int kk = 0; kk < KS1; ++kk)
      B1[ct][kk] = *(const bf16x8*)&W1t[(cw + ct * 16 + c) * DIN + kk * 32 + g * 8];
#pragma unroll
  for (int ct = 0; ct < 2; ++ct)
#pragma unroll
    for (int kk = 0; kk < 4; ++kk)
      B2[ct][kk] = *(const bf16x8*)&W2t[(cw + ct * 16 + c) * 128 + kk * 32 + g * 8];
  const float b1c0 = b1[cw + c], b1c1 = b1[cw + 16 + c];
  const float b2c0 = b2[cw + c], b2c1 = b2[cw + 16 + c];
  float lsum0 = 0.f, lsum1 = 0.f, lsq0 = 0.f, lsq1 = 0.f;

  for (int chunk = blockIdx.x; chunk < nChunks; chunk += gridDim.x) {
    const int base = chunk * 64;
    if constexpr (DIN == 128) {
#pragma unroll
      for (int p = 0; p < 4; ++p) {
        const int idx = tid + 256 * p;
        const int n = idx >> 4, k8 = idx & 15;
        const int node = base + n;
        uint4 ov = make_uint4(0u, 0u, 0u, 0u);
        if (node < NN) {
          const float4 g0 = *(const float4*)&agg[node * 128 + k8 * 8];
          const float4 g1 = *(const float4*)&agg[node * 128 + k8 * 8 + 4];
          const uint4 hv = *(const uint4*)&abf[node * 128 + k8 * 8];
          ov.x = pack2(bf2f((unsigned short)(hv.x & 0xffffu)) + g0.x,
                       bf2f((unsigned short)(hv.x >> 16)) + g0.y);
          ov.y = pack2(bf2f((unsigned short)(hv.y & 0xffffu)) + g0.z,
                       bf2f((unsigned short)(hv.y >> 16)) + g0.w);
          ov.z = pack2(bf2f((unsigned short)(hv.z & 0xffffu)) + g1.x,
                       bf2f((unsigned short)(hv.z >> 16)) + g1.y);
          ov.w = pack2(bf2f((unsigned short)(hv.w & 0xffffu)) + g1.z,
                       bf2f((unsigned short)(hv.w >> 16)) + g1.w);
        }
        *(uint4*)&hin[n * P1 + k8 * 8] = ov;
      }
    } else {
      const int n = tid >> 2, k8 = tid & 3;
      const int node = base + n;
      uint4 ov = make_uint4(0u, 0u, 0u, 0u);
      if (node < NN) {
        const float4 x0 = *(const float4*)&a32[node * 32 + k8 * 8];
        const float4 x1 = *(const float4*)&a32[node * 32 + k8 * 8 + 4];
        const float4 g0 = *(const float4*)&agg[node * 32 + k8 * 8];
        const float4 g1 = *(const float4*)&agg[node * 32 + k8 * 8 + 4];
        ov.x = pack2(x0.x + g0.x, x0.y + g0.y);
        ov.y = pack2(x0.z + g0.z, x0.w + g0.w);
        ov.z = pack2(x1.x + g1.x, x1.y + g1.y);
        ov.w = pack2(x1.z + g1.z, x1.w + g1.w);
      }
      *(uint4*)&hin[n * P1 + k8 * 8] = ov;
    }
    __syncthreads();
#pragma unroll
    for (int nt = 0; nt < 4; ++nt) {
      bf16x8 af[KS1];
#pragma unroll
      for (int kk = 0; kk < KS1; ++kk)
        af[kk] = *(const bf16x8*)&hin[(nt * 16 + c) * P1 + kk * 32 + g * 8];
      f32x4 acc0 = {0.f, 0.f, 0.f, 0.f}, acc1 = {0.f, 0.f, 0.f, 0.f};
#pragma unroll
      for (int kk = 0; kk < KS1; ++kk) {
        acc0 = __builtin_amdgcn_mfma_f32_16x16x32_bf16(af[kk], B1[0][kk], acc0, 0, 0, 0);
        acc1 = __builtin_amdgcn_mfma_f32_16x16x32_bf16(af[kk], B1[1][kk], acc1, 0, 0, 0);
      }
#pragma unroll
      for (int j = 0; j < 4; ++j) {
        const int row = nt * 16 + g * 4 + j;
        tls[row * 136 + cw + c]      = f2bf(fmaxf(acc0[j] + b1c0, 0.f));
        tls[row * 136 + cw + 16 + c] = f2bf(fmaxf(acc1[j] + b1c1, 0.f));
      }
    }
    __syncthreads();
#pragma unroll
    for (int nt = 0; nt < 4; ++nt) {
      bf16x8 af[4];
#pragma unroll
      for (int kk = 0; kk < 4; ++kk)
        af[kk] = *(const bf16x8*)&tls[(nt * 16 + c) * 136 + kk * 32 + g * 8];
      f32x4 acc0 = {0.f, 0.f, 0.f, 0.f}, acc1 = {0.f, 0.f, 0.f, 0.f};
#pragma unroll
      for (int kk = 0; kk < 4; ++kk) {
        acc0 = __builtin_amdgcn_mfma_f32_16x16x32_bf16(af[kk], B2[0][kk], acc0, 0, 0, 0);
        acc1 = __builtin_amdgcn_mfma_f32_16x16x32_bf16(af[kk], B2[1][kk], acc1, 0, 0, 0);
      }
#pragma unroll
      for (int j = 0; j < 4; ++j) {
        const int node = base + nt * 16 + g * 4 + j;
        if (node < NN) {
          const float v0 = acc0[j] + b2c0;
          const float v1 = acc1[j] + b2c1;
          if constexpr (OUTB) {
            outpb[(size_t)node * 128 + cw + c] = f2bf(v0);
            outpb[(size_t)node * 128 + cw + 16 + c] = f2bf(v1);
          } else {
            outp[(size_t)node * 128 + cw + c] = v0;
            outp[(size_t)node * 128 + cw + 16 + c] = v1;
          }
          lsum0 += v0; lsq0 += v0 * v0;
          lsum1 += v1; lsq1 += v1 * v1;
        }
      }
    }
  }
  lsum0 += __shfl_xor(lsum0, 16); lsum0 += __shfl_xor(lsum0, 32);
  lsum1 += __shfl_xor(lsum1, 16); lsum1 += __shfl_xor(lsum1, 32);
  lsq0  += __shfl_xor(lsq0, 16);  lsq0  += __shfl_xor(lsq0, 32);
  lsq1  += __shfl_xor(lsq1, 16);  lsq1  += __shfl_xor(lsq1, 32);
  if (lane < 16) {
    atomicAdd(&stats[cw + lane], lsum0);
    atomicAdd(&stats[cw + 16 + lane], lsum1);
    atomicAdd(&stats[128 + cw + lane], lsq0);
    atomicAdd(&stats[128 + cw + 16 + lane], lsq1);
  }
}

// ---------------------------------------------------------------------------
// BN apply (bf16 in -> bf16 out), finalize inlined via LDS.
// Grid: NN*128/8/256 = 6250 blocks; 8 bf16 per thread.
// ---------------------------------------------------------------------------
__global__ __launch_bounds__(256) void bn_apply_bb(
    const unsigned short* __restrict__ hpreb, const float* __restrict__ stats,
    const float* __restrict__ gamma, const float* __restrict__ beta,
    unsigned short* __restrict__ hb)
{
  __shared__ float scs[128], shs[128];
  const int tid = threadIdx.x;
  if (tid < 128) {
    const float inv_n = 1.0f / (float)NN;
    const float mu = stats[tid] * inv_n;
    float var = stats[128 + tid] * inv_n - mu * mu;
    var = fmaxf(var, 0.f);
    const float sc = rsqrtf(var + 1e-5f) * gamma[tid];
    scs[tid] = sc;
    shs[tid] = beta[tid] - mu * sc;
  }
  __syncthreads();
  const int idx = blockIdx.x * 256 + tid;   // over NN*16 uint4 groups
  const int c8 = (idx & 15) * 8;
  const uint4 hv = ((const uint4*)hpreb)[idx];
  const float t0 = bf2f((unsigned short)(hv.x & 0xffffu));
  const float t1 = bf2f((unsigned short)(hv.x >> 16));
  const float t2 = bf2f((unsigned short)(hv.y & 0xffffu));
  const float t3 = bf2f((unsigned short)(hv.y >> 16));
  const float t4 = bf2f((unsigned short)(hv.z & 0xffffu));
  const float t5 = bf2f((unsigned short)(hv.z >> 16));
  const float t6 = bf2f((unsigned short)(hv.w & 0xffffu));
  const float t7 = bf2f((unsigned short)(hv.w >> 16));
  uint4 o;
  o.x = pack2(fmaxf(fmaf(t0, scs[c8 + 0], shs[c8 + 0]), 0.f),
              fmaxf(fmaf(t1, scs[c8 + 1], shs[c8 + 1]), 0.f));
  o.y = pack2(fmaxf(fmaf(t2, scs[c8 + 2], shs[c8 + 2]), 0.f),
              fmaxf(fmaf(t3, scs[c8 + 3], shs[c8 + 3]), 0.f));
  o.z = pack2(fmaxf(fmaf(t4, scs[c8 + 4], shs[c8 + 4]), 0.f),
              fmaxf(fmaf(t5, scs[c8 + 5], shs[c8 + 5]), 0.f));
  o.w = pack2(fmaxf(fmaf(t6, scs[c8 + 6], shs[c8 + 6]), 0.f),
              fmaxf(fmaf(t7, scs[c8 + 7], shs[c8 + 7]), 0.f));
  ((uint4*)hb)[idx] = o;
}

// ---------------------------------------------------------------------------
// Fused BN-apply + head, hpre in BF16, finalize inlined via LDS:
//   out = sigmoid(relu(relu(bf16(hpre)*sc+sh)@W1+b1)@w2 + b2)
// ---------------------------------------------------------------------------
__global__ __launch_bounds__(256) void head_bn(
    const unsigned short* __restrict__ hpreb, const float* __restrict__ stats,
    const float* __restrict__ gamma, const float* __restrict__ beta,
    const unsigned short* __restrict__ W1t, const float* __restrict__ b1,
    const float* __restrict__ w2, const float* __restrict__ b2,
    float* __restrict__ out, int nChunks)
{
  __shared__ float pl[4][64];
  __shared__ float scs[128], shs[128];
  const int tid = threadIdx.x;
  if (tid < 128) {
    const float inv_n = 1.0f / (float)NN;
    const float mu = stats[tid] * inv_n;
    float var = stats[128 + tid] * inv_n - mu * mu;
    var = fmaxf(var, 0.f);
    const float sc = rsqrtf(var + 1e-5f) * gamma[tid];
    scs[tid] = sc;
    shs[tid] = beta[tid] - mu * sc;
  }
  __syncthreads();
  const int w = tid >> 6;
  const int lane = tid & 63;
  const int c = lane & 15, g = lane >> 4;
  const int cw = w * 32;

  bf16x8 B1[2][4];
#pragma unroll
  for (int ct = 0; ct < 2; ++ct)
#pragma unroll
    for (int kk = 0; kk < 4; ++kk)
      B1[ct][kk] = *(const bf16x8*)&W1t[(cw + ct * 16 + c) * 128 + kk * 32 + g * 8];
  const float b1c0 = b1[cw + c], b1c1 = b1[cw + 16 + c];
  const float w2c0 = w2[cw + c], w2c1 = w2[cw + 16 + c];
  const float b2v = b2[0];
  float4 scq[4][2], shq[4][2];
#pragma unroll
  for (int kk = 0; kk < 4; ++kk) {
    const int cb = kk * 32 + g * 8;
    scq[kk][0] = make_float4(scs[cb], scs[cb + 1], scs[cb + 2], scs[cb + 3]);
    scq[kk][1] = make_float4(scs[cb + 4], scs[cb + 5], scs[cb + 6], scs[cb + 7]);
    shq[kk][0] = make_float4(shs[cb], shs[cb + 1], shs[cb + 2], shs[cb + 3]);
    shq[kk][1] = make_float4(shs[cb + 4], shs[cb + 5], shs[cb + 6], shs[cb + 7]);
  }

  for (int chunk = blockIdx.x; chunk < nChunks; chunk += gridDim.x) {
    const int base = chunk * 64;
    float p[4][4];
#pragma unroll
    for (int nt = 0; nt < 4; ++nt) {
      const int node = base + nt * 16 + c;
      bf16x8 af[4];
#pragma unroll
      for (int kk = 0; kk < 4; ++kk) {
        uint4 u = make_uint4(0u, 0u, 0u, 0u);
        if (node < NN) {
          const uint4 hv = *(const uint4*)&hpreb[(size_t)node * 128 + kk * 32 + g * 8];
          const float4 s0 = scq[kk][0], s1 = scq[kk][1];
          const float4 h0 = shq[kk][0], h1 = shq[kk][1];
          const float t0 = bf2f((unsigned short)(hv.x & 0xffffu));
          const float t1 = bf2f((unsigned short)(hv.x >> 16));
          const float t2 = bf2f((unsigned short)(hv.y & 0xffffu));
          const float t3 = bf2f((unsigned short)(hv.y >> 16));
          const float t4 = bf2f((unsigned short)(hv.z & 0xffffu));
          const float t5 = bf2f((unsigned short)(hv.z >> 16));
          const float t6 = bf2f((unsigned short)(hv.w & 0xffffu));
          const float t7 = bf2f((unsigned short)(hv.w >> 16));
          u.x = pack2(fmaxf(fmaf(t0, s0.x, h0.x), 0.f),
                      fmaxf(fmaf(t1, s0.y, h0.y), 0.f));
          u.y = pack2(fmaxf(fmaf(t2, s0.z, h0.z), 0.f),
                      fmaxf(fmaf(t3, s0.w, h0.w), 0.f));
          u.z = pack2(fmaxf(fmaf(t4, s1.x, h1.x), 0.f),
                      fmaxf(fmaf(t5, s1.y, h1.y), 0.f));
          u.w = pack2(fmaxf(fmaf(t6, s1.z, h1.z), 0.f),
                      fmaxf(fmaf(t7, s1.w, h1.w), 0.f));
        }
        union { uint4 u4; bf16x8 v; } cv; cv.u4 = u;
        af[kk] = cv.v;
      }
      f32x4 acc0 = {0.f, 0.f, 0.f, 0.f}, acc1 = {0.f, 0.f, 0.f, 0.f};
#pragma unroll
      for (int kk = 0; kk < 4; ++kk) {
        acc0 = __builtin_amdgcn_mfma_f32_16x16x32_bf16(af[kk], B1[0][kk], acc0, 0, 0, 0);
        acc1 = __builtin_amdgcn_mfma_f32_16x16x32_bf16(af[kk], B1[1][kk], acc1, 0, 0, 0);
      }
#pragma unroll
      for (int j = 0; j < 4; ++j)
        p[nt][j] = fmaxf(acc0[j] + b1c0, 0.f) * w2c0 +
                   fmaxf(acc1[j] + b1c1, 0.f) * w2c1;
    }
#pragma unroll
    for (int dd = 1; dd <= 8; dd <<= 1)
#pragma unroll
      for (int nt = 0; nt < 4; ++nt)
#pragma unroll
        for (int j = 0; j < 4; ++j)
          p[nt][j] += __shfl_xor(p[nt][j], dd);
    if (c == 0) {
#pragma unroll
      for (int nt = 0; nt < 4; ++nt)
#pragma unroll
        for (int j = 0; j < 4; ++j)
          pl[w][nt * 16 + g * 4 + j] = p[nt][j];
    }
    __syncthreads();
    if (tid < 64) {
      const int node = base + tid;
      if (node < NN) {
        const float s = pl[0][tid] + pl[1][tid] + pl[2][tid] + pl[3][tid] + b2v;
        out[node] = 1.f / (1.f + expf(-s));
      }
    }
    __syncthreads();
  }
}

extern "C" void kernel_launch(void* const* d_in, const int* in_sizes, int n_in,
                              void* d_out, int out_size, void* d_ws, size_t ws_size,
                              hipStream_t stream)
{
  const float* x    = (const float*)d_in[0];
  const int*   ei   = (const int*)  d_in[1];
  const float* ea   = (const float*)d_in[2];
  const float* l0We = (const float*)d_in[3];
  const float* l0be = (const float*)d_in[4];
  const float* l0W1 = (const float*)d_in[5];
  const float* l0b1 = (const float*)d_in[6];
  const float* l0W2 = (const float*)d_in[7];
  const float* l0b2 = (const float*)d_in[8];
  const float* l0g  = (const float*)d_in[9];
  const float* l0bt = (const float*)d_in[10];
  const float* l1We = (const float*)d_in[11];
  const float* l1be = (const float*)d_in[12];
  const float* l1W1 = (const float*)d_in[13];
  const float* l1b1 = (const float*)d_in[14];
  const float* l1W2 = (const float*)d_in[15];
  const float* l1b2 = (const float*)d_in[16];
  const float* l1g  = (const float*)d_in[17];
  const float* l1bt = (const float*)d_in[18];
  const float* hW1  = (const float*)d_in[19];
  const float* hb1  = (const float*)d_in[20];
  const float* hW2  = (const float*)d_in[21];
  const float* hb2  = (const float*)d_in[22];
  float* out = (float*)d_out;

  // workspace layout (~201 MB; proven available R9-R17)
  float*  A    = (float*)d_ws;                         // NN*128 (hpre bf16 view)
  float*  AGG  = A + (size_t)NN * 128;                 // NN*128 f32
  unsigned short* hb = (unsigned short*)(AGG + (size_t)NN * 128);  // NN*128 bf16
  unsigned short* xb = hb + (size_t)NN * 128;          // NN*32 bf16
  uint32* deg     = (uint32*)(xb + (size_t)NN * 32);   // NN
  uint32* cnt     = deg + NN;                          // NN
  uint32* toff    = cnt + NN;                          // NN
  uint32* eoff    = toff + NN;                         // NN
  ull*    counter = (ull*)(eoff + NN);                 // 1 (pad 2)
  int*    snode   = (int*)(counter + 2);               // TMAX
  uint2*  esrc2   = (uint2*)(snode + TMAX);            // NE + 128 pad
  float*  st0     = (float*)(esrc2 + NE + 128);        // 512
  float*  st1     = st0 + 512;                         // 512
  unsigned short* W1t0 = (unsigned short*)(st1 + 512); // 32*128
  unsigned short* W2t0 = W1t0 + 4096;                  // 128*128
  unsigned short* W1t1 = W2t0 + 16384;
  unsigned short* W2t1 = W1t1 + 16384;
  unsigned short* hW1t = W2t1 + 16384;
  unsigned short* Wet0 = hW1t + 16384;                 // 32*16
  unsigned short* Wet1 = Wet0 + 512;                   // 128*16
  unsigned short* eabc = Wet1 + 2048;                  // NE*16 bf16 (51.2 MB)
  unsigned short* Ab = (unsigned short*)A;             // bf16 view (hpre)

  const size_t needed = (size_t)((char*)(eabc + (size_t)NE * 16) - (char*)d_ws);
  if (ws_size < needed) return;

  hipMemsetAsync(deg, 0, (size_t)2 * NN * 4, stream);          // deg, cnt
  hipMemsetAsync(counter, 0, 16, stream);
  hipMemsetAsync(snode, 0xFF, (size_t)TMAX * 4, stream);
  hipMemsetAsync(st0, 0, 4096, stream);                        // st0 + st1
  hipMemsetAsync(AGG, 0, (size_t)NN * 32 * 4, stream);         // layer-0 agg

  const int nChunks = (NN + 63) / 64;     // 1563
  const int eBlocks = (NE + 255) / 256;   // 6250
  const int nBlocks = (NN + 255) / 256;   // 391

  // combined conversion + degree histogram (one launch)
  conv_hist<<<16 + 64 * 4 + 2 + 8 + 1563 + eBlocks, 256, 0, stream>>>(
      l0W1, l0W2, l1W1, l1W2, hW1, l0We, l1We, x,
      W1t0, W2t0, W1t1, W2t1, hW1t, Wet0, Wet1, xb, ei, deg);

  offsets2_kernel<<<nBlocks, 256, 0, stream>>>(deg, toff, eoff, counter);
  snode_and_fill<<<nBlocks + eBlocks, 256, 0, stream>>>(
      toff, deg, snode, ei, eoff, cnt, esrc2);

  // layer 0: gathers ea (long latency) -> depth-3 pipeline
  flat_agg9<32, 2, true, 3><<<NRANGES / 4, 256, 0, stream>>>(
      snode, toff, eoff, deg, esrc2, ea, eabc, xb, Wet0, l0be, counter, AGG);
  mlp_mfma<32, false, true><<<782, 256, 0, stream>>>(
      x, (const unsigned short*)nullptr, AGG, W1t0, l0b1, W2t0, l0b2,
      (float*)nullptr, Ab, st0, nChunks);
  hipMemsetAsync(AGG, 0, (size_t)NN * 128 * 4, stream);   // re-zero for layer 1
  bn_apply_bb<<<(NN * 16) / 256, 256, 0, stream>>>(Ab, st0, l0g, l0bt, hb);

  // layer 1: eabc path (short latency) -> depth-2; writes hpre1 as BF16
  flat_agg9<128, 8, false, 2><<<NRANGES / 4, 256, 0, stream>>>(
      snode, toff, eoff, deg, esrc2, ea, eabc, hb, Wet1, l1be, counter, AGG);
  mlp_mfma<128, true, true><<<782, 256, 0, stream>>>(
      (const float*)nullptr, hb, AGG, W1t1, l1b1, W2t1, l1b2,
      (float*)nullptr, Ab, st1, nChunks);

  // fused BN-finalize + BN-apply + head (bf16 hpre)
  head_bn<<<782, 256, 0, stream>>>(Ab, st1, l1g, l1bt, hW1t, hb1, hW2, hb2,
                                   out, nChunks);
}

// Round 19
// 503.484 us; speedup vs baseline: 1.1498x; 1.0214x over previous
//
#include <hip/hip_runtime.h>

#define NN 100000
#define NE 1600000
#define TMAX 193760           // >= sum ceil(deg/16) worst case (193750)
#define NRANGES 24220         // TMAX / 8

typedef unsigned int uint32;
typedef unsigned long long ull;
typedef __attribute__((ext_vector_type(8))) short bf16x8;
typedef __attribute__((ext_vector_type(4))) float f32x4;

__device__ __forceinline__ unsigned short f2bf(float f) {
  unsigned int u = __float_as_uint(f);
  unsigned int r = (u + 0x7fffu + ((u >> 16) & 1u)) >> 16;  // RNE
  return (unsigned short)r;
}
__device__ __forceinline__ float bf2f(unsigned short u) {
  return __uint_as_float(((unsigned int)u) << 16);
}
__device__ __forceinline__ unsigned int pack2(float a, float b) {
  return (unsigned int)f2bf(a) | ((unsigned int)f2bf(b) << 16);
}
// round-half-up pack of two f32 -> bf16 pair (cheap, ~= RNE for random data)
__device__ __forceinline__ uint32 pack2ru(float a, float b) {
  const uint32 ua = __float_as_uint(a) + 0x8000u;
  const uint32 ub = __float_as_uint(b) + 0x8000u;
  return (ua >> 16) | (ub & 0xffff0000u);
}

// ---------------------------------------------------------------------------
// Combined weight/activation conversion + degree histogram (one launch).
// ---------------------------------------------------------------------------
__device__ __forceinline__ void wconv_body(const float* __restrict__ src,
    unsigned short* __restrict__ dst, int K, int N, int b)
{
  const int i = b * 256 + threadIdx.x;
  if (i < K * N) {
    const int n = i / K, k = i - n * K;
    dst[i] = f2bf(src[k * N + n]);
  }
}

__global__ __launch_bounds__(256) void conv_hist(
    const float* __restrict__ l0W1, const float* __restrict__ l0W2,
    const float* __restrict__ l1W1, const float* __restrict__ l1W2,
    const float* __restrict__ hW1,  const float* __restrict__ l0We,
    const float* __restrict__ l1We, const float* __restrict__ x,
    unsigned short* __restrict__ W1t0, unsigned short* __restrict__ W2t0,
    unsigned short* __restrict__ W1t1, unsigned short* __restrict__ W2t1,
    unsigned short* __restrict__ hW1t, unsigned short* __restrict__ Wet0,
    unsigned short* __restrict__ Wet1, unsigned short* __restrict__ xb,
    const int* __restrict__ ei, uint32* __restrict__ deg)
{
  int b = blockIdx.x;
  if (b < 16)  { wconv_body(l0W1, W1t0, 32, 128, b); return; }  b -= 16;
  if (b < 64)  { wconv_body(l0W2, W2t0, 128, 128, b); return; } b -= 64;
  if (b < 64)  { wconv_body(l1W1, W1t1, 128, 128, b); return; } b -= 64;
  if (b < 64)  { wconv_body(l1W2, W2t1, 128, 128, b); return; } b -= 64;
  if (b < 64)  { wconv_body(hW1,  hW1t, 128, 128, b); return; } b -= 64;
  if (b < 2)   { wconv_body(l0We, Wet0, 16, 32, b); return; }   b -= 2;
  if (b < 8)   { wconv_body(l1We, Wet1, 16, 128, b); return; }  b -= 8;
  if (b < 1563) {
    const int i = b * 256 + threadIdx.x;
    if (i * 8 < NN * 32) {
      const float4 a = ((const float4*)x)[i * 2];
      const float4 d = ((const float4*)x)[i * 2 + 1];
      uint4 o;
      o.x = pack2(a.x, a.y); o.y = pack2(a.z, a.w);
      o.z = pack2(d.x, d.y); o.w = pack2(d.z, d.w);
      ((uint4*)xb)[i] = o;
    }
    return;
  }
  b -= 1563;
  const int e = b * 256 + threadIdx.x;
  if (e < NE) atomicAdd(&deg[ei[NE + e]], 1u);
}

// ---------------------------------------------------------------------------
// CSR build: dual prefix scan (tiles, edges) -> snode + fill (merged)
// ---------------------------------------------------------------------------
__global__ __launch_bounds__(256) void offsets2_kernel(
    const uint32* __restrict__ deg, uint32* __restrict__ toff,
    uint32* __restrict__ eoff, ull* __restrict__ counter)
{
  __shared__ ull s[256];
  __shared__ ull base;
  const int tid = threadIdx.x;
  const int n = blockIdx.x * 256 + tid;
  const uint32 d = (n < NN) ? deg[n] : 0u;
  const uint32 tc = (d + 15u) >> 4;
  const ull v = ((ull)tc << 32) | (ull)d;
  s[tid] = v;
  __syncthreads();
#pragma unroll
  for (int st = 1; st < 256; st <<= 1) {
    ull w = (tid >= st) ? s[tid - st] : 0ull;
    __syncthreads();
    s[tid] += w;
    __syncthreads();
  }
  if (tid == 255) base = atomicAdd(counter, s[255]);
  __syncthreads();
  if (n < NN) {
    const ull t = base + (s[tid] - v);
    toff[n] = (uint32)(t >> 32);
    eoff[n] = (uint32)t;
  }
}

// merged: snode map fill + layer-0 boundary-row zeroing (391 blocks)
//         + edge slot fill (6250 blocks)
__global__ __launch_bounds__(256) void snode_and_fill(
    const uint32* __restrict__ toff, const uint32* __restrict__ deg,
    int* __restrict__ snode, const int* __restrict__ ei,
    const uint32* __restrict__ eoff, uint32* __restrict__ cnt,
    uint2* __restrict__ esrc2, float* __restrict__ agg)
{
  int b = blockIdx.x;
  if (b < (NN + 255) / 256) {
    const int n = b * 256 + threadIdx.x;
    if (n < NN) {
      const uint32 t0 = toff[n];
      const uint32 tc = (deg[n] + 15u) >> 4;
      for (uint32 i = 0; i < tc; ++i) snode[t0 + i] = n;
      // zero layer-0 agg row (D=32) iff node's flush will use atomics
      // (tiles straddle an 8-tile range boundary) or node has no edges
      if (tc == 0u || ((t0 & 7u) + tc) > 8u) {
        float4* p = (float4*)&agg[(size_t)n * 32];
#pragma unroll
        for (int k = 0; k < 8; ++k) p[k] = make_float4(0.f, 0.f, 0.f, 0.f);
      }
    }
    return;
  }
  b -= (NN + 255) / 256;
  const int e = b * 256 + threadIdx.x;
  if (e < NE) {
    const int dst = ei[NE + e];
    const uint32 pos = eoff[dst] + atomicAdd(&cnt[dst], 1u);
    esrc2[pos] = make_uint2((uint32)e, (uint32)ei[e]);
  }
}

// ---------------------------------------------------------------------------
// flat_agg9: TRANSPOSED padded-tile aggregate + template pipeline DEPTH.
//  DEPTH=3 for GEA layer 0; DEPTH=2 for layer 1 (unchanged from R16).
// ---------------------------------------------------------------------------
template<int D, int NB, bool GEA, int DEPTH>
__global__ __launch_bounds__(256) void flat_agg9(
    const int* __restrict__ snode, const uint32* __restrict__ toff,
    const uint32* __restrict__ eoff, const uint32* __restrict__ deg,
    const uint2* __restrict__ esrc2, const float* __restrict__ ea,
    unsigned short* __restrict__ eabc,
    const unsigned short* __restrict__ hsrc,
    const unsigned short* __restrict__ Wet, const float* __restrict__ be,
    const ull* __restrict__ tot, float* __restrict__ agg)
{
  const int tid = threadIdx.x;
  const int wid = tid >> 6;
  const int lane = tid & 63;
  const int c = lane & 15;
  const int g = lane >> 4;
  const int range = blockIdx.x * 4 + wid;
  const int tile0 = range * 8;
  const uint32 ntile = (uint32)((*tot) >> 32);
  if ((uint32)tile0 >= ntile) return;   // dead range

  // B fragments (weights): col c -> channel c*NB+ct; k16=be, k17=1.0
  bf16x8 wf[NB];
#pragma unroll
  for (int ct = 0; ct < NB; ++ct) {
    const int ch = c * NB + ct;
    uint4 u = make_uint4(0u, 0u, 0u, 0u);
    if (g < 2) u = *(const uint4*)&Wet[ch * 16 + g * 8];
    else if (g == 2) u.x = (0x3f80u << 16) | (uint32)f2bf(be[ch]);
    union { uint4 u4; bf16x8 v; } cv; cv.u4 = u;
    wf[ct] = cv.v;
  }

  // per-tile metadata on lanes 0..7: pk = d0(7b) | rem(5b,<=16) | flags(2b)
  int sn8 = -1, pk8 = 0, p_ = 0;
  if (lane < 8) {
    sn8 = snode[tile0 + lane];
    if (sn8 >= 0) {
      const uint32 to = toff[sn8], dg = deg[sn8], eo = eoff[sn8];
      const int k = tile0 + lane - (int)to;
      p_ = (int)eo + k * 16;
      int rv = (int)dg - k * 16; if (rv > 16) rv = 16;
      const int fl = (k == 0 ? 1 : 0) |
                     ((k == (int)((dg + 15u) >> 4) - 1) ? 2 : 0);
      pk8 = (rv << 7) | (fl << 12);
    }
  }
  const int p0base = __shfl(p_, 0);   // lane 0 (tile0) is always real
  if (lane < 8 && sn8 >= 0) pk8 |= (p_ - p0base);

  // bulk preload: range spans <= 128 dense slots starting at p0base
  const uint2 q0 = esrc2[(size_t)p0base + lane];
  const uint2 q1 = esrc2[(size_t)p0base + 64 + lane];

  float acc[NB];
#pragma unroll
  for (int ct = 0; ct < NB; ++ct) acc[ct] = 0.f;
  int openNode = -1; bool openFull = false, openClosed = false;

  auto flushOpen = [&](bool storeOK) {
#pragma unroll
    for (int ct = 0; ct < NB; ++ct) {
      acc[ct] += __shfl_xor(acc[ct], 16);
      acc[ct] += __shfl_xor(acc[ct], 32);
    }
    if (g == 0) {
      float* p = &agg[(size_t)openNode * D + c * NB];
      if (storeOK) {
        if constexpr (NB == 8) {
          *(float4*)p = make_float4(acc[0], acc[1], acc[2], acc[3]);
          *(float4*)(p + 4) = make_float4(acc[4], acc[5], acc[6], acc[7]);
        } else {
          *(float2*)p = make_float2(acc[0], acc[1]);
        }
      } else {
#pragma unroll
        for (int ct = 0; ct < NB; ++ct) atomicAdd(p + ct, acc[ct]);
      }
    }
  };

  auto issue = [&](int t, float4& E0, float4& E1, uint4& afu,
                   uint4* h, int& n_, int& mt_) {
    n_ = __shfl(sn8, t);
    mt_ = __shfl(pk8, t);
    const int d0 = mt_ & 127;
    const int rem = (mt_ >> 7) & 31;
    const int idxA = d0 + ((c < rem) ? c : 0);
    if constexpr (GEA) {
      const int liA = idxA & 63;
      const uint32 eA_ = (uint32)__shfl((int)q0.x, liA);
      const uint32 eB_ = (uint32)__shfl((int)q1.x, liA);
      const int e = (int)((idxA & 64) ? eB_ : eA_);
      if (g < 2) {
        E0 = *(const float4*)&ea[(size_t)e * 16 + g * 8];
        E1 = *(const float4*)&ea[(size_t)e * 16 + g * 8 + 4];
      }
    } else {
      if (g < 2) afu = *(const uint4*)&eabc[((size_t)p0base + idxA) * 16 + g * 8];
    }
    // h for this lane's 4 edges (4g..4g+3), channels c*NB..c*NB+NB-1
#pragma unroll
    for (int j = 0; j < 4; ++j) {
      const int cj = 4 * g + j;
      const int idxj = d0 + ((cj < rem) ? cj : 0);
      const int lij = idxj & 63;
      const uint32 s0_ = (uint32)__shfl((int)q0.y, lij);
      const uint32 s1_ = (uint32)__shfl((int)q1.y, lij);
      const int src = (int)((idxj & 64) ? s1_ : s0_);
      if constexpr (D == 128)
        h[j] = *(const uint4*)&hsrc[(size_t)src * 128 + c * 8];
      else
        h[j].x = *(const uint32*)&hsrc[(size_t)src * 32 + c * 2];
    }
  };

  auto compute = [&](const float4 E0, const float4 E1, uint4 afu,
                     const uint4* h, const int n, const int mt) {
    if (n < 0) return;
    const int rem = (mt >> 7) & 31;
    const int fl = mt >> 12;
    if (n != openNode) {
      if (openNode >= 0) {
        flushOpen(openFull);
#pragma unroll
        for (int ct = 0; ct < NB; ++ct) acc[ct] = 0.f;
      }
      openNode = n; openFull = (fl & 1) != 0; openClosed = false;
    }
    if (fl & 2) openClosed = true;
    if constexpr (GEA) {
      afu.x = pack2ru(E0.x, E0.y); afu.y = pack2ru(E0.z, E0.w);
      afu.z = pack2ru(E1.x, E1.y); afu.w = pack2ru(E1.z, E1.w);
      if (g < 2) {
        const int d0 = mt & 127;
        const int idxA = d0 + ((c < rem) ? c : 0);
        *(uint4*)&eabc[((size_t)p0base + idxA) * 16 + g * 8] = afu;
      }
    }
    bf16x8 afv;   // A operand: edge rows; k16=1.0, k17 = poison if invalid
    {
      uint4 u = make_uint4(0u, 0u, 0u, 0u);
      if (g < 2) u = afu;
      else if (g == 2) u.x = 0x3f80u | (((c < rem) ? 0u : 0xFE96u) << 16);
      union { uint4 u4; bf16x8 v; } cv; cv.u4 = u; afv = cv.v;
    }
#pragma unroll
    for (int ct = 0; ct < NB; ++ct) {
      f32x4 pre = __builtin_amdgcn_mfma_f32_16x16x32_bf16(
          afv, wf[ct], (f32x4){0.f, 0.f, 0.f, 0.f}, 0, 0, 0);
#pragma unroll
      for (int j = 0; j < 4; ++j) {
        uint32 wv;
        if constexpr (D == 128) {
          const int q = ct >> 1;
          wv = (q == 0) ? h[j].x : (q == 1) ? h[j].y : (q == 2) ? h[j].z : h[j].w;
        } else {
          wv = h[j].x;
        }
        const unsigned short hu = (unsigned short)((ct & 1) ? (wv >> 16)
                                                            : (wv & 0xffffu));
        acc[ct] += fmaxf(pre[j] + bf2f(hu), 0.f);
      }
    }
  };

  float4 eA0, eA1, eB0, eB1, eC0, eC1;
  uint4 aA = make_uint4(0,0,0,0), aB = make_uint4(0,0,0,0), aC = make_uint4(0,0,0,0);
  uint4 hA[4], hB[4], hC[4];
#pragma unroll
  for (int j = 0; j < 4; ++j) {
    hA[j] = make_uint4(0,0,0,0); hB[j] = make_uint4(0,0,0,0);
    hC[j] = make_uint4(0,0,0,0);
  }
  int nA = -1, mA = 0, nB_ = -1, mB = 0, nC = -1, mC = 0;

  if constexpr (DEPTH == 3) {
    issue(0, eA0, eA1, aA, hA, nA, mA);
    issue(1, eB0, eB1, aB, hB, nB_, mB);
    issue(2, eC0, eC1, aC, hC, nC, mC);
    compute(eA0, eA1, aA, hA, nA, mA); issue(3, eA0, eA1, aA, hA, nA, mA);
    compute(eB0, eB1, aB, hB, nB_, mB); issue(4, eB0, eB1, aB, hB, nB_, mB);
    compute(eC0, eC1, aC, hC, nC, mC); issue(5, eC0, eC1, aC, hC, nC, mC);
    compute(eA0, eA1, aA, hA, nA, mA); issue(6, eA0, eA1, aA, hA, nA, mA);
    compute(eB0, eB1, aB, hB, nB_, mB); issue(7, eB0, eB1, aB, hB, nB_, mB);
    compute(eC0, eC1, aC, hC, nC, mC);
    compute(eA0, eA1, aA, hA, nA, mA);
    compute(eB0, eB1, aB, hB, nB_, mB);
  } else {
    issue(0, eA0, eA1, aA, hA, nA, mA);
    issue(1, eB0, eB1, aB, hB, nB_, mB);
    compute(eA0, eA1, aA, hA, nA, mA); issue(2, eA0, eA1, aA, hA, nA, mA);
    compute(eB0, eB1, aB, hB, nB_, mB); issue(3, eB0, eB1, aB, hB, nB_, mB);
    compute(eA0, eA1, aA, hA, nA, mA); issue(4, eA0, eA1, aA, hA, nA, mA);
    compute(eB0, eB1, aB, hB, nB_, mB); issue(5, eB0, eB1, aB, hB, nB_, mB);
    compute(eA0, eA1, aA, hA, nA, mA); issue(6, eA0, eA1, aA, hA, nA, mA);
    compute(eB0, eB1, aB, hB, nB_, mB); issue(7, eB0, eB1, aB, hB, nB_, mB);
    compute(eA0, eA1, aA, hA, nA, mA);
    compute(eB0, eB1, aB, hB, nB_, mB);
  }
  if (openNode >= 0) flushOpen(openFull && openClosed);
}

// ---------------------------------------------------------------------------
// MFMA node MLP: out = relu((a+agg)@W1+b1)@W2+b2, + BN stats.
// OUTB: write pre-BN output as bf16 (stats still from f32).
// ---------------------------------------------------------------------------
template<int DIN, bool ABF16, bool OUTB>
__global__ __launch_bounds__(256) void mlp_mfma(
    const float* __restrict__ a32, const unsigned short* __restrict__ abf,
    const float* __restrict__ agg,
    const unsigned short* __restrict__ W1t, const float* __restrict__ b1,
    const unsigned short* __restrict__ W2t, const float* __restrict__ b2,
    float* __restrict__ outp, unsigned short* __restrict__ outpb,
    float* __restrict__ stats, int nChunks)
{
  constexpr int P1 = (DIN == 128) ? 136 : 40;
  constexpr int KS1 = DIN / 32;
  __shared__ __align__(16) unsigned short hin[64 * P1];
  __shared__ __align__(16) unsigned short tls[64 * 136];
  const int tid = threadIdx.x;
  const int w = tid >> 6;
  const int lane = tid & 63;
  const int c = lane & 15, g = lane >> 4;
  const int cw = w * 32;

  bf16x8 B1[2][KS1], B2[2][4];
#pragma unroll
  for (int ct = 0; ct < 2; ++ct)
#pragma unroll
    for (int kk = 0; kk < KS1; ++kk)
      B1[ct][kk] = *(const bf16x8*)&W1t[(cw + ct * 16 + c) * DIN + kk * 32 + g * 8];
#pragma unroll
  for (int ct = 0; ct < 2; ++ct)
#pragma unroll
    for (int kk = 0; kk < 4; ++kk)
      B2[ct][kk] = *(const bf16x8*)&W2t[(cw + ct * 16 + c) * 128 + kk * 32 + g * 8];
  const float b1c0 = b1[cw + c], b1c1 = b1[cw + 16 + c];
  const float b2c0 = b2[cw + c], b2c1 = b2[cw + 16 + c];
  float lsum0 = 0.f, lsum1 = 0.f, lsq0 = 0.f, lsq1 = 0.f;

  for (int chunk = blockIdx.x; chunk < nChunks; chunk += gridDim.x) {
    const int base = chunk * 64;
    if constexpr (DIN == 128) {
#pragma unroll
      for (int p = 0; p < 4; ++p) {
        const int idx = tid + 256 * p;
        const int n = idx >> 4, k8 = idx & 15;
        const int node = base + n;
        uint4 ov = make_uint4(0u, 0u, 0u, 0u);
        if (node < NN) {
          const float4 g0 = *(const float4*)&agg[node * 128 + k8 * 8];
          const float4 g1 = *(const float4*)&agg[node * 128 + k8 * 8 + 4];
          const uint4 hv = *(const uint4*)&abf[node * 128 + k8 * 8];
          ov.x = pack2(bf2f((unsigned short)(hv.x & 0xffffu)) + g0.x,
                       bf2f((unsigned short)(hv.x >> 16)) + g0.y);
          ov.y = pack2(bf2f((unsigned short)(hv.y & 0xffffu)) + g0.z,
                       bf2f((unsigned short)(hv.y >> 16)) + g0.w);
          ov.z = pack2(bf2f((unsigned short)(hv.z & 0xffffu)) + g1.x,
                       bf2f((unsigned short)(hv.z >> 16)) + g1.y);
          ov.w = pack2(bf2f((unsigned short)(hv.w & 0xffffu)) + g1.z,
                       bf2f((unsigned short)(hv.w >> 16)) + g1.w);
        }
        *(uint4*)&hin[n * P1 + k8 * 8] = ov;
      }
    } else {
      const int n = tid >> 2, k8 = tid & 3;
      const int node = base + n;
      uint4 ov = make_uint4(0u, 0u, 0u, 0u);
      if (node < NN) {
        const float4 x0 = *(const float4*)&a32[node * 32 + k8 * 8];
        const float4 x1 = *(const float4*)&a32[node * 32 + k8 * 8 + 4];
        const float4 g0 = *(const float4*)&agg[node * 32 + k8 * 8];
        const float4 g1 = *(const float4*)&agg[node * 32 + k8 * 8 + 4];
        ov.x = pack2(x0.x + g0.x, x0.y + g0.y);
        ov.y = pack2(x0.z + g0.z, x0.w + g0.w);
        ov.z = pack2(x1.x + g1.x, x1.y + g1.y);
        ov.w = pack2(x1.z + g1.z, x1.w + g1.w);
      }
      *(uint4*)&hin[n * P1 + k8 * 8] = ov;
    }
    __syncthreads();
#pragma unroll
    for (int nt = 0; nt < 4; ++nt) {
      bf16x8 af[KS1];
#pragma unroll
      for (int kk = 0; kk < KS1; ++kk)
        af[kk] = *(const bf16x8*)&hin[(nt * 16 + c) * P1 + kk * 32 + g * 8];
      f32x4 acc0 = {0.f, 0.f, 0.f, 0.f}, acc1 = {0.f, 0.f, 0.f, 0.f};
#pragma unroll
      for (int kk = 0; kk < KS1; ++kk) {
        acc0 = __builtin_amdgcn_mfma_f32_16x16x32_bf16(af[kk], B1[0][kk], acc0, 0, 0, 0);
        acc1 = __builtin_amdgcn_mfma_f32_16x16x32_bf16(af[kk], B1[1][kk], acc1, 0, 0, 0);
      }
#pragma unroll
      for (int j = 0; j < 4; ++j) {
        const int row = nt * 16 + g * 4 + j;
        tls[row * 136 + cw + c]      = f2bf(fmaxf(acc0[j] + b1c0, 0.f));
        tls[row * 136 + cw + 16 + c] = f2bf(fmaxf(acc1[j] + b1c1, 0.f));
      }
    }
    __syncthreads();
#pragma unroll
    for (int nt = 0; nt < 4; ++nt) {
      bf16x8 af[4];
#pragma unroll
      for (int kk = 0; kk < 4; ++kk)
        af[kk] = *(const bf16x8*)&tls[(nt * 16 + c) * 136 + kk * 32 + g * 8];
      f32x4 acc0 = {0.f, 0.f, 0.f, 0.f}, acc1 = {0.f, 0.f, 0.f, 0.f};
#pragma unroll
      for (int kk = 0; kk < 4; ++kk) {
        acc0 = __builtin_amdgcn_mfma_f32_16x16x32_bf16(af[kk], B2[0][kk], acc0, 0, 0, 0);
        acc1 = __builtin_amdgcn_mfma_f32_16x16x32_bf16(af[kk], B2[1][kk], acc1, 0, 0, 0);
      }
#pragma unroll
      for (int j = 0; j < 4; ++j) {
        const int node = base + nt * 16 + g * 4 + j;
        if (node < NN) {
          const float v0 = acc0[j] + b2c0;
          const float v1 = acc1[j] + b2c1;
          if constexpr (OUTB) {
            outpb[(size_t)node * 128 + cw + c] = f2bf(v0);
            outpb[(size_t)node * 128 + cw + 16 + c] = f2bf(v1);
          } else {
            outp[(size_t)node * 128 + cw + c] = v0;
            outp[(size_t)node * 128 + cw + 16 + c] = v1;
          }
          lsum0 += v0; lsq0 += v0 * v0;
          lsum1 += v1; lsq1 += v1 * v1;
        }
      }
    }
  }
  lsum0 += __shfl_xor(lsum0, 16); lsum0 += __shfl_xor(lsum0, 32);
  lsum1 += __shfl_xor(lsum1, 16); lsum1 += __shfl_xor(lsum1, 32);
  lsq0  += __shfl_xor(lsq0, 16);  lsq0  += __shfl_xor(lsq0, 32);
  lsq1  += __shfl_xor(lsq1, 16);  lsq1  += __shfl_xor(lsq1, 32);
  if (lane < 16) {
    atomicAdd(&stats[cw + lane], lsum0);
    atomicAdd(&stats[cw + 16 + lane], lsum1);
    atomicAdd(&stats[128 + cw + lane], lsq0);
    atomicAdd(&stats[128 + cw + 16 + lane], lsq1);
  }
}

// ---------------------------------------------------------------------------
// BN apply (bf16 in -> bf16 out), finalize inlined via LDS; PLUS 391 extra
// blocks that zero layer-1 AGG boundary rows (replaces the 51 MB memset).
// ---------------------------------------------------------------------------
__global__ __launch_bounds__(256) void bn_apply_bb(
    const unsigned short* __restrict__ hpreb, const float* __restrict__ stats,
    const float* __restrict__ gamma, const float* __restrict__ beta,
    unsigned short* __restrict__ hb,
    const uint32* __restrict__ toff, const uint32* __restrict__ deg,
    float* __restrict__ agg)
{
  if (blockIdx.x >= (NN * 16) / 256) {
    // zero layer-1 agg rows (D=128) for atomic-flush / empty nodes
    const int n = (blockIdx.x - (NN * 16) / 256) * 256 + threadIdx.x;
    if (n < NN) {
      const uint32 t0 = toff[n];
      const uint32 tc = (deg[n] + 15u) >> 4;
      if (tc == 0u || ((t0 & 7u) + tc) > 8u) {
        float4* p = (float4*)&agg[(size_t)n * 128];
#pragma unroll
        for (int k = 0; k < 32; ++k) p[k] = make_float4(0.f, 0.f, 0.f, 0.f);
      }
    }
    return;
  }
  __shared__ float scs[128], shs[128];
  const int tid = threadIdx.x;
  if (tid < 128) {
    const float inv_n = 1.0f / (float)NN;
    const float mu = stats[tid] * inv_n;
    float var = stats[128 + tid] * inv_n - mu * mu;
    var = fmaxf(var, 0.f);
    const float sc = rsqrtf(var + 1e-5f) * gamma[tid];
    scs[tid] = sc;
    shs[tid] = beta[tid] - mu * sc;
  }
  __syncthreads();
  const int idx = blockIdx.x * 256 + tid;   // over NN*16 uint4 groups
  const int c8 = (idx & 15) * 8;
  const uint4 hv = ((const uint4*)hpreb)[idx];
  const float t0 = bf2f((unsigned short)(hv.x & 0xffffu));
  const float t1 = bf2f((unsigned short)(hv.x >> 16));
  const float t2 = bf2f((unsigned short)(hv.y & 0xffffu));
  const float t3 = bf2f((unsigned short)(hv.y >> 16));
  const float t4 = bf2f((unsigned short)(hv.z & 0xffffu));
  const float t5 = bf2f((unsigned short)(hv.z >> 16));
  const float t6 = bf2f((unsigned short)(hv.w & 0xffffu));
  const float t7 = bf2f((unsigned short)(hv.w >> 16));
  uint4 o;
  o.x = pack2(fmaxf(fmaf(t0, scs[c8 + 0], shs[c8 + 0]), 0.f),
              fmaxf(fmaf(t1, scs[c8 + 1], shs[c8 + 1]), 0.f));
  o.y = pack2(fmaxf(fmaf(t2, scs[c8 + 2], shs[c8 + 2]), 0.f),
              fmaxf(fmaf(t3, scs[c8 + 3], shs[c8 + 3]), 0.f));
  o.z = pack2(fmaxf(fmaf(t4, scs[c8 + 4], shs[c8 + 4]), 0.f),
              fmaxf(fmaf(t5, scs[c8 + 5], shs[c8 + 5]), 0.f));
  o.w = pack2(fmaxf(fmaf(t6, scs[c8 + 6], shs[c8 + 6]), 0.f),
              fmaxf(fmaf(t7, scs[c8 + 7], shs[c8 + 7]), 0.f));
  ((uint4*)hb)[idx] = o;
}

// ---------------------------------------------------------------------------
// Fused BN-apply + head, hpre in BF16, finalize inlined via LDS:
//   out = sigmoid(relu(relu(bf16(hpre)*sc+sh)@W1+b1)@w2 + b2)
// ---------------------------------------------------------------------------
__global__ __launch_bounds__(256) void head_bn(
    const unsigned short* __restrict__ hpreb, const float* __restrict__ stats,
    const float* __restrict__ gamma, const float* __restrict__ beta,
    const unsigned short* __restrict__ W1t, const float* __restrict__ b1,
    const float* __restrict__ w2, const float* __restrict__ b2,
    float* __restrict__ out, int nChunks)
{
  __shared__ float pl[4][64];
  __shared__ float scs[128], shs[128];
  const int tid = threadIdx.x;
  if (tid < 128) {
    const float inv_n = 1.0f / (float)NN;
    const float mu = stats[tid] * inv_n;
    float var = stats[128 + tid] * inv_n - mu * mu;
    var = fmaxf(var, 0.f);
    const float sc = rsqrtf(var + 1e-5f) * gamma[tid];
    scs[tid] = sc;
    shs[tid] = beta[tid] - mu * sc;
  }
  __syncthreads();
  const int w = tid >> 6;
  const int lane = tid & 63;
  const int c = lane & 15, g = lane >> 4;
  const int cw = w * 32;

  bf16x8 B1[2][4];
#pragma unroll
  for (int ct = 0; ct < 2; ++ct)
#pragma unroll
    for (int kk = 0; kk < 4; ++kk)
      B1[ct][kk] = *(const bf16x8*)&W1t[(cw + ct * 16 + c) * 128 + kk * 32 + g * 8];
  const float b1c0 = b1[cw + c], b1c1 = b1[cw + 16 + c];
  const float w2c0 = w2[cw + c], w2c1 = w2[cw + 16 + c];
  const float b2v = b2[0];
  float4 scq[4][2], shq[4][2];
#pragma unroll
  for (int kk = 0; kk < 4; ++kk) {
    const int cb = kk * 32 + g * 8;
    scq[kk][0] = make_float4(scs[cb], scs[cb + 1], scs[cb + 2], scs[cb + 3]);
    scq[kk][1] = make_float4(scs[cb + 4], scs[cb + 5], scs[cb + 6], scs[cb + 7]);
    shq[kk][0] = make_float4(shs[cb], shs[cb + 1], shs[cb + 2], shs[cb + 3]);
    shq[kk][1] = make_float4(shs[cb + 4], shs[cb + 5], shs[cb + 6], shs[cb + 7]);
  }

  for (int chunk = blockIdx.x; chunk < nChunks; chunk += gridDim.x) {
    const int base = chunk * 64;
    float p[4][4];
#pragma unroll
    for (int nt = 0; nt < 4; ++nt) {
      const int node = base + nt * 16 + c;
      bf16x8 af[4];
#pragma unroll
      for (int kk = 0; kk < 4; ++kk) {
        uint4 u = make_uint4(0u, 0u, 0u, 0u);
        if (node < NN) {
          const uint4 hv = *(const uint4*)&hpreb[(size_t)node * 128 + kk * 32 + g * 8];
          const float4 s0 = scq[kk][0], s1 = scq[kk][1];
          const float4 h0 = shq[kk][0], h1 = shq[kk][1];
          const float t0 = bf2f((unsigned short)(hv.x & 0xffffu));
          const float t1 = bf2f((unsigned short)(hv.x >> 16));
          const float t2 = bf2f((unsigned short)(hv.y & 0xffffu));
          const float t3 = bf2f((unsigned short)(hv.y >> 16));
          const float t4 = bf2f((unsigned short)(hv.z & 0xffffu));
          const float t5 = bf2f((unsigned short)(hv.z >> 16));
          const float t6 = bf2f((unsigned short)(hv.w & 0xffffu));
          const float t7 = bf2f((unsigned short)(hv.w >> 16));
          u.x = pack2(fmaxf(fmaf(t0, s0.x, h0.x), 0.f),
                      fmaxf(fmaf(t1, s0.y, h0.y), 0.f));
          u.y = pack2(fmaxf(fmaf(t2, s0.z, h0.z), 0.f),
                      fmaxf(fmaf(t3, s0.w, h0.w), 0.f));
          u.z = pack2(fmaxf(fmaf(t4, s1.x, h1.x), 0.f),
                      fmaxf(fmaf(t5, s1.y, h1.y), 0.f));
          u.w = pack2(fmaxf(fmaf(t6, s1.z, h1.z), 0.f),
                      fmaxf(fmaf(t7, s1.w, h1.w), 0.f));
        }
        union { uint4 u4; bf16x8 v; } cv; cv.u4 = u;
        af[kk] = cv.v;
      }
      f32x4 acc0 = {0.f, 0.f, 0.f, 0.f}, acc1 = {0.f, 0.f, 0.f, 0.f};
#pragma unroll
      for (int kk = 0; kk < 4; ++kk) {
        acc0 = __builtin_amdgcn_mfma_f32_16x16x32_bf16(af[kk], B1[0][kk], acc0, 0, 0, 0);
        acc1 = __builtin_amdgcn_mfma_f32_16x16x32_bf16(af[kk], B1[1][kk], acc1, 0, 0, 0);
      }
#pragma unroll
      for (int j = 0; j < 4; ++j)
        p[nt][j] = fmaxf(acc0[j] + b1c0, 0.f) * w2c0 +
                   fmaxf(acc1[j] + b1c1, 0.f) * w2c1;
    }
#pragma unroll
    for (int dd = 1; dd <= 8; dd <<= 1)
#pragma unroll
      for (int nt = 0; nt < 4; ++nt)
#pragma unroll
        for (int j = 0; j < 4; ++j)
          p[nt][j] += __shfl_xor(p[nt][j], dd);
    if (c == 0) {
#pragma unroll
      for (int nt = 0; nt < 4; ++nt)
#pragma unroll
        for (int j = 0; j < 4; ++j)
          pl[w][nt * 16 + g * 4 + j] = p[nt][j];
    }
    __syncthreads();
    if (tid < 64) {
      const int node = base + tid;
      if (node < NN) {
        const float s = pl[0][tid] + pl[1][tid] + pl[2][tid] + pl[3][tid] + b2v;
        out[node] = 1.f / (1.f + expf(-s));
      }
    }
    __syncthreads();
  }
}

extern "C" void kernel_launch(void* const* d_in, const int* in_sizes, int n_in,
                              void* d_out, int out_size, void* d_ws, size_t ws_size,
                              hipStream_t stream)
{
  const float* x    = (const float*)d_in[0];
  const int*   ei   = (const int*)  d_in[1];
  const float* ea   = (const float*)d_in[2];
  const float* l0We = (const float*)d_in[3];
  const float* l0be = (const float*)d_in[4];
  const float* l0W1 = (const float*)d_in[5];
  const float* l0b1 = (const float*)d_in[6];
  const float* l0W2 = (const float*)d_in[7];
  const float* l0b2 = (const float*)d_in[8];
  const float* l0g  = (const float*)d_in[9];
  const float* l0bt = (const float*)d_in[10];
  const float* l1We = (const float*)d_in[11];
  const float* l1be = (const float*)d_in[12];
  const float* l1W1 = (const float*)d_in[13];
  const float* l1b1 = (const float*)d_in[14];
  const float* l1W2 = (const float*)d_in[15];
  const float* l1b2 = (const float*)d_in[16];
  const float* l1g  = (const float*)d_in[17];
  const float* l1bt = (const float*)d_in[18];
  const float* hW1  = (const float*)d_in[19];
  const float* hb1  = (const float*)d_in[20];
  const float* hW2  = (const float*)d_in[21];
  const float* hb2  = (const float*)d_in[22];
  float* out = (float*)d_out;

  // workspace layout (~201 MB; proven available R9-R18)
  float*  A    = (float*)d_ws;                         // NN*128 (hpre bf16 view)
  float*  AGG  = A + (size_t)NN * 128;                 // NN*128 f32
  unsigned short* hb = (unsigned short*)(AGG + (size_t)NN * 128);  // NN*128 bf16
  unsigned short* xb = hb + (size_t)NN * 128;          // NN*32 bf16
  uint32* deg     = (uint32*)(xb + (size_t)NN * 32);   // NN
  uint32* cnt     = deg + NN;                          // NN
  uint32* toff    = cnt + NN;                          // NN
  uint32* eoff    = toff + NN;                         // NN
  ull*    counter = (ull*)(eoff + NN);                 // 1 (pad 2)
  int*    snode   = (int*)(counter + 2);               // TMAX
  uint2*  esrc2   = (uint2*)(snode + TMAX);            // NE + 128 pad
  float*  st0     = (float*)(esrc2 + NE + 128);        // 512
  float*  st1     = st0 + 512;                         // 512
  unsigned short* W1t0 = (unsigned short*)(st1 + 512); // 32*128
  unsigned short* W2t0 = W1t0 + 4096;                  // 128*128
  unsigned short* W1t1 = W2t0 + 16384;
  unsigned short* W2t1 = W1t1 + 16384;
  unsigned short* hW1t = W2t1 + 16384;
  unsigned short* Wet0 = hW1t + 16384;                 // 32*16
  unsigned short* Wet1 = Wet0 + 512;                   // 128*16
  unsigned short* eabc = Wet1 + 2048;                  // NE*16 bf16 (51.2 MB)
  unsigned short* Ab = (unsigned short*)A;             // bf16 view (hpre)

  const size_t needed = (size_t)((char*)(eabc + (size_t)NE * 16) - (char*)d_ws);
  if (ws_size < needed) return;

  hipMemsetAsync(deg, 0, (size_t)2 * NN * 4, stream);          // deg, cnt
  hipMemsetAsync(counter, 0, 16, stream);
  hipMemsetAsync(snode, 0xFF, (size_t)TMAX * 4, stream);
  hipMemsetAsync(st0, 0, 4096, stream);                        // st0 + st1

  const int nChunks = (NN + 63) / 64;     // 1563
  const int eBlocks = (NE + 255) / 256;   // 6250
  const int nBlocks = (NN + 255) / 256;   // 391

  // combined conversion + degree histogram (one launch)
  conv_hist<<<16 + 64 * 4 + 2 + 8 + 1563 + eBlocks, 256, 0, stream>>>(
      l0W1, l0W2, l1W1, l1W2, hW1, l0We, l1We, x,
      W1t0, W2t0, W1t1, W2t1, hW1t, Wet0, Wet1, xb, ei, deg);

  offsets2_kernel<<<nBlocks, 256, 0, stream>>>(deg, toff, eoff, counter);
  // snode fill + layer-0 boundary-row zeroing + edge slot fill
  snode_and_fill<<<nBlocks + eBlocks, 256, 0, stream>>>(
      toff, deg, snode, ei, eoff, cnt, esrc2, AGG);

  // layer 0: gathers ea (long latency) -> depth-3 pipeline
  flat_agg9<32, 2, true, 3><<<NRANGES / 4, 256, 0, stream>>>(
      snode, toff, eoff, deg, esrc2, ea, eabc, xb, Wet0, l0be, counter, AGG);
  mlp_mfma<32, false, true><<<782, 256, 0, stream>>>(
      x, (const unsigned short*)nullptr, AGG, W1t0, l0b1, W2t0, l0b2,
      (float*)nullptr, Ab, st0, nChunks);
  // BN apply (bf16->bf16) + layer-1 AGG boundary-row zeroing (merged)
  bn_apply_bb<<<(NN * 16) / 256 + nBlocks, 256, 0, stream>>>(
      Ab, st0, l0g, l0bt, hb, toff, deg, AGG);

  // layer 1: eabc path (short latency) -> depth-2; writes hpre1 as BF16
  flat_agg9<128, 8, false, 2><<<NRANGES / 4, 256, 0, stream>>>(
      snode, toff, eoff, deg, esrc2, ea, eabc, hb, Wet1, l1be, counter, AGG);
  mlp_mfma<128, true, true><<<782, 256, 0, stream>>>(
      (const float*)nullptr, hb, AGG, W1t1, l1b1, W2t1, l1b2,
      (float*)nullptr, Ab, st1, nChunks);

  // fused BN-finalize + BN-apply + head (bf16 hpre)
  head_bn<<<782, 256, 0, stream>>>(Ab, st1, l1g, l1bt, hW1t, hb1, hW2, hb2,
                                   out, nChunks);
}